// Round 4
// baseline (2090.399 us; speedup 1.0000x reference)
//
#include <hip/hip_runtime.h>
#include <hip/hip_bf16.h>
#include <math.h>

// ----------------------------------------------------------------------------
// vMFLunaBlock v4: everything matmul-shaped on MFMA (split-bf16 3-term).
// Shapes: B=4 S=4096 M=256 D=768 H=12 Dh=64 T=1024 MLP=3072
// Workspace: 40,894,464 floats = 163.6 MB (same audited layout as v3).
// ----------------------------------------------------------------------------

typedef unsigned short u16;
typedef __attribute__((ext_vector_type(8))) short bf8v;   // 8 bf16 (4 VGPR)
typedef __attribute__((ext_vector_type(4))) float f4v;
typedef __attribute__((ext_vector_type(4))) unsigned short us4v;

#define AS1 __attribute__((address_space(1)))
#define AS3 __attribute__((address_space(3)))

__device__ __forceinline__ void gld_lds16(const void* g, void* l) {
  __builtin_amdgcn_global_load_lds((const AS1 unsigned int*)g,
                                   (AS3 unsigned int*)l, 16, 0, 0);
}

__device__ __forceinline__ u16 bf16_rne(float x) {
  unsigned u = __float_as_uint(x);
  return (u16)((u + 0x7fffu + ((u >> 16) & 1u)) >> 16);
}
__device__ __forceinline__ float bf16_to_f(u16 h) {
  return __uint_as_float(((unsigned)h) << 16);
}

// ---------------- split fp32 -> (hi, lo) bf16 (vectorized x4) ----------------
__global__ __launch_bounds__(256) void split_kernel(
    const float* __restrict__ in, u16* __restrict__ hi, u16* __restrict__ lo,
    int n4) {
  int i = blockIdx.x * 256 + threadIdx.x;
  if (i >= n4) return;
  float4 v = ((const float4*)in)[i];
  us4v h, l;
  float vv[4] = {v.x, v.y, v.z, v.w};
#pragma unroll
  for (int j = 0; j < 4; ++j) {
    u16 hb = bf16_rne(vv[j]);
    h[j] = hb;
    l[j] = bf16_rne(vv[j] - bf16_to_f(hb));
  }
  ((us4v*)hi)[i] = h;
  ((us4v*)lo)[i] = l;
}

// ---------------- split-bf16 MFMA GEMM (batched, BN templated) ----------------
// C = scale * (A @ B^T) [+ exact GELU]
// A: fp32 [M x K] (lda), split hi/lo in-kernel (reg-staged, swizzled ds_write).
// B: pre-split bf16 hi/lo u16 arrays, [N x K] layout (ldb).
// Tiles: 128 x BN, BK=32. 4 waves (2x2), wave tile 64 x BN/2.
// Batch z: bb = z/HB, hh = z%HB; strides per operand (A,C in floats, B in u16).
template <int BN, int GELU>
__global__ __launch_bounds__(256) void mgemm_kernel(
    const float* __restrict__ A, const u16* __restrict__ Bh,
    const u16* __restrict__ Bl, float* __restrict__ C, int M, int N, int K,
    int lda, int ldb, int ldc, long long aSB, long long aSH, long long bSB,
    long long bSH, long long cSB, long long cSH, int HB, float scale) {
  constexpr int NJ = BN / 32;   // B frags per wave
  constexpr int GPM = BN / 16;  // 16-row groups per B matrix
  constexpr int LPW = BN / 32;  // B gld_lds issues per wave (2 matrices)
  __shared__ u16 smA[2][4096];      // [128][32] hi/lo
  __shared__ u16 smB[2][BN * 32];   // [BN][32] hi/lo
  const int t = threadIdx.x;
  const int w = t >> 6, lane = t & 63;
  const int z = blockIdx.z;
  const int bb = z / HB, hh = z % HB;
  const float* Ab = A + bb * aSB + hh * aSH;
  const u16* Bhb = Bh + bb * bSB + hh * bSH;
  const u16* Blb = Bl + bb * bSB + hh * bSH;
  float* Cb = C + bb * cSB + hh * cSH;
  const int row0 = blockIdx.y * 128, col0 = blockIdx.x * BN;

  // B staging: 16-row groups of [16][32] u16 = 1KB, linear dest,
  // pre-swizzled source column chunk (validated in v3).
  const int brow_l = lane >> 2;
  const int bchunk = ((lane & 3) ^ ((lane >> 3) & 3)) * 8;
  // A staging (fp32 -> split -> swizzled ds_write), validated in v3.
  const int ar = t >> 3;
  const int ac = (t & 7) * 4;
  const int adst = ((((t >> 1) & 3) ^ ((t >> 4) & 3)) * 8) + ((t & 1) * 4);
  // fragment reads
  const int fr = lane & 15;
  const int fq = lane >> 4;
  const int fco = (fq ^ ((lane >> 1) & 3)) * 8;
  const int wr = (w >> 1) * 64, wc = (w & 1) * (BN / 2);

  f4v acc[4][NJ];
#pragma unroll
  for (int i = 0; i < 4; ++i)
#pragma unroll
    for (int j = 0; j < NJ; ++j) acc[i][j] = {0.f, 0.f, 0.f, 0.f};

  for (int k0 = 0; k0 < K; k0 += 32) {
    __syncthreads();
    // ---- B: async global -> LDS ----
#pragma unroll
    for (int i = 0; i < LPW; ++i) {
      const int g = w * LPW + i;
      const int hl = g / GPM, ms = g % GPM;
      const int r = ms * 16 + brow_l;
      const u16* src =
          (hl ? Blb : Bhb) + (long long)(col0 + r) * ldb + k0 + bchunk;
      gld_lds16(src, &smB[hl][ms * 512 + lane * 8]);
    }
    // ---- A: fp32 load -> split -> swizzled ds_write ----
#pragma unroll
    for (int i = 0; i < 4; ++i) {
      const int r = i * 32 + ar;
      const float4 v = *(const float4*)(Ab + (long long)(row0 + r) * lda + k0 + ac);
      const float vv[4] = {v.x, v.y, v.z, v.w};
      us4v h, l;
#pragma unroll
      for (int j = 0; j < 4; ++j) {
        u16 hb = bf16_rne(vv[j]);
        h[j] = hb;
        l[j] = bf16_rne(vv[j] - bf16_to_f(hb));
      }
      *(us4v*)&smA[0][r * 32 + adst] = h;
      *(us4v*)&smA[1][r * 32 + adst] = l;
    }
    __syncthreads();
    // ---- fragments + 3-term MFMA ----
    bf8v af[4][2], bf[NJ][2];
#pragma unroll
    for (int mi = 0; mi < 4; ++mi) {
      const int r = wr + mi * 16 + fr;
      af[mi][0] = *(const bf8v*)&smA[0][r * 32 + fco];
      af[mi][1] = *(const bf8v*)&smA[1][r * 32 + fco];
    }
#pragma unroll
    for (int nj = 0; nj < NJ; ++nj) {
      const int r = wc + nj * 16 + fr;
      bf[nj][0] = *(const bf8v*)&smB[0][r * 32 + fco];
      bf[nj][1] = *(const bf8v*)&smB[1][r * 32 + fco];
    }
#pragma unroll
    for (int mi = 0; mi < 4; ++mi)
#pragma unroll
      for (int nj = 0; nj < NJ; ++nj) {
        acc[mi][nj] = __builtin_amdgcn_mfma_f32_16x16x32_bf16(
            af[mi][0], bf[nj][0], acc[mi][nj], 0, 0, 0);
        acc[mi][nj] = __builtin_amdgcn_mfma_f32_16x16x32_bf16(
            af[mi][0], bf[nj][1], acc[mi][nj], 0, 0, 0);
        acc[mi][nj] = __builtin_amdgcn_mfma_f32_16x16x32_bf16(
            af[mi][1], bf[nj][0], acc[mi][nj], 0, 0, 0);
      }
  }
  // ---- epilogue: C/D layout col = lane&15, row = (lane>>4)*4 + reg ----
#pragma unroll
  for (int mi = 0; mi < 4; ++mi)
#pragma unroll
    for (int nj = 0; nj < NJ; ++nj) {
      const int col = col0 + wc + nj * 16 + fr;
      const long long base =
          (long long)(row0 + wr + mi * 16 + fq * 4) * ldc + col;
#pragma unroll
      for (int j = 0; j < 4; ++j) {
        float v = acc[mi][nj][j] * scale;
        if (GELU) v = 0.5f * v * (1.f + erff(v * 0.70710678118654752f));
        Cb[base + (long long)j * ldc] = v;
      }
    }
}

// ---------------- conv pool -> split bf16 hi/lo, [b,h,t,dh] layout ----------
__global__ __launch_bounds__(256) void conv_split_kernel(
    const float* __restrict__ in, const float* __restrict__ w,
    u16* __restrict__ hi, u16* __restrict__ lo, int total) {
  int idx = blockIdx.x * 256 + threadIdx.x;
  if (idx >= total) return;
  const int dh = idx & 63;
  int r = idx >> 6;
  const int tt = r & 1023; r >>= 10;
  const int h = r % 12;
  const int b = r / 12;
  const float* s = in + ((long long)(b * 4096 + 4 * tt)) * 768 + h * 64 + dh;
  const float* wh = w + h * 4;
  const float v = fmaf(wh[0], s[0],
                  fmaf(wh[1], s[768], fmaf(wh[2], s[1536], wh[3] * s[2304])));
  const u16 hb = bf16_rne(v);
  hi[idx] = hb;
  lo[idx] = bf16_rne(v - bf16_to_f(hb));
}

// ---------------- conv pool -> split, TRANSPOSED [b,h,dh,t] layout ----------
__global__ __launch_bounds__(256) void conv_splitT_kernel(
    const float* __restrict__ in, const float* __restrict__ w,
    u16* __restrict__ hi, u16* __restrict__ lo, int total) {
  int idx = blockIdx.x * 256 + threadIdx.x;
  if (idx >= total) return;
  const int tt = idx & 1023;
  int r = idx >> 10;
  const int dh = r & 63; r >>= 6;
  const int h = r % 12;
  const int b = r / 12;
  const float* s = in + ((long long)(b * 4096 + 4 * tt)) * 768 + h * 64 + dh;
  const float* wh = w + h * 4;
  const float v = fmaf(wh[0], s[0],
                  fmaf(wh[1], s[768], fmaf(wh[2], s[1536], wh[3] * s[2304])));
  const u16 hb = bf16_rne(v);
  hi[idx] = hb;
  lo[idx] = bf16_rne(v - bf16_to_f(hb));
}

// ---------------- transpose+split: [4,256,768] -> [b,h,dh,key] hi/lo --------
__global__ __launch_bounds__(256) void splitT_kernel(
    const float* __restrict__ in, u16* __restrict__ hi, u16* __restrict__ lo,
    int total) {
  int idx = blockIdx.x * 256 + threadIdx.x;
  if (idx >= total) return;
  const int key = idx & 255;
  int r = idx >> 8;
  const int dh = r & 63; r >>= 6;
  const int h = r % 12;
  const int b = r / 12;
  const float v = in[((long long)(b * 256 + key)) * 768 + h * 64 + dh];
  const u16 hb = bf16_rne(v);
  hi[idx] = hb;
  lo[idx] = bf16_rne(v - bf16_to_f(hb));
}

// ---------------- row softmax (in place), rowlen = ITERS*256 ----------------
template <int ITERS>
__global__ __launch_bounds__(256) void softmax_kernel(float* __restrict__ data) {
  const long long row = blockIdx.x;
  float* p = data + row * (ITERS * 256);
  const int t = threadIdx.x;
  __shared__ float red[4];
  float v[ITERS];
  float lmax = -3.4e38f;
#pragma unroll
  for (int i = 0; i < ITERS; ++i) {
    v[i] = p[t + (i << 8)];
    lmax = fmaxf(lmax, v[i]);
  }
  for (int o = 32; o; o >>= 1) lmax = fmaxf(lmax, __shfl_xor(lmax, o));
  if ((t & 63) == 0) red[t >> 6] = lmax;
  __syncthreads();
  const float gmax = fmaxf(fmaxf(red[0], red[1]), fmaxf(red[2], red[3]));
  float lsum = 0.f;
#pragma unroll
  for (int i = 0; i < ITERS; ++i) {
    v[i] = expf(v[i] - gmax);
    lsum += v[i];
  }
  __syncthreads();
  for (int o = 32; o; o >>= 1) lsum += __shfl_xor(lsum, o);
  if ((t & 63) == 0) red[t >> 6] = lsum;
  __syncthreads();
  const float inv = 1.f / (red[0] + red[1] + red[2] + red[3]);
#pragma unroll
  for (int i = 0; i < ITERS; ++i) p[t + (i << 8)] = v[i] * inv;
}

// ---------------- LayerNorm(a + b*maskf), eps 1e-6, width 768 ----------------
__global__ __launch_bounds__(256) void ln_kernel(
    const float* __restrict__ a, const float* __restrict__ b,
    const int* __restrict__ mask, float* __restrict__ out) {
  const long long row = blockIdx.x;
  const float* pa = a + row * 768;
  const float* pb = b + row * 768;
  const float ms = mask ? (float)mask[row] : 1.f;
  __shared__ float buf[768];
  __shared__ float red[4];
  const int t = threadIdx.x;
  float lsum = 0.f;
#pragma unroll
  for (int i = t; i < 768; i += 256) {
    const float v = fmaf(pb[i], ms, pa[i]);
    buf[i] = v;
    lsum += v;
  }
  for (int o = 32; o; o >>= 1) lsum += __shfl_xor(lsum, o);
  if ((t & 63) == 0) red[t >> 6] = lsum;
  __syncthreads();
  const float mu = (red[0] + red[1] + red[2] + red[3]) * (1.f / 768.f);
  float lvar = 0.f;
#pragma unroll
  for (int i = t; i < 768; i += 256) {
    const float d = buf[i] - mu;
    lvar = fmaf(d, d, lvar);
  }
  __syncthreads();
  for (int o = 32; o; o >>= 1) lvar += __shfl_xor(lvar, o);
  if ((t & 63) == 0) red[t >> 6] = lvar;
  __syncthreads();
  const float var = (red[0] + red[1] + red[2] + red[3]) * (1.f / 768.f);
  const float rstd = rsqrtf(var + 1e-6f);
  float* po = out + row * 768;
#pragma unroll
  for (int i = t; i < 768; i += 256) po[i] = (buf[i] - mu) * rstd;
}

// ---------------- host helpers ----------------
static inline void mgemm(hipStream_t st, const float* A, const u16* Bh,
                         const u16* Bl, float* C, int M, int N, int K, int lda,
                         int ldb, int ldc, long long aSB, long long aSH,
                         long long bSB, long long bSH, long long cSB,
                         long long cSH, int nBat, int HB, float scale, int bn,
                         int gelu) {
  if (bn == 128) {
    dim3 g(N / 128, M / 128, nBat);
    if (gelu)
      mgemm_kernel<128, 1><<<g, 256, 0, st>>>(A, Bh, Bl, C, M, N, K, lda, ldb,
                                              ldc, aSB, aSH, bSB, bSH, cSB, cSH,
                                              HB, scale);
    else
      mgemm_kernel<128, 0><<<g, 256, 0, st>>>(A, Bh, Bl, C, M, N, K, lda, ldb,
                                              ldc, aSB, aSH, bSB, bSH, cSB, cSH,
                                              HB, scale);
  } else {
    dim3 g(N / 64, M / 128, nBat);
    mgemm_kernel<64, 0><<<g, 256, 0, st>>>(A, Bh, Bl, C, M, N, K, lda, ldb, ldc,
                                           aSB, aSH, bSB, bSH, cSB, cSH, HB,
                                           scale);
  }
}

static inline void split_launch(hipStream_t st, const float* in, u16* hi,
                                u16* lo, int n) {
  int n4 = n / 4;
  split_kernel<<<(n4 + 255) / 256, 256, 0, st>>>(in, hi, lo, n4);
}

extern "C" void kernel_launch(void* const* d_in, const int* in_sizes, int n_in,
                              void* d_out, int out_size, void* d_ws,
                              size_t ws_size, hipStream_t stream) {
  const float* x = (const float*)d_in[0];       // [4,4096,768]
  const float* memory = (const float*)d_in[1];  // [4,256,768]
  const int* mask = (const int*)d_in[2];        // [4,4096]
  const float* Wq = (const float*)d_in[3];
  const float* Wk = (const float*)d_in[4];
  const float* Wv = (const float*)d_in[5];
  const float* Wo = (const float*)d_in[6];
  const float* conv_w = (const float*)d_in[7];  // [12,1,4,1]
  const float* Uq = (const float*)d_in[8];
  const float* Uk = (const float*)d_in[9];
  const float* Uv = (const float*)d_in[10];
  const float* Uo = (const float*)d_in[11];
  const float* W1 = (const float*)d_in[12];  // [3072,768]
  const float* W2 = (const float*)d_in[13];  // [768,3072]
  float* out = (float*)d_out;  // q_out [4,4096,768] then m_out [4,256,768]
  float* ws = (float*)d_ws;

  const int XR = 16384, MR = 1024, D = 768, MLP = 3072;
  const long long CB = 3145728;  // 4096*768
  const int WD = 589824;         // 768*768
  const int WM = 2359296;        // 3072*768

  // ---- workspace (floats); total 40,894,464 = 163.6 MB ----
  float* slotA = ws + 0;         // 12.58M: kproj -> pack-logits -> ulog -> uo/hbuf
  float* slotB = ws + 12582912;  // 12.58M: vproj -> uq -> qout1
  float* slotC = ws + 25165824;  //  3.15M: uattv_b / y_b
  float* X     = ws + 28311552;  //  6.29M: kp/vpT splits -> U+ukb/uvbT -> W1/W2
  float* qproj = ws + 34603008;  //  786K
  float* attvm = ws + 35389440;  //  786K
  float* packed= ws + 36175872;  //  786K
  float* ukb   = ws + 36962304;  //  786K
  float* uvb   = ws + 37748736;  //  786K
  float* Wp    = ws + 38535168;  //  2.36M: pack-weight splits

  u16* wp16 = (u16*)Wp;
  u16 *Wkh = wp16, *Wkl = wp16 + WD, *Wvh = wp16 + 2 * WD, *Wvl = wp16 + 3 * WD,
      *Wqh = wp16 + 4 * WD, *Wql = wp16 + 5 * WD, *Woh = wp16 + 6 * WD,
      *Wol = wp16 + 7 * WD;
  // X as u16, pack phase: kp/vpT splits (4 x 3,145,728 u16 = full 6.29M f)
  u16* xk = (u16*)X;
  u16 *kph = xk, *kpl = xk + 3145728, *vph = xk + 6291456, *vpl = xk + 9437184;
  // X, unpack phase: U splits + ukb/uvbT splits
  u16 *Uqh = xk, *Uql = xk + WD, *Ukh = xk + 2 * WD, *Ukl = xk + 3 * WD,
      *Uvh = xk + 4 * WD, *Uvl = xk + 5 * WD, *Uoh = xk + 6 * WD,
      *Uol = xk + 7 * WD;
  u16 *ukbh = xk + 4718592, *ukbl = xk + 5505024;
  u16 *uvth = xk + 6291456, *uvtl = xk + 7077888;
  // X, FFN phase: W1/W2 splits
  u16 *W1h = xk, *W1l = xk + WM, *W2h = xk + 2 * WM, *W2l = xk + 3 * WM;

  // ---- pack phase ----
  split_launch(stream, Wk, Wkh, Wkl, WD);
  split_launch(stream, Wv, Wvh, Wvl, WD);
  split_launch(stream, Wq, Wqh, Wql, WD);
  split_launch(stream, Wo, Woh, Wol, WD);
  mgemm(stream, x, Wkh, Wkl, slotA, XR, D, D, D, D, D, 0, 0, 0, 0, 0, 0, 1, 1, 1.f, 128, 0);
  mgemm(stream, x, Wvh, Wvl, slotB, XR, D, D, D, D, D, 0, 0, 0, 0, 0, 0, 1, 1, 1.f, 128, 0);
  mgemm(stream, memory, Wqh, Wql, qproj, MR, D, D, D, D, D, 0, 0, 0, 0, 0, 0, 1, 1, 1.f, 128, 0);
  conv_split_kernel<<<12288, 256, 0, stream>>>(slotA, conv_w, kph, kpl, 3145728);
  conv_splitT_kernel<<<12288, 256, 0, stream>>>(slotB, conv_w, vph, vpl, 3145728);
  // pack logits [b,h,256,1024] = qproj @ kp^T (K=64)
  mgemm(stream, qproj, kph, kpl, slotA, 256, 1024, 64, 768, 64, 1024,
        196608, 64, 786432, 65536, 3145728, 262144, 48, 12, 1.f, 128, 0);
  softmax_kernel<4><<<12288, 256, 0, stream>>>(slotA);
  // pack PV: [256,64] per (b,h), K=1024, Vt [b,h,64,1024]
  mgemm(stream, slotA, vph, vpl, attvm, 256, 64, 1024, 1024, 1024, 768,
        3145728, 262144, 786432, 65536, 196608, 64, 48, 12, 1.f, 64, 0);
  mgemm(stream, attvm, Woh, Wol, packed, MR, D, D, D, D, D, 0, 0, 0, 0, 0, 0, 1, 1, 1.f, 128, 0);
  ln_kernel<<<MR, 256, 0, stream>>>(memory, packed, nullptr, out + 12582912);

  // ---- unpack phase (kp/vpT dead -> X hosts U + kv splits) ----
  split_launch(stream, Uq, Uqh, Uql, WD);
  split_launch(stream, Uk, Ukh, Ukl, WD);
  split_launch(stream, Uv, Uvh, Uvl, WD);
  split_launch(stream, Uo, Uoh, Uol, WD);
  mgemm(stream, x, Uqh, Uql, slotB, XR, D, D, D, D, D, 0, 0, 0, 0, 0, 0, 1, 1, 1.f, 128, 0);  // uq
  mgemm(stream, packed, Ukh, Ukl, ukb, MR, D, D, D, D, D, 0, 0, 0, 0, 0, 0, 1, 1, 1.f, 128, 0);
  mgemm(stream, packed, Uvh, Uvl, uvb, MR, D, D, D, D, D, 0, 0, 0, 0, 0, 0, 1, 1, 1.f, 128, 0);
  split_launch(stream, ukb, ukbh, ukbl, 786432);
  splitT_kernel<<<3072, 256, 0, stream>>>(uvb, uvth, uvtl, 786432);
  for (int b = 0; b < 4; ++b) {
    // ulog [h,4096,256] = (uq_b/8) @ uk_b^T  (mask: per-row const -> no-op)
    mgemm(stream, slotB + b * CB, ukbh + (long long)b * 196608,
          ukbl + (long long)b * 196608, slotA, 4096, 256, 64, 768, 768, 256,
          0, 64, 0, 64, 0, 1048576, 12, 12, 0.125f, 128, 0);
    softmax_kernel<1><<<49152, 256, 0, stream>>>(slotA);
    // uattv_b [4096,768 merged] ; Vt [h,64,256]
    mgemm(stream, slotA, uvth + (long long)b * 196608,
          uvtl + (long long)b * 196608, slotC, 4096, 64, 256, 256, 256, 768,
          0, 1048576, 0, 16384, 0, 64, 12, 12, 1.f, 64, 0);
    // unp_b = uattv_b @ Uo^T -> slotA (logits dead)
    mgemm(stream, slotC, Uoh, Uol, slotA, 4096, D, D, D, D, D, 0, 0, 0, 0, 0, 0, 1, 1, 1.f, 128, 0);
    ln_kernel<<<4096, 256, 0, stream>>>(x + b * CB, slotA, mask + b * 4096,
                                        slotB + b * CB);
  }

  // ---- FFN phase (U/ukb splits dead -> X hosts W1/W2 splits) ----
  split_launch(stream, W1, W1h, W1l, WM);
  split_launch(stream, W2, W2h, W2l, WM);
  for (int b = 0; b < 4; ++b) {
    mgemm(stream, slotB + b * CB, W1h, W1l, slotA, 4096, MLP, D, D, D, MLP,
          0, 0, 0, 0, 0, 0, 1, 1, 1.f, 128, 1);
    mgemm(stream, slotA, W2h, W2l, slotC, 4096, D, MLP, MLP, MLP, D,
          0, 0, 0, 0, 0, 0, 1, 1, 1.f, 128, 0);
    ln_kernel<<<4096, 256, 0, stream>>>(slotB + b * CB, slotC, mask + b * 4096,
                                        out + b * CB);
  }
}

// Round 5
// 1706.469 us; speedup vs baseline: 1.2250x; 1.2250x over previous
//
#include <hip/hip_runtime.h>
#include <hip/hip_bf16.h>
#include <math.h>

// ----------------------------------------------------------------------------
// vMFLunaBlock v5: v4 + fused MFMA unpack attention + occupancy fixes.
// Shapes: B=4 S=4096 M=256 D=768 H=12 Dh=64 T=1024 MLP=3072
// Workspace: 40,894,464 floats = 163.6 MB (same audited layout as v3/v4).
// ----------------------------------------------------------------------------

typedef unsigned short u16;
typedef __attribute__((ext_vector_type(8))) short bf8v;   // 8 bf16 (4 VGPR)
typedef __attribute__((ext_vector_type(4))) float f4v;
typedef __attribute__((ext_vector_type(4))) unsigned short us4v;

#define AS1 __attribute__((address_space(1)))
#define AS3 __attribute__((address_space(3)))

__device__ __forceinline__ void gld_lds16(const void* g, void* l) {
  __builtin_amdgcn_global_load_lds((const AS1 unsigned int*)g,
                                   (AS3 unsigned int*)l, 16, 0, 0);
}

__device__ __forceinline__ u16 bf16_rne(float x) {
  unsigned u = __float_as_uint(x);
  return (u16)((u + 0x7fffu + ((u >> 16) & 1u)) >> 16);
}
__device__ __forceinline__ float bf16_to_f(u16 h) {
  return __uint_as_float(((unsigned)h) << 16);
}

// ---------------- split fp32 -> (hi, lo) bf16 (vectorized x4) ----------------
__global__ __launch_bounds__(256) void split_kernel(
    const float* __restrict__ in, u16* __restrict__ hi, u16* __restrict__ lo,
    int n4) {
  int i = blockIdx.x * 256 + threadIdx.x;
  if (i >= n4) return;
  float4 v = ((const float4*)in)[i];
  us4v h, l;
  float vv[4] = {v.x, v.y, v.z, v.w};
#pragma unroll
  for (int j = 0; j < 4; ++j) {
    u16 hb = bf16_rne(vv[j]);
    h[j] = hb;
    l[j] = bf16_rne(vv[j] - bf16_to_f(hb));
  }
  ((us4v*)hi)[i] = h;
  ((us4v*)lo)[i] = l;
}

// ---------------- split-bf16 MFMA GEMM (batched, BN templated) ----------------
// C = scale * (A @ B^T) [+ exact GELU]; A fp32 split in-kernel, B pre-split.
// Tiles: 128 x BN, BK=32. 4 waves (2x2), wave tile 64 x BN/2.
template <int BN, int GELU>
__global__ __launch_bounds__(256) void mgemm_kernel(
    const float* __restrict__ A, const u16* __restrict__ Bh,
    const u16* __restrict__ Bl, float* __restrict__ C, int M, int N, int K,
    int lda, int ldb, int ldc, long long aSB, long long aSH, long long bSB,
    long long bSH, long long cSB, long long cSH, int HB, float scale) {
  constexpr int NJ = BN / 32;   // B frags per wave
  constexpr int GPM = BN / 16;  // 16-row groups per B matrix
  constexpr int LPW = BN / 32;  // B gld_lds issues per wave (2 matrices)
  __shared__ u16 smA[2][4096];      // [128][32] hi/lo
  __shared__ u16 smB[2][BN * 32];   // [BN][32] hi/lo
  const int t = threadIdx.x;
  const int w = t >> 6, lane = t & 63;
  const int z = blockIdx.z;
  const int bb = z / HB, hh = z % HB;
  const float* Ab = A + bb * aSB + hh * aSH;
  const u16* Bhb = Bh + bb * bSB + hh * bSH;
  const u16* Blb = Bl + bb * bSB + hh * bSH;
  float* Cb = C + bb * cSB + hh * cSH;
  const int row0 = blockIdx.y * 128, col0 = blockIdx.x * BN;

  const int brow_l = lane >> 2;
  const int bchunk = ((lane & 3) ^ ((lane >> 3) & 3)) * 8;
  const int ar = t >> 3;
  const int ac = (t & 7) * 4;
  const int adst = ((((t >> 1) & 3) ^ ((t >> 4) & 3)) * 8) + ((t & 1) * 4);
  const int fr = lane & 15;
  const int fq = lane >> 4;
  const int fco = (fq ^ ((lane >> 1) & 3)) * 8;
  const int wr = (w >> 1) * 64, wc = (w & 1) * (BN / 2);

  f4v acc[4][NJ];
#pragma unroll
  for (int i = 0; i < 4; ++i)
#pragma unroll
    for (int j = 0; j < NJ; ++j) acc[i][j] = {0.f, 0.f, 0.f, 0.f};

  for (int k0 = 0; k0 < K; k0 += 32) {
    __syncthreads();
#pragma unroll
    for (int i = 0; i < LPW; ++i) {
      const int g = w * LPW + i;
      const int hl = g / GPM, ms = g % GPM;
      const int r = ms * 16 + brow_l;
      const u16* src =
          (hl ? Blb : Bhb) + (long long)(col0 + r) * ldb + k0 + bchunk;
      gld_lds16(src, &smB[hl][ms * 512 + lane * 8]);
    }
#pragma unroll
    for (int i = 0; i < 4; ++i) {
      const int r = i * 32 + ar;
      const float4 v = *(const float4*)(Ab + (long long)(row0 + r) * lda + k0 + ac);
      const float vv[4] = {v.x, v.y, v.z, v.w};
      us4v h, l;
#pragma unroll
      for (int j = 0; j < 4; ++j) {
        u16 hb = bf16_rne(vv[j]);
        h[j] = hb;
        l[j] = bf16_rne(vv[j] - bf16_to_f(hb));
      }
      *(us4v*)&smA[0][r * 32 + adst] = h;
      *(us4v*)&smA[1][r * 32 + adst] = l;
    }
    __syncthreads();
    bf8v af[4][2], bf[NJ][2];
#pragma unroll
    for (int mi = 0; mi < 4; ++mi) {
      const int r = wr + mi * 16 + fr;
      af[mi][0] = *(const bf8v*)&smA[0][r * 32 + fco];
      af[mi][1] = *(const bf8v*)&smA[1][r * 32 + fco];
    }
#pragma unroll
    for (int nj = 0; nj < NJ; ++nj) {
      const int r = wc + nj * 16 + fr;
      bf[nj][0] = *(const bf8v*)&smB[0][r * 32 + fco];
      bf[nj][1] = *(const bf8v*)&smB[1][r * 32 + fco];
    }
#pragma unroll
    for (int mi = 0; mi < 4; ++mi)
#pragma unroll
      for (int nj = 0; nj < NJ; ++nj) {
        acc[mi][nj] = __builtin_amdgcn_mfma_f32_16x16x32_bf16(
            af[mi][0], bf[nj][0], acc[mi][nj], 0, 0, 0);
        acc[mi][nj] = __builtin_amdgcn_mfma_f32_16x16x32_bf16(
            af[mi][0], bf[nj][1], acc[mi][nj], 0, 0, 0);
        acc[mi][nj] = __builtin_amdgcn_mfma_f32_16x16x32_bf16(
            af[mi][1], bf[nj][0], acc[mi][nj], 0, 0, 0);
      }
  }
#pragma unroll
  for (int mi = 0; mi < 4; ++mi)
#pragma unroll
    for (int nj = 0; nj < NJ; ++nj) {
      const int col = col0 + wc + nj * 16 + fr;
      const long long base =
          (long long)(row0 + wr + mi * 16 + fq * 4) * ldc + col;
#pragma unroll
      for (int j = 0; j < 4; ++j) {
        float v = acc[mi][nj][j] * scale;
        if (GELU) v = 0.5f * v * (1.f + erff(v * 0.70710678118654752f));
        Cb[base + (long long)j * ldc] = v;
      }
    }
}

// ---------------- fused unpack attention (MFMA, flash-style) ----------------
// Per block: (b,h), 128 q rows, all 256 keys. 512 threads (8 waves).
// Q fp32 [4,4096,768] head slice (scaled 1/8, split in-kernel);
// K pre-split [1024,768] head slice; Vt pre-split [4,12,64,256].
// out fp32 [4,4096,768] head slice = softmax(QK^T) @ V.
__global__ __launch_bounds__(512) void fused_unpack_attn(
    const float* __restrict__ q, const u16* __restrict__ kh,
    const u16* __restrict__ kl, const u16* __restrict__ vth,
    const u16* __restrict__ vtl, float* __restrict__ outp) {
  __shared__ char pool[76800];
  u16* smA0 = (u16*)pool;                 // [128*32] Q hi (phase 1)
  u16* smA1 = (u16*)(pool + 8192);        // Q lo
  u16* smB0 = (u16*)(pool + 16384);       // [256*32] K hi
  u16* smB1 = (u16*)(pool + 32768);       // K lo
  u16* Pbuf = (u16*)pool;                 // [8][128*32] P hi (phase 2)
  u16* smV0 = (u16*)(pool + 65536);       // [64*32] V hi
  u16* smV1 = (u16*)(pool + 69632);       // V lo
  float* partial = (float*)(pool + 73728);  // [4][128]
  float* rowmax = (float*)(pool + 75776);   // [128]
  float* rowsum = (float*)(pool + 76288);   // [128]

  const int t = threadIdx.x;
  const int w = t >> 6, lane = t & 63;
  const int z = blockIdx.z;
  const int b = z / 12, h = z % 12;
  const int q0 = blockIdx.x * 128;

  const float* qb = q + ((long long)b * 4096 + q0) * 768 + h * 64;
  const u16* khb = kh + ((long long)b * 256) * 768 + h * 64;
  const u16* klb = kl + ((long long)b * 256) * 768 + h * 64;
  const long long vbase = ((long long)(b * 12 + h)) * 16384;  // 64*256

  const int fr = lane & 15, fq = lane >> 4;
  const int fco = (fq ^ ((lane >> 1) & 3)) * 8;
  const int brow_l = lane >> 2;
  const int bchunk = ((lane & 3) ^ ((lane >> 3) & 3)) * 8;
  const int ar = t >> 3;          // [0,64)
  const int ac = (t & 7) * 4;
  const int adst = ((((t >> 1) & 3) ^ ((t >> 4) & 3)) * 8) + ((t & 1) * 4);

  // ---- phase 1: logits = (Q/8) @ K^T ; wave tile 64q x 64keys ----
  const int wr = (w >> 2) * 64, wc = (w & 3) * 64;
  f4v acc[4][4];
#pragma unroll
  for (int i = 0; i < 4; ++i)
#pragma unroll
    for (int j = 0; j < 4; ++j) acc[i][j] = {0.f, 0.f, 0.f, 0.f};

  for (int k0 = 0; k0 < 64; k0 += 32) {
    __syncthreads();
#pragma unroll
    for (int i = 0; i < 4; ++i) {  // K staging: 32 groups / 8 waves
      const int g = w * 4 + i;
      const int hl = g >> 4, ms = g & 15;
      const int r = ms * 16 + brow_l;
      const u16* src = (hl ? klb : khb) + (long long)r * 768 + k0 + bchunk;
      gld_lds16(src, (hl ? smB1 : smB0) + ms * 512 + lane * 8);
    }
#pragma unroll
    for (int i = 0; i < 2; ++i) {  // Q staging: 128 rows / 2 rounds
      const int r = i * 64 + ar;
      const float4 v = *(const float4*)(qb + (long long)r * 768 + k0 + ac);
      const float vv[4] = {v.x * 0.125f, v.y * 0.125f, v.z * 0.125f,
                           v.w * 0.125f};
      us4v hh, ll;
#pragma unroll
      for (int j = 0; j < 4; ++j) {
        u16 hb = bf16_rne(vv[j]);
        hh[j] = hb;
        ll[j] = bf16_rne(vv[j] - bf16_to_f(hb));
      }
      *(us4v*)&smA0[r * 32 + adst] = hh;
      *(us4v*)&smA1[r * 32 + adst] = ll;
    }
    __syncthreads();
#pragma unroll
    for (int mi = 0; mi < 4; ++mi) {
      const int r = wr + mi * 16 + fr;
      const bf8v a0 = *(const bf8v*)&smA0[r * 32 + fco];
      const bf8v a1 = *(const bf8v*)&smA1[r * 32 + fco];
#pragma unroll
      for (int nj = 0; nj < 4; ++nj) {
        const int rb = wc + nj * 16 + fr;
        const bf8v b0 = *(const bf8v*)&smB0[rb * 32 + fco];
        const bf8v b1 = *(const bf8v*)&smB1[rb * 32 + fco];
        acc[mi][nj] = __builtin_amdgcn_mfma_f32_16x16x32_bf16(a0, b0, acc[mi][nj], 0, 0, 0);
        acc[mi][nj] = __builtin_amdgcn_mfma_f32_16x16x32_bf16(a0, b1, acc[mi][nj], 0, 0, 0);
        acc[mi][nj] = __builtin_amdgcn_mfma_f32_16x16x32_bf16(a1, b0, acc[mi][nj], 0, 0, 0);
      }
    }
  }
  __syncthreads();  // smA/smB dead; Pbuf region reusable

  // ---- phase 2: softmax (cross-wave via LDS partials) ----
  // row max of this wave's 64-key slice
#pragma unroll
  for (int mi = 0; mi < 4; ++mi)
#pragma unroll
    for (int j = 0; j < 4; ++j) {
      float m = fmaxf(fmaxf(acc[mi][0][j], acc[mi][1][j]),
                      fmaxf(acc[mi][2][j], acc[mi][3][j]));
#pragma unroll
      for (int o = 1; o < 16; o <<= 1) m = fmaxf(m, __shfl_xor(m, o));
      if (fr == 0) partial[(w & 3) * 128 + wr + mi * 16 + fq * 4 + j] = m;
    }
  __syncthreads();
  if (t < 128)
    rowmax[t] = fmaxf(fmaxf(partial[t], partial[128 + t]),
                      fmaxf(partial[256 + t], partial[384 + t]));
  __syncthreads();
  // exp (unnormalized) -> P hi into swizzled LDS planes; accumulate row sums
#pragma unroll
  for (int mi = 0; mi < 4; ++mi)
#pragma unroll
    for (int j = 0; j < 4; ++j) {
      const int row = wr + mi * 16 + fq * 4 + j;
      const float rm = rowmax[row];
      float s = 0.f;
#pragma unroll
      for (int nj = 0; nj < 4; ++nj) {
        const float e = expf(acc[mi][nj][j] - rm);
        s += e;
        const int col = wc + nj * 16 + fr;
        const int kc = col >> 5, kloc = col & 31;
        Pbuf[kc * 4096 + row * 32 + (((kloc >> 3) ^ ((row >> 1) & 3)) * 8) +
             (kloc & 7)] = bf16_rne(e);
      }
#pragma unroll
      for (int o = 1; o < 16; o <<= 1) s += __shfl_xor(s, o);
      if (fr == 0) partial[(w & 3) * 128 + row] = s;
    }
  __syncthreads();
  if (t < 128)
    rowsum[t] = (partial[t] + partial[128 + t]) + (partial[256 + t] + partial[384 + t]);

  // ---- phase 3: PV ; wave tile 32q x 32dh ----
  const int wrp = (w >> 1) * 32, wcp = (w & 1) * 32;
  f4v acc2[2][2];
#pragma unroll
  for (int i = 0; i < 2; ++i)
#pragma unroll
    for (int j = 0; j < 2; ++j) acc2[i][j] = {0.f, 0.f, 0.f, 0.f};

  for (int kc = 0; kc < 8; ++kc) {
    __syncthreads();
    {  // V chunk staging: 8 groups / 8 waves
      const int hl = w >> 2, ms = w & 3;
      const int r = ms * 16 + brow_l;  // dh
      const u16* src =
          (hl ? vtl : vth) + vbase + (long long)r * 256 + kc * 32 + bchunk;
      gld_lds16(src, (hl ? smV1 : smV0) + ms * 512 + lane * 8);
    }
    __syncthreads();
#pragma unroll
    for (int mi = 0; mi < 2; ++mi) {
      const bf8v pa =
          *(const bf8v*)&Pbuf[kc * 4096 + (wrp + mi * 16 + fr) * 32 + fco];
#pragma unroll
      for (int nj = 0; nj < 2; ++nj) {
        const int rv = wcp + nj * 16 + fr;
        const bf8v v0 = *(const bf8v*)&smV0[rv * 32 + fco];
        const bf8v v1 = *(const bf8v*)&smV1[rv * 32 + fco];
        acc2[mi][nj] = __builtin_amdgcn_mfma_f32_16x16x32_bf16(pa, v0, acc2[mi][nj], 0, 0, 0);
        acc2[mi][nj] = __builtin_amdgcn_mfma_f32_16x16x32_bf16(pa, v1, acc2[mi][nj], 0, 0, 0);
      }
    }
  }
  // ---- epilogue: divide by row sum, write ----
  float* ob = outp + ((long long)b * 4096 + q0) * 768 + h * 64;
#pragma unroll
  for (int mi = 0; mi < 2; ++mi)
#pragma unroll
    for (int nj = 0; nj < 2; ++nj)
#pragma unroll
      for (int j = 0; j < 4; ++j) {
        const int row = wrp + mi * 16 + fq * 4 + j;
        const int col = wcp + nj * 16 + fr;
        ob[(long long)row * 768 + col] = acc2[mi][nj][j] / rowsum[row];
      }
}

// ---------------- conv pool -> split bf16 hi/lo, [b,h,t,dh] layout ----------
__global__ __launch_bounds__(256) void conv_split_kernel(
    const float* __restrict__ in, const float* __restrict__ w,
    u16* __restrict__ hi, u16* __restrict__ lo, int total) {
  int idx = blockIdx.x * 256 + threadIdx.x;
  if (idx >= total) return;
  const int dh = idx & 63;
  int r = idx >> 6;
  const int tt = r & 1023; r >>= 10;
  const int h = r % 12;
  const int b = r / 12;
  const float* s = in + ((long long)(b * 4096 + 4 * tt)) * 768 + h * 64 + dh;
  const float* wh = w + h * 4;
  const float v = fmaf(wh[0], s[0],
                  fmaf(wh[1], s[768], fmaf(wh[2], s[1536], wh[3] * s[2304])));
  const u16 hb = bf16_rne(v);
  hi[idx] = hb;
  lo[idx] = bf16_rne(v - bf16_to_f(hb));
}

// ---------------- conv pool -> split, TRANSPOSED [b,h,dh,t] layout ----------
__global__ __launch_bounds__(256) void conv_splitT_kernel(
    const float* __restrict__ in, const float* __restrict__ w,
    u16* __restrict__ hi, u16* __restrict__ lo, int total) {
  int idx = blockIdx.x * 256 + threadIdx.x;
  if (idx >= total) return;
  const int tt = idx & 1023;
  int r = idx >> 10;
  const int dh = r & 63; r >>= 6;
  const int h = r % 12;
  const int b = r / 12;
  const float* s = in + ((long long)(b * 4096 + 4 * tt)) * 768 + h * 64 + dh;
  const float* wh = w + h * 4;
  const float v = fmaf(wh[0], s[0],
                  fmaf(wh[1], s[768], fmaf(wh[2], s[1536], wh[3] * s[2304])));
  const u16 hb = bf16_rne(v);
  hi[idx] = hb;
  lo[idx] = bf16_rne(v - bf16_to_f(hb));
}

// ---------------- transpose+split: [4,256,768] -> [b,h,dh,key] hi/lo --------
__global__ __launch_bounds__(256) void splitT_kernel(
    const float* __restrict__ in, u16* __restrict__ hi, u16* __restrict__ lo,
    int total) {
  int idx = blockIdx.x * 256 + threadIdx.x;
  if (idx >= total) return;
  const int key = idx & 255;
  int r = idx >> 8;
  const int dh = r & 63; r >>= 6;
  const int h = r % 12;
  const int b = r / 12;
  const float v = in[((long long)(b * 256 + key)) * 768 + h * 64 + dh];
  const u16 hb = bf16_rne(v);
  hi[idx] = hb;
  lo[idx] = bf16_rne(v - bf16_to_f(hb));
}

// ---------------- row softmax (in place), rowlen = ITERS*256 ----------------
template <int ITERS>
__global__ __launch_bounds__(256) void softmax_kernel(float* __restrict__ data) {
  const long long row = blockIdx.x;
  float* p = data + row * (ITERS * 256);
  const int t = threadIdx.x;
  __shared__ float red[4];
  float v[ITERS];
  float lmax = -3.4e38f;
#pragma unroll
  for (int i = 0; i < ITERS; ++i) {
    v[i] = p[t + (i << 8)];
    lmax = fmaxf(lmax, v[i]);
  }
  for (int o = 32; o; o >>= 1) lmax = fmaxf(lmax, __shfl_xor(lmax, o));
  if ((t & 63) == 0) red[t >> 6] = lmax;
  __syncthreads();
  const float gmax = fmaxf(fmaxf(red[0], red[1]), fmaxf(red[2], red[3]));
  float lsum = 0.f;
#pragma unroll
  for (int i = 0; i < ITERS; ++i) {
    v[i] = expf(v[i] - gmax);
    lsum += v[i];
  }
  __syncthreads();
  for (int o = 32; o; o >>= 1) lsum += __shfl_xor(lsum, o);
  if ((t & 63) == 0) red[t >> 6] = lsum;
  __syncthreads();
  const float inv = 1.f / (red[0] + red[1] + red[2] + red[3]);
#pragma unroll
  for (int i = 0; i < ITERS; ++i) p[t + (i << 8)] = v[i] * inv;
}

// ---------------- LayerNorm(a + b*maskf), eps 1e-6, width 768 ----------------
__global__ __launch_bounds__(256) void ln_kernel(
    const float* __restrict__ a, const float* __restrict__ b,
    const int* __restrict__ mask, float* __restrict__ out) {
  const long long row = blockIdx.x;
  const float* pa = a + row * 768;
  const float* pb = b + row * 768;
  const float ms = mask ? (float)mask[row] : 1.f;
  __shared__ float buf[768];
  __shared__ float red[4];
  const int t = threadIdx.x;
  float lsum = 0.f;
#pragma unroll
  for (int i = t; i < 768; i += 256) {
    const float v = fmaf(pb[i], ms, pa[i]);
    buf[i] = v;
    lsum += v;
  }
  for (int o = 32; o; o >>= 1) lsum += __shfl_xor(lsum, o);
  if ((t & 63) == 0) red[t >> 6] = lsum;
  __syncthreads();
  const float mu = (red[0] + red[1] + red[2] + red[3]) * (1.f / 768.f);
  float lvar = 0.f;
#pragma unroll
  for (int i = t; i < 768; i += 256) {
    const float d = buf[i] - mu;
    lvar = fmaf(d, d, lvar);
  }
  __syncthreads();
  for (int o = 32; o; o >>= 1) lvar += __shfl_xor(lvar, o);
  if ((t & 63) == 0) red[t >> 6] = lvar;
  __syncthreads();
  const float var = (red[0] + red[1] + red[2] + red[3]) * (1.f / 768.f);
  const float rstd = rsqrtf(var + 1e-6f);
  float* po = out + row * 768;
#pragma unroll
  for (int i = t; i < 768; i += 256) po[i] = (buf[i] - mu) * rstd;
}

// ---------------- host helpers ----------------
static inline void mgemm(hipStream_t st, const float* A, const u16* Bh,
                         const u16* Bl, float* C, int M, int N, int K, int lda,
                         int ldb, int ldc, long long aSB, long long aSH,
                         long long bSB, long long bSH, long long cSB,
                         long long cSH, int nBat, int HB, float scale, int bn,
                         int gelu) {
  if (bn == 128) {
    dim3 g(N / 128, M / 128, nBat);
    if (gelu)
      mgemm_kernel<128, 1><<<g, 256, 0, st>>>(A, Bh, Bl, C, M, N, K, lda, ldb,
                                              ldc, aSB, aSH, bSB, bSH, cSB, cSH,
                                              HB, scale);
    else
      mgemm_kernel<128, 0><<<g, 256, 0, st>>>(A, Bh, Bl, C, M, N, K, lda, ldb,
                                              ldc, aSB, aSH, bSB, bSH, cSB, cSH,
                                              HB, scale);
  } else {
    dim3 g(N / 64, M / 128, nBat);
    mgemm_kernel<64, 0><<<g, 256, 0, st>>>(A, Bh, Bl, C, M, N, K, lda, ldb, ldc,
                                           aSB, aSH, bSB, bSH, cSB, cSH, HB,
                                           scale);
  }
}

static inline void split_launch(hipStream_t st, const float* in, u16* hi,
                                u16* lo, int n) {
  int n4 = n / 4;
  split_kernel<<<(n4 + 255) / 256, 256, 0, st>>>(in, hi, lo, n4);
}

extern "C" void kernel_launch(void* const* d_in, const int* in_sizes, int n_in,
                              void* d_out, int out_size, void* d_ws,
                              size_t ws_size, hipStream_t stream) {
  const float* x = (const float*)d_in[0];       // [4,4096,768]
  const float* memory = (const float*)d_in[1];  // [4,256,768]
  const int* mask = (const int*)d_in[2];        // [4,4096]
  const float* Wq = (const float*)d_in[3];
  const float* Wk = (const float*)d_in[4];
  const float* Wv = (const float*)d_in[5];
  const float* Wo = (const float*)d_in[6];
  const float* conv_w = (const float*)d_in[7];  // [12,1,4,1]
  const float* Uq = (const float*)d_in[8];
  const float* Uk = (const float*)d_in[9];
  const float* Uv = (const float*)d_in[10];
  const float* Uo = (const float*)d_in[11];
  const float* W1 = (const float*)d_in[12];  // [3072,768]
  const float* W2 = (const float*)d_in[13];  // [768,3072]
  float* out = (float*)d_out;  // q_out [4,4096,768] then m_out [4,256,768]
  float* ws = (float*)d_ws;

  const int XR = 16384, MR = 1024, D = 768, MLP = 3072;
  const long long CB = 3145728;  // 4096*768
  const int WD = 589824;         // 768*768
  const int WM = 2359296;        // 3072*768

  // ---- workspace (floats); total 40,894,464 = 163.6 MB ----
  float* slotA = ws + 0;         // 12.58M: kproj -> pack-logits -> uattvm -> hbuf
  float* slotB = ws + 12582912;  // 12.58M: vproj -> uq -> unp/qout1
  float* slotC = ws + 25165824;  //  3.15M: y_b
  float* X     = ws + 28311552;  //  6.29M: kp/vpT splits -> U+ukb/uvT -> W1/W2
  float* qproj = ws + 34603008;  //  786K
  float* attvm = ws + 35389440;  //  786K
  float* packed= ws + 36175872;  //  786K
  float* ukb   = ws + 36962304;  //  786K
  float* uvb   = ws + 37748736;  //  786K
  float* Wp    = ws + 38535168;  //  2.36M: pack-weight splits

  u16* wp16 = (u16*)Wp;
  u16 *Wkh = wp16, *Wkl = wp16 + WD, *Wvh = wp16 + 2 * WD, *Wvl = wp16 + 3 * WD,
      *Wqh = wp16 + 4 * WD, *Wql = wp16 + 5 * WD, *Woh = wp16 + 6 * WD,
      *Wol = wp16 + 7 * WD;
  u16* xk = (u16*)X;
  u16 *kph = xk, *kpl = xk + 3145728, *vph = xk + 6291456, *vpl = xk + 9437184;
  u16 *Uqh = xk, *Uql = xk + WD, *Ukh = xk + 2 * WD, *Ukl = xk + 3 * WD,
      *Uvh = xk + 4 * WD, *Uvl = xk + 5 * WD, *Uoh = xk + 6 * WD,
      *Uol = xk + 7 * WD;
  u16 *ukbh = xk + 4718592, *ukbl = xk + 5505024;
  u16 *uvth = xk + 6291456, *uvtl = xk + 7077888;
  u16 *W1h = xk, *W1l = xk + WM, *W2h = xk + 2 * WM, *W2l = xk + 3 * WM;

  // ---- pack phase ----
  split_launch(stream, Wk, Wkh, Wkl, WD);
  split_launch(stream, Wv, Wvh, Wvl, WD);
  split_launch(stream, Wq, Wqh, Wql, WD);
  split_launch(stream, Wo, Woh, Wol, WD);
  mgemm(stream, x, Wkh, Wkl, slotA, XR, D, D, D, D, D, 0, 0, 0, 0, 0, 0, 1, 1, 1.f, 128, 0);
  mgemm(stream, x, Wvh, Wvl, slotB, XR, D, D, D, D, D, 0, 0, 0, 0, 0, 0, 1, 1, 1.f, 128, 0);
  mgemm(stream, memory, Wqh, Wql, qproj, MR, D, D, D, D, D, 0, 0, 0, 0, 0, 0, 1, 1, 1.f, 128, 0);
  conv_split_kernel<<<12288, 256, 0, stream>>>(slotA, conv_w, kph, kpl, 3145728);
  conv_splitT_kernel<<<12288, 256, 0, stream>>>(slotB, conv_w, vph, vpl, 3145728);
  // pack logits [b,h,256,1024] = qproj @ kp^T (K=64)
  mgemm(stream, qproj, kph, kpl, slotA, 256, 1024, 64, 768, 64, 1024,
        196608, 64, 786432, 65536, 3145728, 262144, 48, 12, 1.f, 128, 0);
  softmax_kernel<4><<<12288, 256, 0, stream>>>(slotA);
  // pack PV: [256,64] per (b,h), K=1024, Vt [b,h,64,1024]
  mgemm(stream, slotA, vph, vpl, attvm, 256, 64, 1024, 1024, 1024, 768,
        3145728, 262144, 786432, 65536, 196608, 64, 48, 12, 1.f, 64, 0);
  mgemm(stream, attvm, Woh, Wol, packed, MR, D, D, D, D, D, 0, 0, 0, 0, 0, 0, 1, 1, 1.f, 128, 0);
  ln_kernel<<<MR, 256, 0, stream>>>(memory, packed, nullptr, out + 12582912);

  // ---- unpack phase (kp/vpT dead -> X hosts U + kv splits) ----
  split_launch(stream, Uq, Uqh, Uql, WD);
  split_launch(stream, Uk, Ukh, Ukl, WD);
  split_launch(stream, Uv, Uvh, Uvl, WD);
  split_launch(stream, Uo, Uoh, Uol, WD);
  mgemm(stream, x, Uqh, Uql, slotB, XR, D, D, D, D, D, 0, 0, 0, 0, 0, 0, 1, 1, 1.f, 128, 0);  // uq
  mgemm(stream, packed, Ukh, Ukl, ukb, MR, D, D, D, D, D, 0, 0, 0, 0, 0, 0, 1, 1, 1.f, 128, 0);
  mgemm(stream, packed, Uvh, Uvl, uvb, MR, D, D, D, D, D, 0, 0, 0, 0, 0, 0, 1, 1, 1.f, 128, 0);
  split_launch(stream, ukb, ukbh, ukbl, 786432);
  splitT_kernel<<<3072, 256, 0, stream>>>(uvb, uvth, uvtl, 786432);
  // fused attention: uq (slotB) -> uattvm (slotA)
  {
    dim3 g(32, 1, 48);
    fused_unpack_attn<<<g, 512, 0, stream>>>(slotB, ukbh, ukbl, uvth, uvtl, slotA);
  }
  // unp = uattvm @ Uo^T (z-batched over 4) -> slotB; then LN in-place
  mgemm(stream, slotA, Uoh, Uol, slotB, 4096, D, D, D, D, D,
        CB, 0, 0, 0, CB, 0, 4, 1, 1.f, 128, 0);
  ln_kernel<<<XR, 256, 0, stream>>>(x, slotB, mask, slotB);

  // ---- FFN phase (U/ukb splits dead -> X hosts W1/W2 splits) ----
  split_launch(stream, W1, W1h, W1l, WM);
  split_launch(stream, W2, W2h, W2l, WM);
  for (int b = 0; b < 4; ++b) {
    mgemm(stream, slotB + b * CB, W1h, W1l, slotA, 4096, MLP, D, D, D, MLP,
          0, 0, 0, 0, 0, 0, 1, 1, 1.f, 128, 1);
    mgemm(stream, slotA, W2h, W2l, slotC, 4096, D, MLP, MLP, MLP, D,
          0, 0, 0, 0, 0, 0, 1, 1, 1.f, 64, 0);
    ln_kernel<<<4096, 256, 0, stream>>>(slotB + b * CB, slotC, mask + b * 4096,
                                        out + b * CB);
  }
}

// Round 6
// 1683.130 us; speedup vs baseline: 1.2420x; 1.0139x over previous
//
#include <hip/hip_runtime.h>
#include <hip/hip_bf16.h>
#include <math.h>

// ----------------------------------------------------------------------------
// vMFLunaBlock v6: v5 + XCD-aware block swizzle in mgemm + un-chunked FFN
// (runtime ws_size branch). Shapes: B=4 S=4096 M=256 D=768 H=12 Dh=64 MLP=3072
// Base workspace: 40,894,464 floats = 163.6 MB; big-FFN path adds 50,331,648
// floats (hbuf) -> 364.9 MB total, used only when ws_size permits.
// ----------------------------------------------------------------------------

typedef unsigned short u16;
typedef __attribute__((ext_vector_type(8))) short bf8v;   // 8 bf16 (4 VGPR)
typedef __attribute__((ext_vector_type(4))) float f4v;
typedef __attribute__((ext_vector_type(4))) unsigned short us4v;

#define AS1 __attribute__((address_space(1)))
#define AS3 __attribute__((address_space(3)))

__device__ __forceinline__ void gld_lds16(const void* g, void* l) {
  __builtin_amdgcn_global_load_lds((const AS1 unsigned int*)g,
                                   (AS3 unsigned int*)l, 16, 0, 0);
}

__device__ __forceinline__ u16 bf16_rne(float x) {
  unsigned u = __float_as_uint(x);
  return (u16)((u + 0x7fffu + ((u >> 16) & 1u)) >> 16);
}
__device__ __forceinline__ float bf16_to_f(u16 h) {
  return __uint_as_float(((unsigned)h) << 16);
}

// ---------------- split fp32 -> (hi, lo) bf16 (vectorized x4) ----------------
__global__ __launch_bounds__(256) void split_kernel(
    const float* __restrict__ in, u16* __restrict__ hi, u16* __restrict__ lo,
    int n4) {
  int i = blockIdx.x * 256 + threadIdx.x;
  if (i >= n4) return;
  float4 v = ((const float4*)in)[i];
  us4v h, l;
  float vv[4] = {v.x, v.y, v.z, v.w};
#pragma unroll
  for (int j = 0; j < 4; ++j) {
    u16 hb = bf16_rne(vv[j]);
    h[j] = hb;
    l[j] = bf16_rne(vv[j] - bf16_to_f(hb));
  }
  ((us4v*)hi)[i] = h;
  ((us4v*)lo)[i] = l;
}

// ---------------- split-bf16 MFMA GEMM (batched, BN templated) ----------------
// C = scale * (A @ B^T) [+ exact GELU]; A fp32 split in-kernel, B pre-split.
// Tiles: 128 x BN, BK=32. 4 waves (2x2), wave tile 64 x BN/2.
// XCD-aware bijective block swizzle (when nwg%8==0): all col-blocks of an A
// row-panel land on one XCD -> L2 captures the A reuse.
template <int BN, int GELU>
__global__ __launch_bounds__(256) void mgemm_kernel(
    const float* __restrict__ A, const u16* __restrict__ Bh,
    const u16* __restrict__ Bl, float* __restrict__ C, int M, int N, int K,
    int lda, int ldb, int ldc, long long aSB, long long aSH, long long bSB,
    long long bSH, long long cSB, long long cSH, int HB, float scale) {
  constexpr int NJ = BN / 32;   // B frags per wave
  constexpr int GPM = BN / 16;  // 16-row groups per B matrix
  constexpr int LPW = BN / 32;  // B gld_lds issues per wave (2 matrices)
  __shared__ u16 smA[2][4096];      // [128][32] hi/lo
  __shared__ u16 smB[2][BN * 32];   // [BN][32] hi/lo
  const int t = threadIdx.x;
  const int w = t >> 6, lane = t & 63;
  const int z = blockIdx.z;
  const int bb = z / HB, hh = z % HB;
  const float* Ab = A + bb * aSB + hh * aSH;
  const u16* Bhb = Bh + bb * bSB + hh * bSH;
  const u16* Blb = Bl + bb * bSB + hh * bSH;
  float* Cb = C + bb * cSB + hh * cSH;

  // XCD swizzle (bijective when nwg%8==0; identity otherwise)
  const int gx = gridDim.x;
  const int nwg = gx * gridDim.y;
  int f = blockIdx.x + gx * blockIdx.y;
  if ((nwg & 7) == 0) {
    const int cpx = nwg >> 3;
    f = (f & 7) * cpx + (f >> 3);
  }
  const int row0 = (f / gx) * 128, col0 = (f % gx) * BN;

  const int brow_l = lane >> 2;
  const int bchunk = ((lane & 3) ^ ((lane >> 3) & 3)) * 8;
  const int ar = t >> 3;
  const int ac = (t & 7) * 4;
  const int adst = ((((t >> 1) & 3) ^ ((t >> 4) & 3)) * 8) + ((t & 1) * 4);
  const int fr = lane & 15;
  const int fq = lane >> 4;
  const int fco = (fq ^ ((lane >> 1) & 3)) * 8;
  const int wr = (w >> 1) * 64, wc = (w & 1) * (BN / 2);

  f4v acc[4][NJ];
#pragma unroll
  for (int i = 0; i < 4; ++i)
#pragma unroll
    for (int j = 0; j < NJ; ++j) acc[i][j] = {0.f, 0.f, 0.f, 0.f};

  for (int k0 = 0; k0 < K; k0 += 32) {
    __syncthreads();
#pragma unroll
    for (int i = 0; i < LPW; ++i) {
      const int g = w * LPW + i;
      const int hl = g / GPM, ms = g % GPM;
      const int r = ms * 16 + brow_l;
      const u16* src =
          (hl ? Blb : Bhb) + (long long)(col0 + r) * ldb + k0 + bchunk;
      gld_lds16(src, &smB[hl][ms * 512 + lane * 8]);
    }
#pragma unroll
    for (int i = 0; i < 4; ++i) {
      const int r = i * 32 + ar;
      const float4 v = *(const float4*)(Ab + (long long)(row0 + r) * lda + k0 + ac);
      const float vv[4] = {v.x, v.y, v.z, v.w};
      us4v h, l;
#pragma unroll
      for (int j = 0; j < 4; ++j) {
        u16 hb = bf16_rne(vv[j]);
        h[j] = hb;
        l[j] = bf16_rne(vv[j] - bf16_to_f(hb));
      }
      *(us4v*)&smA[0][r * 32 + adst] = h;
      *(us4v*)&smA[1][r * 32 + adst] = l;
    }
    __syncthreads();
    bf8v af[4][2], bf[NJ][2];
#pragma unroll
    for (int mi = 0; mi < 4; ++mi) {
      const int r = wr + mi * 16 + fr;
      af[mi][0] = *(const bf8v*)&smA[0][r * 32 + fco];
      af[mi][1] = *(const bf8v*)&smA[1][r * 32 + fco];
    }
#pragma unroll
    for (int nj = 0; nj < NJ; ++nj) {
      const int r = wc + nj * 16 + fr;
      bf[nj][0] = *(const bf8v*)&smB[0][r * 32 + fco];
      bf[nj][1] = *(const bf8v*)&smB[1][r * 32 + fco];
    }
#pragma unroll
    for (int mi = 0; mi < 4; ++mi)
#pragma unroll
      for (int nj = 0; nj < NJ; ++nj) {
        acc[mi][nj] = __builtin_amdgcn_mfma_f32_16x16x32_bf16(
            af[mi][0], bf[nj][0], acc[mi][nj], 0, 0, 0);
        acc[mi][nj] = __builtin_amdgcn_mfma_f32_16x16x32_bf16(
            af[mi][0], bf[nj][1], acc[mi][nj], 0, 0, 0);
        acc[mi][nj] = __builtin_amdgcn_mfma_f32_16x16x32_bf16(
            af[mi][1], bf[nj][0], acc[mi][nj], 0, 0, 0);
      }
  }
#pragma unroll
  for (int mi = 0; mi < 4; ++mi)
#pragma unroll
    for (int nj = 0; nj < NJ; ++nj) {
      const int col = col0 + wc + nj * 16 + fr;
      const long long base =
          (long long)(row0 + wr + mi * 16 + fq * 4) * ldc + col;
#pragma unroll
      for (int j = 0; j < 4; ++j) {
        float v = acc[mi][nj][j] * scale;
        if (GELU) v = 0.5f * v * (1.f + erff(v * 0.70710678118654752f));
        Cb[base + (long long)j * ldc] = v;
      }
    }
}

// ---------------- fused unpack attention (MFMA, flash-style) ----------------
// Per block: (b,h), 128 q rows, all 256 keys. 512 threads (8 waves).
__global__ __launch_bounds__(512) void fused_unpack_attn(
    const float* __restrict__ q, const u16* __restrict__ kh,
    const u16* __restrict__ kl, const u16* __restrict__ vth,
    const u16* __restrict__ vtl, float* __restrict__ outp) {
  __shared__ char pool[76800];
  u16* smA0 = (u16*)pool;                 // [128*32] Q hi (phase 1)
  u16* smA1 = (u16*)(pool + 8192);        // Q lo
  u16* smB0 = (u16*)(pool + 16384);       // [256*32] K hi
  u16* smB1 = (u16*)(pool + 32768);       // K lo
  u16* Pbuf = (u16*)pool;                 // [8][128*32] P hi (phase 2)
  u16* smV0 = (u16*)(pool + 65536);       // [64*32] V hi
  u16* smV1 = (u16*)(pool + 69632);       // V lo
  float* partial = (float*)(pool + 73728);  // [4][128]
  float* rowmax = (float*)(pool + 75776);   // [128]
  float* rowsum = (float*)(pool + 76288);   // [128]

  const int t = threadIdx.x;
  const int w = t >> 6, lane = t & 63;
  const int z = blockIdx.z;
  const int b = z / 12, h = z % 12;
  const int q0 = blockIdx.x * 128;

  const float* qb = q + ((long long)b * 4096 + q0) * 768 + h * 64;
  const u16* khb = kh + ((long long)b * 256) * 768 + h * 64;
  const u16* klb = kl + ((long long)b * 256) * 768 + h * 64;
  const long long vbase = ((long long)(b * 12 + h)) * 16384;  // 64*256

  const int fr = lane & 15, fq = lane >> 4;
  const int fco = (fq ^ ((lane >> 1) & 3)) * 8;
  const int brow_l = lane >> 2;
  const int bchunk = ((lane & 3) ^ ((lane >> 3) & 3)) * 8;
  const int ar = t >> 3;          // [0,64)
  const int ac = (t & 7) * 4;
  const int adst = ((((t >> 1) & 3) ^ ((t >> 4) & 3)) * 8) + ((t & 1) * 4);

  // ---- phase 1: logits = (Q/8) @ K^T ; wave tile 64q x 64keys ----
  const int wr = (w >> 2) * 64, wc = (w & 3) * 64;
  f4v acc[4][4];
#pragma unroll
  for (int i = 0; i < 4; ++i)
#pragma unroll
    for (int j = 0; j < 4; ++j) acc[i][j] = {0.f, 0.f, 0.f, 0.f};

  for (int k0 = 0; k0 < 64; k0 += 32) {
    __syncthreads();
#pragma unroll
    for (int i = 0; i < 4; ++i) {  // K staging: 32 groups / 8 waves
      const int g = w * 4 + i;
      const int hl = g >> 4, ms = g & 15;
      const int r = ms * 16 + brow_l;
      const u16* src = (hl ? klb : khb) + (long long)r * 768 + k0 + bchunk;
      gld_lds16(src, (hl ? smB1 : smB0) + ms * 512 + lane * 8);
    }
#pragma unroll
    for (int i = 0; i < 2; ++i) {  // Q staging: 128 rows / 2 rounds
      const int r = i * 64 + ar;
      const float4 v = *(const float4*)(qb + (long long)r * 768 + k0 + ac);
      const float vv[4] = {v.x * 0.125f, v.y * 0.125f, v.z * 0.125f,
                           v.w * 0.125f};
      us4v hh, ll;
#pragma unroll
      for (int j = 0; j < 4; ++j) {
        u16 hb = bf16_rne(vv[j]);
        hh[j] = hb;
        ll[j] = bf16_rne(vv[j] - bf16_to_f(hb));
      }
      *(us4v*)&smA0[r * 32 + adst] = hh;
      *(us4v*)&smA1[r * 32 + adst] = ll;
    }
    __syncthreads();
#pragma unroll
    for (int mi = 0; mi < 4; ++mi) {
      const int r = wr + mi * 16 + fr;
      const bf8v a0 = *(const bf8v*)&smA0[r * 32 + fco];
      const bf8v a1 = *(const bf8v*)&smA1[r * 32 + fco];
#pragma unroll
      for (int nj = 0; nj < 4; ++nj) {
        const int rb = wc + nj * 16 + fr;
        const bf8v b0 = *(const bf8v*)&smB0[rb * 32 + fco];
        const bf8v b1 = *(const bf8v*)&smB1[rb * 32 + fco];
        acc[mi][nj] = __builtin_amdgcn_mfma_f32_16x16x32_bf16(a0, b0, acc[mi][nj], 0, 0, 0);
        acc[mi][nj] = __builtin_amdgcn_mfma_f32_16x16x32_bf16(a0, b1, acc[mi][nj], 0, 0, 0);
        acc[mi][nj] = __builtin_amdgcn_mfma_f32_16x16x32_bf16(a1, b0, acc[mi][nj], 0, 0, 0);
      }
    }
  }
  __syncthreads();  // smA/smB dead; Pbuf region reusable

  // ---- phase 2: softmax (cross-wave via LDS partials) ----
#pragma unroll
  for (int mi = 0; mi < 4; ++mi)
#pragma unroll
    for (int j = 0; j < 4; ++j) {
      float m = fmaxf(fmaxf(acc[mi][0][j], acc[mi][1][j]),
                      fmaxf(acc[mi][2][j], acc[mi][3][j]));
#pragma unroll
      for (int o = 1; o < 16; o <<= 1) m = fmaxf(m, __shfl_xor(m, o));
      if (fr == 0) partial[(w & 3) * 128 + wr + mi * 16 + fq * 4 + j] = m;
    }
  __syncthreads();
  if (t < 128)
    rowmax[t] = fmaxf(fmaxf(partial[t], partial[128 + t]),
                      fmaxf(partial[256 + t], partial[384 + t]));
  __syncthreads();
#pragma unroll
  for (int mi = 0; mi < 4; ++mi)
#pragma unroll
    for (int j = 0; j < 4; ++j) {
      const int row = wr + mi * 16 + fq * 4 + j;
      const float rm = rowmax[row];
      float s = 0.f;
#pragma unroll
      for (int nj = 0; nj < 4; ++nj) {
        const float e = expf(acc[mi][nj][j] - rm);
        s += e;
        const int col = wc + nj * 16 + fr;
        const int kc = col >> 5, kloc = col & 31;
        Pbuf[kc * 4096 + row * 32 + (((kloc >> 3) ^ ((row >> 1) & 3)) * 8) +
             (kloc & 7)] = bf16_rne(e);
      }
#pragma unroll
      for (int o = 1; o < 16; o <<= 1) s += __shfl_xor(s, o);
      if (fr == 0) partial[(w & 3) * 128 + row] = s;
    }
  __syncthreads();
  if (t < 128)
    rowsum[t] = (partial[t] + partial[128 + t]) + (partial[256 + t] + partial[384 + t]);

  // ---- phase 3: PV ; wave tile 32q x 32dh ----
  const int wrp = (w >> 1) * 32, wcp = (w & 1) * 32;
  f4v acc2[2][2];
#pragma unroll
  for (int i = 0; i < 2; ++i)
#pragma unroll
    for (int j = 0; j < 2; ++j) acc2[i][j] = {0.f, 0.f, 0.f, 0.f};

  for (int kc = 0; kc < 8; ++kc) {
    __syncthreads();
    {  // V chunk staging: 8 groups / 8 waves
      const int hl = w >> 2, ms = w & 3;
      const int r = ms * 16 + brow_l;  // dh
      const u16* src =
          (hl ? vtl : vth) + vbase + (long long)r * 256 + kc * 32 + bchunk;
      gld_lds16(src, (hl ? smV1 : smV0) + ms * 512 + lane * 8);
    }
    __syncthreads();
#pragma unroll
    for (int mi = 0; mi < 2; ++mi) {
      const bf8v pa =
          *(const bf8v*)&Pbuf[kc * 4096 + (wrp + mi * 16 + fr) * 32 + fco];
#pragma unroll
      for (int nj = 0; nj < 2; ++nj) {
        const int rv = wcp + nj * 16 + fr;
        const bf8v v0 = *(const bf8v*)&smV0[rv * 32 + fco];
        const bf8v v1 = *(const bf8v*)&smV1[rv * 32 + fco];
        acc2[mi][nj] = __builtin_amdgcn_mfma_f32_16x16x32_bf16(pa, v0, acc2[mi][nj], 0, 0, 0);
        acc2[mi][nj] = __builtin_amdgcn_mfma_f32_16x16x32_bf16(pa, v1, acc2[mi][nj], 0, 0, 0);
      }
    }
  }
  float* ob = outp + ((long long)b * 4096 + q0) * 768 + h * 64;
#pragma unroll
  for (int mi = 0; mi < 2; ++mi)
#pragma unroll
    for (int nj = 0; nj < 2; ++nj)
#pragma unroll
      for (int j = 0; j < 4; ++j) {
        const int row = wrp + mi * 16 + fq * 4 + j;
        const int col = wcp + nj * 16 + fr;
        ob[(long long)row * 768 + col] = acc2[mi][nj][j] / rowsum[row];
      }
}

// ---------------- conv pool -> split bf16 hi/lo, [b,h,t,dh] layout ----------
__global__ __launch_bounds__(256) void conv_split_kernel(
    const float* __restrict__ in, const float* __restrict__ w,
    u16* __restrict__ hi, u16* __restrict__ lo, int total) {
  int idx = blockIdx.x * 256 + threadIdx.x;
  if (idx >= total) return;
  const int dh = idx & 63;
  int r = idx >> 6;
  const int tt = r & 1023; r >>= 10;
  const int h = r % 12;
  const int b = r / 12;
  const float* s = in + ((long long)(b * 4096 + 4 * tt)) * 768 + h * 64 + dh;
  const float* wh = w + h * 4;
  const float v = fmaf(wh[0], s[0],
                  fmaf(wh[1], s[768], fmaf(wh[2], s[1536], wh[3] * s[2304])));
  const u16 hb = bf16_rne(v);
  hi[idx] = hb;
  lo[idx] = bf16_rne(v - bf16_to_f(hb));
}

// ---------------- conv pool -> split, TRANSPOSED [b,h,dh,t] layout ----------
__global__ __launch_bounds__(256) void conv_splitT_kernel(
    const float* __restrict__ in, const float* __restrict__ w,
    u16* __restrict__ hi, u16* __restrict__ lo, int total) {
  int idx = blockIdx.x * 256 + threadIdx.x;
  if (idx >= total) return;
  const int tt = idx & 1023;
  int r = idx >> 10;
  const int dh = r & 63; r >>= 6;
  const int h = r % 12;
  const int b = r / 12;
  const float* s = in + ((long long)(b * 4096 + 4 * tt)) * 768 + h * 64 + dh;
  const float* wh = w + h * 4;
  const float v = fmaf(wh[0], s[0],
                  fmaf(wh[1], s[768], fmaf(wh[2], s[1536], wh[3] * s[2304])));
  const u16 hb = bf16_rne(v);
  hi[idx] = hb;
  lo[idx] = bf16_rne(v - bf16_to_f(hb));
}

// ---------------- transpose+split: [4,256,768] -> [b,h,dh,key] hi/lo --------
__global__ __launch_bounds__(256) void splitT_kernel(
    const float* __restrict__ in, u16* __restrict__ hi, u16* __restrict__ lo,
    int total) {
  int idx = blockIdx.x * 256 + threadIdx.x;
  if (idx >= total) return;
  const int key = idx & 255;
  int r = idx >> 8;
  const int dh = r & 63; r >>= 6;
  const int h = r % 12;
  const int b = r / 12;
  const float v = in[((long long)(b * 256 + key)) * 768 + h * 64 + dh];
  const u16 hb = bf16_rne(v);
  hi[idx] = hb;
  lo[idx] = bf16_rne(v - bf16_to_f(hb));
}

// ---------------- row softmax (in place), rowlen = ITERS*256 ----------------
template <int ITERS>
__global__ __launch_bounds__(256) void softmax_kernel(float* __restrict__ data) {
  const long long row = blockIdx.x;
  float* p = data + row * (ITERS * 256);
  const int t = threadIdx.x;
  __shared__ float red[4];
  float v[ITERS];
  float lmax = -3.4e38f;
#pragma unroll
  for (int i = 0; i < ITERS; ++i) {
    v[i] = p[t + (i << 8)];
    lmax = fmaxf(lmax, v[i]);
  }
  for (int o = 32; o; o >>= 1) lmax = fmaxf(lmax, __shfl_xor(lmax, o));
  if ((t & 63) == 0) red[t >> 6] = lmax;
  __syncthreads();
  const float gmax = fmaxf(fmaxf(red[0], red[1]), fmaxf(red[2], red[3]));
  float lsum = 0.f;
#pragma unroll
  for (int i = 0; i < ITERS; ++i) {
    v[i] = expf(v[i] - gmax);
    lsum += v[i];
  }
  __syncthreads();
  for (int o = 32; o; o >>= 1) lsum += __shfl_xor(lsum, o);
  if ((t & 63) == 0) red[t >> 6] = lsum;
  __syncthreads();
  const float inv = 1.f / (red[0] + red[1] + red[2] + red[3]);
#pragma unroll
  for (int i = 0; i < ITERS; ++i) p[t + (i << 8)] = v[i] * inv;
}

// ---------------- LayerNorm(a + b*maskf), eps 1e-6, width 768 ----------------
__global__ __launch_bounds__(256) void ln_kernel(
    const float* __restrict__ a, const float* __restrict__ b,
    const int* __restrict__ mask, float* __restrict__ out) {
  const long long row = blockIdx.x;
  const float* pa = a + row * 768;
  const float* pb = b + row * 768;
  const float ms = mask ? (float)mask[row] : 1.f;
  __shared__ float buf[768];
  __shared__ float red[4];
  const int t = threadIdx.x;
  float lsum = 0.f;
#pragma unroll
  for (int i = t; i < 768; i += 256) {
    const float v = fmaf(pb[i], ms, pa[i]);
    buf[i] = v;
    lsum += v;
  }
  for (int o = 32; o; o >>= 1) lsum += __shfl_xor(lsum, o);
  if ((t & 63) == 0) red[t >> 6] = lsum;
  __syncthreads();
  const float mu = (red[0] + red[1] + red[2] + red[3]) * (1.f / 768.f);
  float lvar = 0.f;
#pragma unroll
  for (int i = t; i < 768; i += 256) {
    const float d = buf[i] - mu;
    lvar = fmaf(d, d, lvar);
  }
  __syncthreads();
  for (int o = 32; o; o >>= 1) lvar += __shfl_xor(lvar, o);
  if ((t & 63) == 0) red[t >> 6] = lvar;
  __syncthreads();
  const float var = (red[0] + red[1] + red[2] + red[3]) * (1.f / 768.f);
  const float rstd = rsqrtf(var + 1e-6f);
  float* po = out + row * 768;
#pragma unroll
  for (int i = t; i < 768; i += 256) po[i] = (buf[i] - mu) * rstd;
}

// ---------------- host helpers ----------------
static inline void mgemm(hipStream_t st, const float* A, const u16* Bh,
                         const u16* Bl, float* C, int M, int N, int K, int lda,
                         int ldb, int ldc, long long aSB, long long aSH,
                         long long bSB, long long bSH, long long cSB,
                         long long cSH, int nBat, int HB, float scale, int bn,
                         int gelu) {
  if (bn == 128) {
    dim3 g(N / 128, M / 128, nBat);
    if (gelu)
      mgemm_kernel<128, 1><<<g, 256, 0, st>>>(A, Bh, Bl, C, M, N, K, lda, ldb,
                                              ldc, aSB, aSH, bSB, bSH, cSB, cSH,
                                              HB, scale);
    else
      mgemm_kernel<128, 0><<<g, 256, 0, st>>>(A, Bh, Bl, C, M, N, K, lda, ldb,
                                              ldc, aSB, aSH, bSB, bSH, cSB, cSH,
                                              HB, scale);
  } else {
    dim3 g(N / 64, M / 128, nBat);
    mgemm_kernel<64, 0><<<g, 256, 0, st>>>(A, Bh, Bl, C, M, N, K, lda, ldb, ldc,
                                           aSB, aSH, bSB, bSH, cSB, cSH, HB,
                                           scale);
  }
}

static inline void split_launch(hipStream_t st, const float* in, u16* hi,
                                u16* lo, int n) {
  int n4 = n / 4;
  split_kernel<<<(n4 + 255) / 256, 256, 0, st>>>(in, hi, lo, n4);
}

extern "C" void kernel_launch(void* const* d_in, const int* in_sizes, int n_in,
                              void* d_out, int out_size, void* d_ws,
                              size_t ws_size, hipStream_t stream) {
  const float* x = (const float*)d_in[0];       // [4,4096,768]
  const float* memory = (const float*)d_in[1];  // [4,256,768]
  const int* mask = (const int*)d_in[2];        // [4,4096]
  const float* Wq = (const float*)d_in[3];
  const float* Wk = (const float*)d_in[4];
  const float* Wv = (const float*)d_in[5];
  const float* Wo = (const float*)d_in[6];
  const float* conv_w = (const float*)d_in[7];  // [12,1,4,1]
  const float* Uq = (const float*)d_in[8];
  const float* Uk = (const float*)d_in[9];
  const float* Uv = (const float*)d_in[10];
  const float* Uo = (const float*)d_in[11];
  const float* W1 = (const float*)d_in[12];  // [3072,768]
  const float* W2 = (const float*)d_in[13];  // [768,3072]
  float* out = (float*)d_out;  // q_out [4,4096,768] then m_out [4,256,768]
  float* ws = (float*)d_ws;

  const int XR = 16384, MR = 1024, D = 768, MLP = 3072;
  const long long CB = 3145728;  // 4096*768
  const int WD = 589824;         // 768*768
  const int WM = 2359296;        // 3072*768

  // ---- workspace (floats); base total 40,894,464 = 163.6 MB ----
  float* slotA = ws + 0;         // 12.58M: kproj -> pack-logits -> uattvm -> y
  float* slotB = ws + 12582912;  // 12.58M: vproj -> uq -> unp/qout1
  float* slotC = ws + 25165824;  //  3.15M: y_b (fallback path)
  float* X     = ws + 28311552;  //  6.29M: kp/vpT splits -> U+ukb/uvT -> W1/W2
  float* qproj = ws + 34603008;  //  786K
  float* attvm = ws + 35389440;  //  786K
  float* packed= ws + 36175872;  //  786K
  float* ukb   = ws + 36962304;  //  786K
  float* uvb   = ws + 37748736;  //  786K
  float* Wp    = ws + 38535168;  //  2.36M: pack-weight splits
  float* hbufBig = ws + 40894464;  // 50.33M (big-FFN path only)
  const bool bigFFN = ws_size >= (size_t)(40894464 + 50331648) * 4;

  u16* wp16 = (u16*)Wp;
  u16 *Wkh = wp16, *Wkl = wp16 + WD, *Wvh = wp16 + 2 * WD, *Wvl = wp16 + 3 * WD,
      *Wqh = wp16 + 4 * WD, *Wql = wp16 + 5 * WD, *Woh = wp16 + 6 * WD,
      *Wol = wp16 + 7 * WD;
  u16* xk = (u16*)X;
  u16 *kph = xk, *kpl = xk + 3145728, *vph = xk + 6291456, *vpl = xk + 9437184;
  u16 *Uqh = xk, *Uql = xk + WD, *Ukh = xk + 2 * WD, *Ukl = xk + 3 * WD,
      *Uvh = xk + 4 * WD, *Uvl = xk + 5 * WD, *Uoh = xk + 6 * WD,
      *Uol = xk + 7 * WD;
  u16 *ukbh = xk + 4718592, *ukbl = xk + 5505024;
  u16 *uvth = xk + 6291456, *uvtl = xk + 7077888;
  u16 *W1h = xk, *W1l = xk + WM, *W2h = xk + 2 * WM, *W2l = xk + 3 * WM;

  // ---- pack phase ----
  split_launch(stream, Wk, Wkh, Wkl, WD);
  split_launch(stream, Wv, Wvh, Wvl, WD);
  split_launch(stream, Wq, Wqh, Wql, WD);
  split_launch(stream, Wo, Woh, Wol, WD);
  mgemm(stream, x, Wkh, Wkl, slotA, XR, D, D, D, D, D, 0, 0, 0, 0, 0, 0, 1, 1, 1.f, 128, 0);
  mgemm(stream, x, Wvh, Wvl, slotB, XR, D, D, D, D, D, 0, 0, 0, 0, 0, 0, 1, 1, 1.f, 128, 0);
  mgemm(stream, memory, Wqh, Wql, qproj, MR, D, D, D, D, D, 0, 0, 0, 0, 0, 0, 1, 1, 1.f, 128, 0);
  conv_split_kernel<<<12288, 256, 0, stream>>>(slotA, conv_w, kph, kpl, 3145728);
  conv_splitT_kernel<<<12288, 256, 0, stream>>>(slotB, conv_w, vph, vpl, 3145728);
  // pack logits [b,h,256,1024] = qproj @ kp^T (K=64)
  mgemm(stream, qproj, kph, kpl, slotA, 256, 1024, 64, 768, 64, 1024,
        196608, 64, 786432, 65536, 3145728, 262144, 48, 12, 1.f, 128, 0);
  softmax_kernel<4><<<12288, 256, 0, stream>>>(slotA);
  // pack PV: [256,64] per (b,h), K=1024, Vt [b,h,64,1024]
  mgemm(stream, slotA, vph, vpl, attvm, 256, 64, 1024, 1024, 1024, 768,
        3145728, 262144, 786432, 65536, 196608, 64, 48, 12, 1.f, 64, 0);
  mgemm(stream, attvm, Woh, Wol, packed, MR, D, D, D, D, D, 0, 0, 0, 0, 0, 0, 1, 1, 1.f, 128, 0);
  ln_kernel<<<MR, 256, 0, stream>>>(memory, packed, nullptr, out + 12582912);

  // ---- unpack phase (kp/vpT dead -> X hosts U + kv splits) ----
  split_launch(stream, Uq, Uqh, Uql, WD);
  split_launch(stream, Uk, Ukh, Ukl, WD);
  split_launch(stream, Uv, Uvh, Uvl, WD);
  split_launch(stream, Uo, Uoh, Uol, WD);
  mgemm(stream, x, Uqh, Uql, slotB, XR, D, D, D, D, D, 0, 0, 0, 0, 0, 0, 1, 1, 1.f, 128, 0);  // uq
  mgemm(stream, packed, Ukh, Ukl, ukb, MR, D, D, D, D, D, 0, 0, 0, 0, 0, 0, 1, 1, 1.f, 128, 0);
  mgemm(stream, packed, Uvh, Uvl, uvb, MR, D, D, D, D, D, 0, 0, 0, 0, 0, 0, 1, 1, 1.f, 128, 0);
  split_launch(stream, ukb, ukbh, ukbl, 786432);
  splitT_kernel<<<3072, 256, 0, stream>>>(uvb, uvth, uvtl, 786432);
  // fused attention: uq (slotB) -> uattvm (slotA)
  {
    dim3 g(32, 1, 48);
    fused_unpack_attn<<<g, 512, 0, stream>>>(slotB, ukbh, ukbl, uvth, uvtl, slotA);
  }
  // unp = uattvm @ Uo^T (z-batched over 4) -> slotB; then LN in-place
  mgemm(stream, slotA, Uoh, Uol, slotB, 4096, D, D, D, D, D,
        CB, 0, 0, 0, CB, 0, 4, 1, 1.f, 128, 0);
  ln_kernel<<<XR, 256, 0, stream>>>(x, slotB, mask, slotB);

  // ---- FFN phase (U/ukb splits dead -> X hosts W1/W2 splits) ----
  split_launch(stream, W1, W1h, W1l, WM);
  split_launch(stream, W2, W2h, W2l, WM);
  if (bigFFN) {
    // single big GEMMs: h = gelu(qout1 @ W1^T) [16384,3072]; y = h @ W2^T
    mgemm(stream, slotB, W1h, W1l, hbufBig, XR, MLP, D, D, D, MLP,
          0, 0, 0, 0, 0, 0, 1, 1, 1.f, 128, 1);
    mgemm(stream, hbufBig, W2h, W2l, slotA, XR, D, MLP, MLP, MLP, D,
          0, 0, 0, 0, 0, 0, 1, 1, 1.f, 64, 0);
    ln_kernel<<<XR, 256, 0, stream>>>(slotB, slotA, mask, out);
  } else {
    for (int b = 0; b < 4; ++b) {
      mgemm(stream, slotB + b * CB, W1h, W1l, slotA, 4096, MLP, D, D, D, MLP,
            0, 0, 0, 0, 0, 0, 1, 1, 1.f, 128, 1);
      mgemm(stream, slotA, W2h, W2l, slotC, 4096, D, MLP, MLP, MLP, D,
            0, 0, 0, 0, 0, 0, 1, 1, 1.f, 64, 0);
      ln_kernel<<<4096, 256, 0, stream>>>(slotB + b * CB, slotC,
                                          mask + b * 4096, out + b * CB);
    }
  }
}

// Round 7
// 1639.796 us; speedup vs baseline: 1.2748x; 1.0264x over previous
//
#include <hip/hip_runtime.h>
#include <hip/hip_bf16.h>
#include <math.h>

// ----------------------------------------------------------------------------
// vMFLunaBlock v7: v6 + double-buffered 2-phase mgemm pipeline (issue-early /
// write-late, single barrier per K-step) + merged Wk/Wv projection (N=1536).
// Shapes: B=4 S=4096 M=256 D=768 H=12 Dh=64 MLP=3072
// Base workspace: 40,894,464 floats = 163.6 MB (bigFFN path optional).
// ----------------------------------------------------------------------------

typedef unsigned short u16;
typedef __attribute__((ext_vector_type(8))) short bf8v;   // 8 bf16 (4 VGPR)
typedef __attribute__((ext_vector_type(4))) float f4v;
typedef __attribute__((ext_vector_type(4))) unsigned short us4v;

#define AS1 __attribute__((address_space(1)))
#define AS3 __attribute__((address_space(3)))

__device__ __forceinline__ void gld_lds16(const void* g, void* l) {
  __builtin_amdgcn_global_load_lds((const AS1 unsigned int*)g,
                                   (AS3 unsigned int*)l, 16, 0, 0);
}

__device__ __forceinline__ u16 bf16_rne(float x) {
  unsigned u = __float_as_uint(x);
  return (u16)((u + 0x7fffu + ((u >> 16) & 1u)) >> 16);
}
__device__ __forceinline__ float bf16_to_f(u16 h) {
  return __uint_as_float(((unsigned)h) << 16);
}

// ---------------- split fp32 -> (hi, lo) bf16 (vectorized x4) ----------------
__global__ __launch_bounds__(256) void split_kernel(
    const float* __restrict__ in, u16* __restrict__ hi, u16* __restrict__ lo,
    int n4) {
  int i = blockIdx.x * 256 + threadIdx.x;
  if (i >= n4) return;
  float4 v = ((const float4*)in)[i];
  us4v h, l;
  float vv[4] = {v.x, v.y, v.z, v.w};
#pragma unroll
  for (int j = 0; j < 4; ++j) {
    u16 hb = bf16_rne(vv[j]);
    h[j] = hb;
    l[j] = bf16_rne(vv[j] - bf16_to_f(hb));
  }
  ((us4v*)hi)[i] = h;
  ((us4v*)lo)[i] = l;
}

// ---------------- split-bf16 MFMA GEMM, double-buffered pipeline ------------
// C = scale * (A @ B^T) [+ exact GELU]; A fp32 split in-kernel, B pre-split.
// Tiles: 128 x BN, BK=32. 4 waves (2x2), wave tile 64 x BN/2.
// Pipeline per K-step: {issue B(t+1) gld_lds + A(t+1) global->reg} -> MFMA(t)
// -> {split+ds_write A(t+1)} -> ONE __syncthreads (drain lands after compute).
template <int BN, int GELU>
__global__ __launch_bounds__(256) void mgemm_kernel(
    const float* __restrict__ A, const u16* __restrict__ Bh,
    const u16* __restrict__ Bl, float* __restrict__ C, int M, int N, int K,
    int lda, int ldb, int ldc, long long aSB, long long aSH, long long bSB,
    long long bSH, long long cSB, long long cSH, int HB, float scale) {
  constexpr int NJ = BN / 32;   // B frags per wave
  constexpr int GPM = BN / 16;  // 16-row groups per B matrix
  constexpr int LPW = BN / 32;  // B gld_lds issues per wave (2 matrices)
  __shared__ u16 smA[2][2][4096];     // [buf][hi/lo][128*32]
  __shared__ u16 smB[2][2][BN * 32];  // [buf][hi/lo][BN*32]
  const int t = threadIdx.x;
  const int w = t >> 6, lane = t & 63;
  const int z = blockIdx.z;
  const int bb = z / HB, hh = z % HB;
  const float* Ab = A + bb * aSB + hh * aSH;
  const u16* Bhb = Bh + bb * bSB + hh * bSH;
  const u16* Blb = Bl + bb * bSB + hh * bSH;
  float* Cb = C + bb * cSB + hh * cSH;

  // XCD swizzle (bijective when nwg%8==0; identity otherwise)
  const int gx = gridDim.x;
  const int nwg = gx * gridDim.y;
  int f = blockIdx.x + gx * blockIdx.y;
  if ((nwg & 7) == 0) {
    const int cpx = nwg >> 3;
    f = (f & 7) * cpx + (f >> 3);
  }
  const int row0 = (f / gx) * 128, col0 = (f % gx) * BN;

  const int brow_l = lane >> 2;
  const int bchunk = ((lane & 3) ^ ((lane >> 3) & 3)) * 8;
  const int ar = t >> 3;
  const int ac = (t & 7) * 4;
  const int adst = ((((t >> 1) & 3) ^ ((t >> 4) & 3)) * 8) + ((t & 1) * 4);
  const int fr = lane & 15;
  const int fq = lane >> 4;
  const int fco = (fq ^ ((lane >> 1) & 3)) * 8;
  const int wr = (w >> 1) * 64, wc = (w & 1) * (BN / 2);

  f4v acc[4][NJ];
#pragma unroll
  for (int i = 0; i < 4; ++i)
#pragma unroll
    for (int j = 0; j < NJ; ++j) acc[i][j] = {0.f, 0.f, 0.f, 0.f};

  const int NT = K >> 5;
  float4 aregs[4];

  // ---- prologue: stage tile 0 into buf 0 ----
#pragma unroll
  for (int i = 0; i < LPW; ++i) {
    const int g = w * LPW + i;
    const int hl = g / GPM, ms = g % GPM;
    const int r = ms * 16 + brow_l;
    const u16* src = (hl ? Blb : Bhb) + (long long)(col0 + r) * ldb + bchunk;
    gld_lds16(src, &smB[0][hl][ms * 512 + lane * 8]);
  }
#pragma unroll
  for (int i = 0; i < 4; ++i)
    aregs[i] = *(const float4*)(Ab + (long long)(row0 + i * 32 + ar) * lda + ac);
#pragma unroll
  for (int i = 0; i < 4; ++i) {
    const int r = i * 32 + ar;
    const float vv[4] = {aregs[i].x, aregs[i].y, aregs[i].z, aregs[i].w};
    us4v h, l;
#pragma unroll
    for (int j = 0; j < 4; ++j) {
      u16 hb = bf16_rne(vv[j]);
      h[j] = hb;
      l[j] = bf16_rne(vv[j] - bf16_to_f(hb));
    }
    *(us4v*)&smA[0][0][r * 32 + adst] = h;
    *(us4v*)&smA[0][1][r * 32 + adst] = l;
  }
  __syncthreads();

  for (int tt = 0; tt < NT; ++tt) {
    const int cur = tt & 1, nxt = cur ^ 1;
    const bool more = (tt + 1) < NT;
    if (more) {
      const int k1 = (tt + 1) << 5;
      // issue next B tile (async into LDS) + next A tile (global -> regs)
#pragma unroll
      for (int i = 0; i < LPW; ++i) {
        const int g = w * LPW + i;
        const int hl = g / GPM, ms = g % GPM;
        const int r = ms * 16 + brow_l;
        const u16* src =
            (hl ? Blb : Bhb) + (long long)(col0 + r) * ldb + k1 + bchunk;
        gld_lds16(src, &smB[nxt][hl][ms * 512 + lane * 8]);
      }
#pragma unroll
      for (int i = 0; i < 4; ++i)
        aregs[i] =
            *(const float4*)(Ab + (long long)(row0 + i * 32 + ar) * lda + k1 + ac);
    }
    // ---- compute on buf cur ----
    {
      bf8v af[4][2], bf[NJ][2];
#pragma unroll
      for (int mi = 0; mi < 4; ++mi) {
        const int r = wr + mi * 16 + fr;
        af[mi][0] = *(const bf8v*)&smA[cur][0][r * 32 + fco];
        af[mi][1] = *(const bf8v*)&smA[cur][1][r * 32 + fco];
      }
#pragma unroll
      for (int nj = 0; nj < NJ; ++nj) {
        const int r = wc + nj * 16 + fr;
        bf[nj][0] = *(const bf8v*)&smB[cur][0][r * 32 + fco];
        bf[nj][1] = *(const bf8v*)&smB[cur][1][r * 32 + fco];
      }
#pragma unroll
      for (int mi = 0; mi < 4; ++mi)
#pragma unroll
        for (int nj = 0; nj < NJ; ++nj) {
          acc[mi][nj] = __builtin_amdgcn_mfma_f32_16x16x32_bf16(
              af[mi][0], bf[nj][0], acc[mi][nj], 0, 0, 0);
          acc[mi][nj] = __builtin_amdgcn_mfma_f32_16x16x32_bf16(
              af[mi][0], bf[nj][1], acc[mi][nj], 0, 0, 0);
          acc[mi][nj] = __builtin_amdgcn_mfma_f32_16x16x32_bf16(
              af[mi][1], bf[nj][0], acc[mi][nj], 0, 0, 0);
        }
    }
    if (more) {
      // split + ds_write next A tile (A regs arrived under the MFMAs)
#pragma unroll
      for (int i = 0; i < 4; ++i) {
        const int r = i * 32 + ar;
        const float vv[4] = {aregs[i].x, aregs[i].y, aregs[i].z, aregs[i].w};
        us4v h, l;
#pragma unroll
        for (int j = 0; j < 4; ++j) {
          u16 hb = bf16_rne(vv[j]);
          h[j] = hb;
          l[j] = bf16_rne(vv[j] - bf16_to_f(hb));
        }
        *(us4v*)&smA[nxt][0][r * 32 + adst] = h;
        *(us4v*)&smA[nxt][1][r * 32 + adst] = l;
      }
    }
    __syncthreads();
  }

#pragma unroll
  for (int mi = 0; mi < 4; ++mi)
#pragma unroll
    for (int nj = 0; nj < NJ; ++nj) {
      const int col = col0 + wc + nj * 16 + fr;
      const long long base =
          (long long)(row0 + wr + mi * 16 + fq * 4) * ldc + col;
#pragma unroll
      for (int j = 0; j < 4; ++j) {
        float v = acc[mi][nj][j] * scale;
        if (GELU) v = 0.5f * v * (1.f + erff(v * 0.70710678118654752f));
        Cb[base + (long long)j * ldc] = v;
      }
    }
}

// ---------------- fused unpack attention (MFMA, flash-style) ----------------
// Per block: (b,h), 128 q rows, all 256 keys. 512 threads (8 waves).
__global__ __launch_bounds__(512) void fused_unpack_attn(
    const float* __restrict__ q, const u16* __restrict__ kh,
    const u16* __restrict__ kl, const u16* __restrict__ vth,
    const u16* __restrict__ vtl, float* __restrict__ outp) {
  __shared__ char pool[76800];
  u16* smA0 = (u16*)pool;                 // [128*32] Q hi (phase 1)
  u16* smA1 = (u16*)(pool + 8192);        // Q lo
  u16* smB0 = (u16*)(pool + 16384);       // [256*32] K hi
  u16* smB1 = (u16*)(pool + 32768);       // K lo
  u16* Pbuf = (u16*)pool;                 // [8][128*32] P hi (phase 2)
  u16* smV0 = (u16*)(pool + 65536);       // [64*32] V hi
  u16* smV1 = (u16*)(pool + 69632);       // V lo
  float* partial = (float*)(pool + 73728);  // [4][128]
  float* rowmax = (float*)(pool + 75776);   // [128]
  float* rowsum = (float*)(pool + 76288);   // [128]

  const int t = threadIdx.x;
  const int w = t >> 6, lane = t & 63;
  const int z = blockIdx.z;
  const int b = z / 12, h = z % 12;
  const int q0 = blockIdx.x * 128;

  const float* qb = q + ((long long)b * 4096 + q0) * 768 + h * 64;
  const u16* khb = kh + ((long long)b * 256) * 768 + h * 64;
  const u16* klb = kl + ((long long)b * 256) * 768 + h * 64;
  const long long vbase = ((long long)(b * 12 + h)) * 16384;  // 64*256

  const int fr = lane & 15, fq = lane >> 4;
  const int fco = (fq ^ ((lane >> 1) & 3)) * 8;
  const int brow_l = lane >> 2;
  const int bchunk = ((lane & 3) ^ ((lane >> 3) & 3)) * 8;
  const int ar = t >> 3;          // [0,64)
  const int ac = (t & 7) * 4;
  const int adst = ((((t >> 1) & 3) ^ ((t >> 4) & 3)) * 8) + ((t & 1) * 4);

  // ---- phase 1: logits = (Q/8) @ K^T ; wave tile 64q x 64keys ----
  const int wr = (w >> 2) * 64, wc = (w & 3) * 64;
  f4v acc[4][4];
#pragma unroll
  for (int i = 0; i < 4; ++i)
#pragma unroll
    for (int j = 0; j < 4; ++j) acc[i][j] = {0.f, 0.f, 0.f, 0.f};

  for (int k0 = 0; k0 < 64; k0 += 32) {
    __syncthreads();
#pragma unroll
    for (int i = 0; i < 4; ++i) {  // K staging: 32 groups / 8 waves
      const int g = w * 4 + i;
      const int hl = g >> 4, ms = g & 15;
      const int r = ms * 16 + brow_l;
      const u16* src = (hl ? klb : khb) + (long long)r * 768 + k0 + bchunk;
      gld_lds16(src, (hl ? smB1 : smB0) + ms * 512 + lane * 8);
    }
#pragma unroll
    for (int i = 0; i < 2; ++i) {  // Q staging: 128 rows / 2 rounds
      const int r = i * 64 + ar;
      const float4 v = *(const float4*)(qb + (long long)r * 768 + k0 + ac);
      const float vv[4] = {v.x * 0.125f, v.y * 0.125f, v.z * 0.125f,
                           v.w * 0.125f};
      us4v hh, ll;
#pragma unroll
      for (int j = 0; j < 4; ++j) {
        u16 hb = bf16_rne(vv[j]);
        hh[j] = hb;
        ll[j] = bf16_rne(vv[j] - bf16_to_f(hb));
      }
      *(us4v*)&smA0[r * 32 + adst] = hh;
      *(us4v*)&smA1[r * 32 + adst] = ll;
    }
    __syncthreads();
#pragma unroll
    for (int mi = 0; mi < 4; ++mi) {
      const int r = wr + mi * 16 + fr;
      const bf8v a0 = *(const bf8v*)&smA0[r * 32 + fco];
      const bf8v a1 = *(const bf8v*)&smA1[r * 32 + fco];
#pragma unroll
      for (int nj = 0; nj < 4; ++nj) {
        const int rb = wc + nj * 16 + fr;
        const bf8v b0 = *(const bf8v*)&smB0[rb * 32 + fco];
        const bf8v b1 = *(const bf8v*)&smB1[rb * 32 + fco];
        acc[mi][nj] = __builtin_amdgcn_mfma_f32_16x16x32_bf16(a0, b0, acc[mi][nj], 0, 0, 0);
        acc[mi][nj] = __builtin_amdgcn_mfma_f32_16x16x32_bf16(a0, b1, acc[mi][nj], 0, 0, 0);
        acc[mi][nj] = __builtin_amdgcn_mfma_f32_16x16x32_bf16(a1, b0, acc[mi][nj], 0, 0, 0);
      }
    }
  }
  __syncthreads();  // smA/smB dead; Pbuf region reusable

  // ---- phase 2: softmax (cross-wave via LDS partials) ----
#pragma unroll
  for (int mi = 0; mi < 4; ++mi)
#pragma unroll
    for (int j = 0; j < 4; ++j) {
      float m = fmaxf(fmaxf(acc[mi][0][j], acc[mi][1][j]),
                      fmaxf(acc[mi][2][j], acc[mi][3][j]));
#pragma unroll
      for (int o = 1; o < 16; o <<= 1) m = fmaxf(m, __shfl_xor(m, o));
      if (fr == 0) partial[(w & 3) * 128 + wr + mi * 16 + fq * 4 + j] = m;
    }
  __syncthreads();
  if (t < 128)
    rowmax[t] = fmaxf(fmaxf(partial[t], partial[128 + t]),
                      fmaxf(partial[256 + t], partial[384 + t]));
  __syncthreads();
#pragma unroll
  for (int mi = 0; mi < 4; ++mi)
#pragma unroll
    for (int j = 0; j < 4; ++j) {
      const int row = wr + mi * 16 + fq * 4 + j;
      const float rm = rowmax[row];
      float s = 0.f;
#pragma unroll
      for (int nj = 0; nj < 4; ++nj) {
        const float e = expf(acc[mi][nj][j] - rm);
        s += e;
        const int col = wc + nj * 16 + fr;
        const int kc = col >> 5, kloc = col & 31;
        Pbuf[kc * 4096 + row * 32 + (((kloc >> 3) ^ ((row >> 1) & 3)) * 8) +
             (kloc & 7)] = bf16_rne(e);
      }
#pragma unroll
      for (int o = 1; o < 16; o <<= 1) s += __shfl_xor(s, o);
      if (fr == 0) partial[(w & 3) * 128 + row] = s;
    }
  __syncthreads();
  if (t < 128)
    rowsum[t] = (partial[t] + partial[128 + t]) + (partial[256 + t] + partial[384 + t]);

  // ---- phase 3: PV ; wave tile 32q x 32dh ----
  const int wrp = (w >> 1) * 32, wcp = (w & 1) * 32;
  f4v acc2[2][2];
#pragma unroll
  for (int i = 0; i < 2; ++i)
#pragma unroll
    for (int j = 0; j < 2; ++j) acc2[i][j] = {0.f, 0.f, 0.f, 0.f};

  for (int kc = 0; kc < 8; ++kc) {
    __syncthreads();
    {  // V chunk staging: 8 groups / 8 waves
      const int hl = w >> 2, ms = w & 3;
      const int r = ms * 16 + brow_l;  // dh
      const u16* src =
          (hl ? vtl : vth) + vbase + (long long)r * 256 + kc * 32 + bchunk;
      gld_lds16(src, (hl ? smV1 : smV0) + ms * 512 + lane * 8);
    }
    __syncthreads();
#pragma unroll
    for (int mi = 0; mi < 2; ++mi) {
      const bf8v pa =
          *(const bf8v*)&Pbuf[kc * 4096 + (wrp + mi * 16 + fr) * 32 + fco];
#pragma unroll
      for (int nj = 0; nj < 2; ++nj) {
        const int rv = wcp + nj * 16 + fr;
        const bf8v v0 = *(const bf8v*)&smV0[rv * 32 + fco];
        const bf8v v1 = *(const bf8v*)&smV1[rv * 32 + fco];
        acc2[mi][nj] = __builtin_amdgcn_mfma_f32_16x16x32_bf16(pa, v0, acc2[mi][nj], 0, 0, 0);
        acc2[mi][nj] = __builtin_amdgcn_mfma_f32_16x16x32_bf16(pa, v1, acc2[mi][nj], 0, 0, 0);
      }
    }
  }
  float* ob = outp + ((long long)b * 4096 + q0) * 768 + h * 64;
#pragma unroll
  for (int mi = 0; mi < 2; ++mi)
#pragma unroll
    for (int nj = 0; nj < 2; ++nj)
#pragma unroll
      for (int j = 0; j < 4; ++j) {
        const int row = wrp + mi * 16 + fq * 4 + j;
        const int col = wcp + nj * 16 + fr;
        ob[(long long)row * 768 + col] = acc2[mi][nj][j] / rowsum[row];
      }
}

// ---------------- conv pool -> split bf16 hi/lo, [b,h,t,dh] layout ----------
__global__ __launch_bounds__(256) void conv_split_kernel(
    const float* __restrict__ in, const float* __restrict__ w,
    u16* __restrict__ hi, u16* __restrict__ lo, int total, int ld) {
  int idx = blockIdx.x * 256 + threadIdx.x;
  if (idx >= total) return;
  const int dh = idx & 63;
  int r = idx >> 6;
  const int tt = r & 1023; r >>= 10;
  const int h = r % 12;
  const int b = r / 12;
  const float* s = in + ((long long)(b * 4096 + 4 * tt)) * ld + h * 64 + dh;
  const float* wh = w + h * 4;
  const float v = fmaf(wh[0], s[0],
                  fmaf(wh[1], s[ld], fmaf(wh[2], s[2 * ld], wh[3] * s[3 * ld])));
  const u16 hb = bf16_rne(v);
  hi[idx] = hb;
  lo[idx] = bf16_rne(v - bf16_to_f(hb));
}

// ---------------- conv pool -> split, TRANSPOSED [b,h,dh,t] layout ----------
__global__ __launch_bounds__(256) void conv_splitT_kernel(
    const float* __restrict__ in, const float* __restrict__ w,
    u16* __restrict__ hi, u16* __restrict__ lo, int total, int ld) {
  int idx = blockIdx.x * 256 + threadIdx.x;
  if (idx >= total) return;
  const int tt = idx & 1023;
  int r = idx >> 10;
  const int dh = r & 63; r >>= 6;
  const int h = r % 12;
  const int b = r / 12;
  const float* s = in + ((long long)(b * 4096 + 4 * tt)) * ld + h * 64 + dh;
  const float* wh = w + h * 4;
  const float v = fmaf(wh[0], s[0],
                  fmaf(wh[1], s[ld], fmaf(wh[2], s[2 * ld], wh[3] * s[3 * ld])));
  const u16 hb = bf16_rne(v);
  hi[idx] = hb;
  lo[idx] = bf16_rne(v - bf16_to_f(hb));
}

// ---------------- transpose+split: [4,256,768] -> [b,h,dh,key] hi/lo --------
__global__ __launch_bounds__(256) void splitT_kernel(
    const float* __restrict__ in, u16* __restrict__ hi, u16* __restrict__ lo,
    int total) {
  int idx = blockIdx.x * 256 + threadIdx.x;
  if (idx >= total) return;
  const int key = idx & 255;
  int r = idx >> 8;
  const int dh = r & 63; r >>= 6;
  const int h = r % 12;
  const int b = r / 12;
  const float v = in[((long long)(b * 256 + key)) * 768 + h * 64 + dh];
  const u16 hb = bf16_rne(v);
  hi[idx] = hb;
  lo[idx] = bf16_rne(v - bf16_to_f(hb));
}

// ---------------- row softmax (in place), rowlen = ITERS*256 ----------------
template <int ITERS>
__global__ __launch_bounds__(256) void softmax_kernel(float* __restrict__ data) {
  const long long row = blockIdx.x;
  float* p = data + row * (ITERS * 256);
  const int t = threadIdx.x;
  __shared__ float red[4];
  float v[ITERS];
  float lmax = -3.4e38f;
#pragma unroll
  for (int i = 0; i < ITERS; ++i) {
    v[i] = p[t + (i << 8)];
    lmax = fmaxf(lmax, v[i]);
  }
  for (int o = 32; o; o >>= 1) lmax = fmaxf(lmax, __shfl_xor(lmax, o));
  if ((t & 63) == 0) red[t >> 6] = lmax;
  __syncthreads();
  const float gmax = fmaxf(fmaxf(red[0], red[1]), fmaxf(red[2], red[3]));
  float lsum = 0.f;
#pragma unroll
  for (int i = 0; i < ITERS; ++i) {
    v[i] = expf(v[i] - gmax);
    lsum += v[i];
  }
  __syncthreads();
  for (int o = 32; o; o >>= 1) lsum += __shfl_xor(lsum, o);
  if ((t & 63) == 0) red[t >> 6] = lsum;
  __syncthreads();
  const float inv = 1.f / (red[0] + red[1] + red[2] + red[3]);
#pragma unroll
  for (int i = 0; i < ITERS; ++i) p[t + (i << 8)] = v[i] * inv;
}

// ---------------- LayerNorm(a + b*maskf), eps 1e-6, width 768 ----------------
__global__ __launch_bounds__(256) void ln_kernel(
    const float* __restrict__ a, const float* __restrict__ b,
    const int* __restrict__ mask, float* __restrict__ out) {
  const long long row = blockIdx.x;
  const float* pa = a + row * 768;
  const float* pb = b + row * 768;
  const float ms = mask ? (float)mask[row] : 1.f;
  __shared__ float buf[768];
  __shared__ float red[4];
  const int t = threadIdx.x;
  float lsum = 0.f;
#pragma unroll
  for (int i = t; i < 768; i += 256) {
    const float v = fmaf(pb[i], ms, pa[i]);
    buf[i] = v;
    lsum += v;
  }
  for (int o = 32; o; o >>= 1) lsum += __shfl_xor(lsum, o);
  if ((t & 63) == 0) red[t >> 6] = lsum;
  __syncthreads();
  const float mu = (red[0] + red[1] + red[2] + red[3]) * (1.f / 768.f);
  float lvar = 0.f;
#pragma unroll
  for (int i = t; i < 768; i += 256) {
    const float d = buf[i] - mu;
    lvar = fmaf(d, d, lvar);
  }
  __syncthreads();
  for (int o = 32; o; o >>= 1) lvar += __shfl_xor(lvar, o);
  if ((t & 63) == 0) red[t >> 6] = lvar;
  __syncthreads();
  const float var = (red[0] + red[1] + red[2] + red[3]) * (1.f / 768.f);
  const float rstd = rsqrtf(var + 1e-6f);
  float* po = out + row * 768;
#pragma unroll
  for (int i = t; i < 768; i += 256) po[i] = (buf[i] - mu) * rstd;
}

// ---------------- host helpers ----------------
static inline void mgemm(hipStream_t st, const float* A, const u16* Bh,
                         const u16* Bl, float* C, int M, int N, int K, int lda,
                         int ldb, int ldc, long long aSB, long long aSH,
                         long long bSB, long long bSH, long long cSB,
                         long long cSH, int nBat, int HB, float scale, int bn,
                         int gelu) {
  if (bn == 128) {
    dim3 g(N / 128, M / 128, nBat);
    if (gelu)
      mgemm_kernel<128, 1><<<g, 256, 0, st>>>(A, Bh, Bl, C, M, N, K, lda, ldb,
                                              ldc, aSB, aSH, bSB, bSH, cSB, cSH,
                                              HB, scale);
    else
      mgemm_kernel<128, 0><<<g, 256, 0, st>>>(A, Bh, Bl, C, M, N, K, lda, ldb,
                                              ldc, aSB, aSH, bSB, bSH, cSB, cSH,
                                              HB, scale);
  } else {
    dim3 g(N / 64, M / 128, nBat);
    mgemm_kernel<64, 0><<<g, 256, 0, st>>>(A, Bh, Bl, C, M, N, K, lda, ldb, ldc,
                                           aSB, aSH, bSB, bSH, cSB, cSH, HB,
                                           scale);
  }
}

static inline void split_launch(hipStream_t st, const float* in, u16* hi,
                                u16* lo, int n) {
  int n4 = n / 4;
  split_kernel<<<(n4 + 255) / 256, 256, 0, st>>>(in, hi, lo, n4);
}

extern "C" void kernel_launch(void* const* d_in, const int* in_sizes, int n_in,
                              void* d_out, int out_size, void* d_ws,
                              size_t ws_size, hipStream_t stream) {
  const float* x = (const float*)d_in[0];       // [4,4096,768]
  const float* memory = (const float*)d_in[1];  // [4,256,768]
  const int* mask = (const int*)d_in[2];        // [4,4096]
  const float* Wq = (const float*)d_in[3];
  const float* Wk = (const float*)d_in[4];
  const float* Wv = (const float*)d_in[5];
  const float* Wo = (const float*)d_in[6];
  const float* conv_w = (const float*)d_in[7];  // [12,1,4,1]
  const float* Uq = (const float*)d_in[8];
  const float* Uk = (const float*)d_in[9];
  const float* Uv = (const float*)d_in[10];
  const float* Uo = (const float*)d_in[11];
  const float* W1 = (const float*)d_in[12];  // [3072,768]
  const float* W2 = (const float*)d_in[13];  // [768,3072]
  float* out = (float*)d_out;  // q_out [4,4096,768] then m_out [4,256,768]
  float* ws = (float*)d_ws;

  const int XR = 16384, MR = 1024, D = 768, MLP = 3072;
  const long long CB = 3145728;  // 4096*768
  const int WD = 589824;         // 768*768
  const int WM = 2359296;        // 3072*768

  // ---- workspace (floats); base total 40,894,464 = 163.6 MB ----
  float* slotA = ws + 0;         // 12.58M: kvproj(low) -> pack-logits -> uattvm -> h_b
  float* slotB = ws + 12582912;  // 12.58M: kvproj(high) -> uq -> unp/qout1
  float* slotC = ws + 25165824;  //  3.15M: y_b
  float* X     = ws + 28311552;  //  6.29M: kp/vpT splits -> U+ukb/uvT -> W1/W2
  float* qproj = ws + 34603008;  //  786K
  float* attvm = ws + 35389440;  //  786K
  float* packed= ws + 36175872;  //  786K
  float* ukb   = ws + 36962304;  //  786K
  float* uvb   = ws + 37748736;  //  786K
  float* Wp    = ws + 38535168;  //  2.36M: pack-weight splits
  float* hbufBig = ws + 40894464;  // 50.33M (big-FFN path only)
  const bool bigFFN = ws_size >= (size_t)(40894464 + 50331648) * 4;

  // Wp layout (u16): Wkv hi [1536*768], Wkv lo [1536*768], Wq hi/lo, Wo hi/lo
  u16* wp16 = (u16*)Wp;
  u16 *Wkvh = wp16, *Wkvl = wp16 + 2 * WD,
      *Wqh = wp16 + 4 * WD, *Wql = wp16 + 5 * WD, *Woh = wp16 + 6 * WD,
      *Wol = wp16 + 7 * WD;
  u16* xk = (u16*)X;
  u16 *kph = xk, *kpl = xk + 3145728, *vph = xk + 6291456, *vpl = xk + 9437184;
  u16 *Uqh = xk, *Uql = xk + WD, *Ukh = xk + 2 * WD, *Ukl = xk + 3 * WD,
      *Uvh = xk + 4 * WD, *Uvl = xk + 5 * WD, *Uoh = xk + 6 * WD,
      *Uol = xk + 7 * WD;
  u16 *ukbh = xk + 4718592, *ukbl = xk + 5505024;
  u16 *uvth = xk + 6291456, *uvtl = xk + 7077888;
  u16 *W1h = xk, *W1l = xk + WM, *W2h = xk + 2 * WM, *W2l = xk + 3 * WM;

  // ---- pack phase ----
  split_launch(stream, Wk, Wkvh, Wkvl, WD);            // rows 0-767 of Wkv
  split_launch(stream, Wv, Wkvh + WD, Wkvl + WD, WD);  // rows 768-1535
  split_launch(stream, Wq, Wqh, Wql, WD);
  split_launch(stream, Wo, Woh, Wol, WD);
  // merged k+v projection: [16384,1536] = x @ [Wk;Wv]^T, C spans slotA∪slotB
  mgemm(stream, x, Wkvh, Wkvl, slotA, XR, 1536, D, D, D, 1536,
        0, 0, 0, 0, 0, 0, 1, 1, 1.f, 128, 0);
  mgemm(stream, memory, Wqh, Wql, qproj, MR, D, D, D, D, D, 0, 0, 0, 0, 0, 0, 1, 1, 1.f, 128, 0);
  conv_split_kernel<<<12288, 256, 0, stream>>>(slotA, conv_w, kph, kpl, 3145728, 1536);
  conv_splitT_kernel<<<12288, 256, 0, stream>>>(slotA + 768, conv_w, vph, vpl, 3145728, 1536);
  // pack logits [b,h,256,1024] = qproj @ kp^T (K=64)
  mgemm(stream, qproj, kph, kpl, slotA, 256, 1024, 64, 768, 64, 1024,
        196608, 64, 786432, 65536, 3145728, 262144, 48, 12, 1.f, 128, 0);
  softmax_kernel<4><<<12288, 256, 0, stream>>>(slotA);
  // pack PV: [256,64] per (b,h), K=1024, Vt [b,h,64,1024]
  mgemm(stream, slotA, vph, vpl, attvm, 256, 64, 1024, 1024, 1024, 768,
        3145728, 262144, 786432, 65536, 196608, 64, 48, 12, 1.f, 64, 0);
  mgemm(stream, attvm, Woh, Wol, packed, MR, D, D, D, D, D, 0, 0, 0, 0, 0, 0, 1, 1, 1.f, 128, 0);
  ln_kernel<<<MR, 256, 0, stream>>>(memory, packed, nullptr, out + 12582912);

  // ---- unpack phase (kp/vpT dead -> X hosts U + kv splits) ----
  split_launch(stream, Uq, Uqh, Uql, WD);
  split_launch(stream, Uk, Ukh, Ukl, WD);
  split_launch(stream, Uv, Uvh, Uvl, WD);
  split_launch(stream, Uo, Uoh, Uol, WD);
  mgemm(stream, x, Uqh, Uql, slotB, XR, D, D, D, D, D, 0, 0, 0, 0, 0, 0, 1, 1, 1.f, 128, 0);  // uq
  mgemm(stream, packed, Ukh, Ukl, ukb, MR, D, D, D, D, D, 0, 0, 0, 0, 0, 0, 1, 1, 1.f, 128, 0);
  mgemm(stream, packed, Uvh, Uvl, uvb, MR, D, D, D, D, D, 0, 0, 0, 0, 0, 0, 1, 1, 1.f, 128, 0);
  split_launch(stream, ukb, ukbh, ukbl, 786432);
  splitT_kernel<<<3072, 256, 0, stream>>>(uvb, uvth, uvtl, 786432);
  // fused attention: uq (slotB) -> uattvm (slotA)
  {
    dim3 g(32, 1, 48);
    fused_unpack_attn<<<g, 512, 0, stream>>>(slotB, ukbh, ukbl, uvth, uvtl, slotA);
  }
  // unp = uattvm @ Uo^T (z-batched over 4) -> slotB; then LN in-place
  mgemm(stream, slotA, Uoh, Uol, slotB, 4096, D, D, D, D, D,
        CB, 0, 0, 0, CB, 0, 4, 1, 1.f, 128, 0);
  ln_kernel<<<XR, 256, 0, stream>>>(x, slotB, mask, slotB);

  // ---- FFN phase (U/ukb splits dead -> X hosts W1/W2 splits) ----
  split_launch(stream, W1, W1h, W1l, WM);
  split_launch(stream, W2, W2h, W2l, WM);
  if (bigFFN) {
    mgemm(stream, slotB, W1h, W1l, hbufBig, XR, MLP, D, D, D, MLP,
          0, 0, 0, 0, 0, 0, 1, 1, 1.f, 128, 1);
    mgemm(stream, hbufBig, W2h, W2l, slotA, XR, D, MLP, MLP, MLP, D,
          0, 0, 0, 0, 0, 0, 1, 1, 1.f, 64, 0);
    ln_kernel<<<XR, 256, 0, stream>>>(slotB, slotA, mask, out);
  } else {
    for (int b = 0; b < 4; ++b) {
      mgemm(stream, slotB + b * CB, W1h, W1l, slotA, 4096, MLP, D, D, D, MLP,
            0, 0, 0, 0, 0, 0, 1, 1, 1.f, 128, 1);
      mgemm(stream, slotA, W2h, W2l, slotC, 4096, D, MLP, MLP, MLP, D,
            0, 0, 0, 0, 0, 0, 1, 1, 1.f, 64, 0);
      ln_kernel<<<4096, 256, 0, stream>>>(slotB + b * CB, slotC,
                                          mask + b * 4096, out + b * CB);
    }
  }
}

// Round 8
// 1574.484 us; speedup vs baseline: 1.3277x; 1.0415x over previous
//
#include <hip/hip_runtime.h>
#include <hip/hip_bf16.h>
#include <math.h>

// ----------------------------------------------------------------------------
// vMFLunaBlock v8: split-once dataflow. GEMM outputs feeding other GEMMs are
// written pre-split (hi/lo bf16 planes); consumer A-path becomes pure
// global_load_lds (no per-K-step VALU split). Bit-identical arithmetic to v7.
// Workspace: 40,894,464 floats = 163.6 MB (same audited layout).
// ----------------------------------------------------------------------------

typedef unsigned short u16;
typedef __attribute__((ext_vector_type(8))) short bf8v;
typedef __attribute__((ext_vector_type(4))) float f4v;
typedef __attribute__((ext_vector_type(4))) unsigned short us4v;

#define AS1 __attribute__((address_space(1)))
#define AS3 __attribute__((address_space(3)))

__device__ __forceinline__ void gld_lds16(const void* g, void* l) {
  __builtin_amdgcn_global_load_lds((const AS1 unsigned int*)g,
                                   (AS3 unsigned int*)l, 16, 0, 0);
}

__device__ __forceinline__ u16 bf16_rne(float x) {
  unsigned u = __float_as_uint(x);
  return (u16)((u + 0x7fffu + ((u >> 16) & 1u)) >> 16);
}
__device__ __forceinline__ float bf16_to_f(u16 h) {
  return __uint_as_float(((unsigned)h) << 16);
}

// ---------------- split fp32 -> (hi, lo) bf16 (weights) ----------------
__global__ __launch_bounds__(256) void split_kernel(
    const float* __restrict__ in, u16* __restrict__ hi, u16* __restrict__ lo,
    int n4) {
  int i = blockIdx.x * 256 + threadIdx.x;
  if (i >= n4) return;
  float4 v = ((const float4*)in)[i];
  us4v h, l;
  float vv[4] = {v.x, v.y, v.z, v.w};
#pragma unroll
  for (int j = 0; j < 4; ++j) {
    u16 hb = bf16_rne(vv[j]);
    h[j] = hb;
    l[j] = bf16_rne(vv[j] - bf16_to_f(hb));
  }
  ((us4v*)hi)[i] = h;
  ((us4v*)lo)[i] = l;
}

// ---------------- split-bf16 MFMA GEMM, double-buffered ----------------
// C = scale*(A @ B^T) [+GELU]. ASPLIT: A given as hi/lo u16 planes (gld_lds);
// else A fp32, split in-kernel. OMODE: 0=fp32 out, 1=split out, 2=both.
template <int BN, int GELU, int ASPLIT, int OMODE>
__global__ __launch_bounds__(256) void mgemm_kernel(
    const float* __restrict__ Af, const u16* __restrict__ Ah,
    const u16* __restrict__ Al, const u16* __restrict__ Bh,
    const u16* __restrict__ Bl, float* __restrict__ Cf, u16* __restrict__ Ch,
    u16* __restrict__ Cl, int M, int N, int K, int lda, int ldb, int ldc,
    long long aSB, long long aSH, long long bSB, long long bSH, long long cSB,
    long long cSH, int HB, float scale) {
  constexpr int NJ = BN / 32;
  constexpr int GPM = BN / 16;
  constexpr int LPW = BN / 32;
  __shared__ u16 smA[2][2][4096];
  __shared__ u16 smB[2][2][BN * 32];
  const int t = threadIdx.x;
  const int w = t >> 6, lane = t & 63;
  const int z = blockIdx.z;
  const int bb = z / HB, hh = z % HB;
  const float* Afb = ASPLIT ? nullptr : (Af + bb * aSB + hh * aSH);
  const u16* Ahb = ASPLIT ? (Ah + bb * aSB + hh * aSH) : nullptr;
  const u16* Alb = ASPLIT ? (Al + bb * aSB + hh * aSH) : nullptr;
  const u16* Bhb = Bh + bb * bSB + hh * bSH;
  const u16* Blb = Bl + bb * bSB + hh * bSH;
  float* Cfb = (OMODE != 1) ? (Cf + bb * cSB + hh * cSH) : nullptr;
  u16* Chb = (OMODE >= 1) ? (Ch + bb * cSB + hh * cSH) : nullptr;
  u16* Clb = (OMODE >= 1) ? (Cl + bb * cSB + hh * cSH) : nullptr;

  // XCD swizzle (bijective when nwg%8==0)
  const int gx = gridDim.x;
  const int nwg = gx * gridDim.y;
  int f = blockIdx.x + gx * blockIdx.y;
  if ((nwg & 7) == 0) {
    const int cpx = nwg >> 3;
    f = (f & 7) * cpx + (f >> 3);
  }
  const int row0 = (f / gx) * 128, col0 = (f % gx) * BN;

  const int brow_l = lane >> 2;
  const int bchunk = ((lane & 3) ^ ((lane >> 3) & 3)) * 8;
  const int ar = t >> 3;
  const int ac = (t & 7) * 4;
  const int adst = ((((t >> 1) & 3) ^ ((t >> 4) & 3)) * 8) + ((t & 1) * 4);
  const int fr = lane & 15;
  const int fq = lane >> 4;
  const int fco = (fq ^ ((lane >> 1) & 3)) * 8;
  const int wr = (w >> 1) * 64, wc = (w & 1) * (BN / 2);

  f4v acc[4][NJ];
#pragma unroll
  for (int i = 0; i < 4; ++i)
#pragma unroll
    for (int j = 0; j < NJ; ++j) acc[i][j] = {0.f, 0.f, 0.f, 0.f};

  const int NT = K >> 5;
  float4 aregs[4];

  // ---- prologue: stage tile 0 ----
#pragma unroll
  for (int i = 0; i < LPW; ++i) {
    const int g = w * LPW + i;
    const int hl = g / GPM, ms = g % GPM;
    const int r = ms * 16 + brow_l;
    gld_lds16((hl ? Blb : Bhb) + (long long)(col0 + r) * ldb + bchunk,
              &smB[0][hl][ms * 512 + lane * 8]);
  }
  if (ASPLIT) {
#pragma unroll
    for (int i = 0; i < 4; ++i) {
      const int g = w * 4 + i;
      const int hl = g >> 3, ms = g & 7;
      const int r = ms * 16 + brow_l;
      gld_lds16((hl ? Alb : Ahb) + (long long)(row0 + r) * lda + bchunk,
                &smA[0][hl][ms * 512 + lane * 8]);
    }
  } else {
#pragma unroll
    for (int i = 0; i < 4; ++i)
      aregs[i] = *(const float4*)(Afb + (long long)(row0 + i * 32 + ar) * lda + ac);
#pragma unroll
    for (int i = 0; i < 4; ++i) {
      const int r = i * 32 + ar;
      const float vv[4] = {aregs[i].x, aregs[i].y, aregs[i].z, aregs[i].w};
      us4v h, l;
#pragma unroll
      for (int j = 0; j < 4; ++j) {
        u16 hb = bf16_rne(vv[j]);
        h[j] = hb;
        l[j] = bf16_rne(vv[j] - bf16_to_f(hb));
      }
      *(us4v*)&smA[0][0][r * 32 + adst] = h;
      *(us4v*)&smA[0][1][r * 32 + adst] = l;
    }
  }
  __syncthreads();

  for (int tt = 0; tt < NT; ++tt) {
    const int cur = tt & 1, nxt = cur ^ 1;
    const bool more = (tt + 1) < NT;
    if (more) {
      const int k1 = (tt + 1) << 5;
#pragma unroll
      for (int i = 0; i < LPW; ++i) {
        const int g = w * LPW + i;
        const int hl = g / GPM, ms = g % GPM;
        const int r = ms * 16 + brow_l;
        gld_lds16((hl ? Blb : Bhb) + (long long)(col0 + r) * ldb + k1 + bchunk,
                  &smB[nxt][hl][ms * 512 + lane * 8]);
      }
      if (ASPLIT) {
#pragma unroll
        for (int i = 0; i < 4; ++i) {
          const int g = w * 4 + i;
          const int hl = g >> 3, ms = g & 7;
          const int r = ms * 16 + brow_l;
          gld_lds16((hl ? Alb : Ahb) + (long long)(row0 + r) * lda + k1 + bchunk,
                    &smA[nxt][hl][ms * 512 + lane * 8]);
        }
      } else {
#pragma unroll
        for (int i = 0; i < 4; ++i)
          aregs[i] =
              *(const float4*)(Afb + (long long)(row0 + i * 32 + ar) * lda + k1 + ac);
      }
    }
    // ---- compute on buf cur ----
    {
      bf8v af[4][2], bf[NJ][2];
#pragma unroll
      for (int mi = 0; mi < 4; ++mi) {
        const int r = wr + mi * 16 + fr;
        af[mi][0] = *(const bf8v*)&smA[cur][0][r * 32 + fco];
        af[mi][1] = *(const bf8v*)&smA[cur][1][r * 32 + fco];
      }
#pragma unroll
      for (int nj = 0; nj < NJ; ++nj) {
        const int r = wc + nj * 16 + fr;
        bf[nj][0] = *(const bf8v*)&smB[cur][0][r * 32 + fco];
        bf[nj][1] = *(const bf8v*)&smB[cur][1][r * 32 + fco];
      }
#pragma unroll
      for (int mi = 0; mi < 4; ++mi)
#pragma unroll
        for (int nj = 0; nj < NJ; ++nj) {
          acc[mi][nj] = __builtin_amdgcn_mfma_f32_16x16x32_bf16(
              af[mi][0], bf[nj][0], acc[mi][nj], 0, 0, 0);
          acc[mi][nj] = __builtin_amdgcn_mfma_f32_16x16x32_bf16(
              af[mi][0], bf[nj][1], acc[mi][nj], 0, 0, 0);
          acc[mi][nj] = __builtin_amdgcn_mfma_f32_16x16x32_bf16(
              af[mi][1], bf[nj][0], acc[mi][nj], 0, 0, 0);
        }
    }
    if (!ASPLIT && more) {
#pragma unroll
      for (int i = 0; i < 4; ++i) {
        const int r = i * 32 + ar;
        const float vv[4] = {aregs[i].x, aregs[i].y, aregs[i].z, aregs[i].w};
        us4v h, l;
#pragma unroll
        for (int j = 0; j < 4; ++j) {
          u16 hb = bf16_rne(vv[j]);
          h[j] = hb;
          l[j] = bf16_rne(vv[j] - bf16_to_f(hb));
        }
        *(us4v*)&smA[nxt][0][r * 32 + adst] = h;
        *(us4v*)&smA[nxt][1][r * 32 + adst] = l;
      }
    }
    __syncthreads();
  }

#pragma unroll
  for (int mi = 0; mi < 4; ++mi)
#pragma unroll
    for (int nj = 0; nj < NJ; ++nj) {
      const int col = col0 + wc + nj * 16 + fr;
      const long long base =
          (long long)(row0 + wr + mi * 16 + fq * 4) * ldc + col;
#pragma unroll
      for (int j = 0; j < 4; ++j) {
        float v = acc[mi][nj][j] * scale;
        if (GELU) v = 0.5f * v * (1.f + erff(v * 0.70710678118654752f));
        const long long idx = base + (long long)j * ldc;
        if (OMODE != 1) Cfb[idx] = v;
        if (OMODE >= 1) {
          const u16 hb = bf16_rne(v);
          Chb[idx] = hb;
          Clb[idx] = bf16_rne(v - bf16_to_f(hb));
        }
      }
    }
}

// ---------------- fused unpack attention (pre-split Q/K/V, split out) -------
__global__ __launch_bounds__(512) void fused_unpack_attn(
    const u16* __restrict__ qh, const u16* __restrict__ ql,
    const u16* __restrict__ kh, const u16* __restrict__ kl,
    const u16* __restrict__ vth, const u16* __restrict__ vtl,
    u16* __restrict__ oh, u16* __restrict__ ol) {
  __shared__ char pool[76800];
  u16* smA0 = (u16*)pool;                 // [128*32] Q hi
  u16* smA1 = (u16*)(pool + 8192);        // Q lo
  u16* smB0 = (u16*)(pool + 16384);       // [256*32] K hi
  u16* smB1 = (u16*)(pool + 32768);       // K lo
  u16* Pbuf = (u16*)pool;                 // [8][128*32] P hi (phase 2)
  u16* smV0 = (u16*)(pool + 65536);       // [64*32] V hi
  u16* smV1 = (u16*)(pool + 69632);       // V lo
  float* partial = (float*)(pool + 73728);  // [4][128]
  float* rowmax = (float*)(pool + 75776);   // [128]
  float* rowsum = (float*)(pool + 76288);   // [128]

  const int t = threadIdx.x;
  const int w = t >> 6, lane = t & 63;
  const int z = blockIdx.z;
  const int b = z / 12, h = z % 12;
  const int q0 = blockIdx.x * 128;

  const long long qoff = ((long long)b * 4096 + q0) * 768 + h * 64;
  const long long koff = ((long long)b * 256) * 768 + h * 64;
  const long long vbase = ((long long)(b * 12 + h)) * 16384;

  const int fr = lane & 15, fq = lane >> 4;
  const int fco = (fq ^ ((lane >> 1) & 3)) * 8;
  const int brow_l = lane >> 2;
  const int bchunk = ((lane & 3) ^ ((lane >> 3) & 3)) * 8;

  // ---- phase 1: logits = Qs @ K^T (Q pre-scaled by 1/8) ----
  const int wr = (w >> 2) * 64, wc = (w & 3) * 64;
  f4v acc[4][4];
#pragma unroll
  for (int i = 0; i < 4; ++i)
#pragma unroll
    for (int j = 0; j < 4; ++j) acc[i][j] = {0.f, 0.f, 0.f, 0.f};

  for (int k0 = 0; k0 < 64; k0 += 32) {
    __syncthreads();
#pragma unroll
    for (int i = 0; i < 4; ++i) {  // K staging: 32 groups / 8 waves
      const int g = w * 4 + i;
      const int hl = g >> 4, ms = g & 15;
      const int r = ms * 16 + brow_l;
      gld_lds16((hl ? kl : kh) + koff + (long long)r * 768 + k0 + bchunk,
                (hl ? smB1 : smB0) + ms * 512 + lane * 8);
    }
#pragma unroll
    for (int i = 0; i < 2; ++i) {  // Q staging: 16 groups / 8 waves
      const int g = w * 2 + i;
      const int hl = g >> 3, ms = g & 7;
      const int r = ms * 16 + brow_l;
      gld_lds16((hl ? ql : qh) + qoff + (long long)r * 768 + k0 + bchunk,
                (hl ? smA1 : smA0) + ms * 512 + lane * 8);
    }
    __syncthreads();
#pragma unroll
    for (int mi = 0; mi < 4; ++mi) {
      const int r = wr + mi * 16 + fr;
      const bf8v a0 = *(const bf8v*)&smA0[r * 32 + fco];
      const bf8v a1 = *(const bf8v*)&smA1[r * 32 + fco];
#pragma unroll
      for (int nj = 0; nj < 4; ++nj) {
        const int rb = wc + nj * 16 + fr;
        const bf8v b0 = *(const bf8v*)&smB0[rb * 32 + fco];
        const bf8v b1 = *(const bf8v*)&smB1[rb * 32 + fco];
        acc[mi][nj] = __builtin_amdgcn_mfma_f32_16x16x32_bf16(a0, b0, acc[mi][nj], 0, 0, 0);
        acc[mi][nj] = __builtin_amdgcn_mfma_f32_16x16x32_bf16(a0, b1, acc[mi][nj], 0, 0, 0);
        acc[mi][nj] = __builtin_amdgcn_mfma_f32_16x16x32_bf16(a1, b0, acc[mi][nj], 0, 0, 0);
      }
    }
  }
  __syncthreads();

  // ---- phase 2: softmax ----
#pragma unroll
  for (int mi = 0; mi < 4; ++mi)
#pragma unroll
    for (int j = 0; j < 4; ++j) {
      float m = fmaxf(fmaxf(acc[mi][0][j], acc[mi][1][j]),
                      fmaxf(acc[mi][2][j], acc[mi][3][j]));
#pragma unroll
      for (int o = 1; o < 16; o <<= 1) m = fmaxf(m, __shfl_xor(m, o));
      if (fr == 0) partial[(w & 3) * 128 + wr + mi * 16 + fq * 4 + j] = m;
    }
  __syncthreads();
  if (t < 128)
    rowmax[t] = fmaxf(fmaxf(partial[t], partial[128 + t]),
                      fmaxf(partial[256 + t], partial[384 + t]));
  __syncthreads();
#pragma unroll
  for (int mi = 0; mi < 4; ++mi)
#pragma unroll
    for (int j = 0; j < 4; ++j) {
      const int row = wr + mi * 16 + fq * 4 + j;
      const float rm = rowmax[row];
      float s = 0.f;
#pragma unroll
      for (int nj = 0; nj < 4; ++nj) {
        const float e = expf(acc[mi][nj][j] - rm);
        s += e;
        const int col = wc + nj * 16 + fr;
        const int kc = col >> 5, kloc = col & 31;
        Pbuf[kc * 4096 + row * 32 + (((kloc >> 3) ^ ((row >> 1) & 3)) * 8) +
             (kloc & 7)] = bf16_rne(e);
      }
#pragma unroll
      for (int o = 1; o < 16; o <<= 1) s += __shfl_xor(s, o);
      if (fr == 0) partial[(w & 3) * 128 + row] = s;
    }
  __syncthreads();
  if (t < 128)
    rowsum[t] = (partial[t] + partial[128 + t]) + (partial[256 + t] + partial[384 + t]);

  // ---- phase 3: PV ----
  const int wrp = (w >> 1) * 32, wcp = (w & 1) * 32;
  f4v acc2[2][2];
#pragma unroll
  for (int i = 0; i < 2; ++i)
#pragma unroll
    for (int j = 0; j < 2; ++j) acc2[i][j] = {0.f, 0.f, 0.f, 0.f};

  for (int kc = 0; kc < 8; ++kc) {
    __syncthreads();
    {
      const int hl = w >> 2, ms = w & 3;
      const int r = ms * 16 + brow_l;
      gld_lds16((hl ? vtl : vth) + vbase + (long long)r * 256 + kc * 32 + bchunk,
                (hl ? smV1 : smV0) + ms * 512 + lane * 8);
    }
    __syncthreads();
#pragma unroll
    for (int mi = 0; mi < 2; ++mi) {
      const bf8v pa =
          *(const bf8v*)&Pbuf[kc * 4096 + (wrp + mi * 16 + fr) * 32 + fco];
#pragma unroll
      for (int nj = 0; nj < 2; ++nj) {
        const int rv = wcp + nj * 16 + fr;
        const bf8v v0 = *(const bf8v*)&smV0[rv * 32 + fco];
        const bf8v v1 = *(const bf8v*)&smV1[rv * 32 + fco];
        acc2[mi][nj] = __builtin_amdgcn_mfma_f32_16x16x32_bf16(pa, v0, acc2[mi][nj], 0, 0, 0);
        acc2[mi][nj] = __builtin_amdgcn_mfma_f32_16x16x32_bf16(pa, v1, acc2[mi][nj], 0, 0, 0);
      }
    }
  }
  // ---- epilogue: divide by row sum, write split ----
#pragma unroll
  for (int mi = 0; mi < 2; ++mi)
#pragma unroll
    for (int nj = 0; nj < 2; ++nj)
#pragma unroll
      for (int j = 0; j < 4; ++j) {
        const int row = wrp + mi * 16 + fq * 4 + j;
        const int col = wcp + nj * 16 + fr;
        const float v = acc2[mi][nj][j] / rowsum[row];
        const long long idx = qoff + (long long)row * 768 + col;
        const u16 hb = bf16_rne(v);
        oh[idx] = hb;
        ol[idx] = bf16_rne(v - bf16_to_f(hb));
      }
}

// ---------------- conv pool on split input -> split bf16, [b,h,t,dh] --------
__global__ __launch_bounds__(256) void conv_split_kernel(
    const u16* __restrict__ inh, const u16* __restrict__ inl,
    const float* __restrict__ w, u16* __restrict__ hi, u16* __restrict__ lo,
    int total, int ld) {
  int idx = blockIdx.x * 256 + threadIdx.x;
  if (idx >= total) return;
  const int dh = idx & 63;
  int r = idx >> 6;
  const int tt = r & 1023; r >>= 10;
  const int h = r % 12;
  const int b = r / 12;
  const long long s = ((long long)(b * 4096 + 4 * tt)) * ld + h * 64 + dh;
  const float* wh = w + h * 4;
  float v = 0.f;
#pragma unroll
  for (int j = 0; j < 4; ++j)
    v = fmaf(wh[j], bf16_to_f(inh[s + j * ld]) + bf16_to_f(inl[s + j * ld]), v);
  const u16 hb = bf16_rne(v);
  hi[idx] = hb;
  lo[idx] = bf16_rne(v - bf16_to_f(hb));
}

// ---------------- conv pool on split input -> split, TRANSPOSED [b,h,dh,t] --
__global__ __launch_bounds__(256) void conv_splitT_kernel(
    const u16* __restrict__ inh, const u16* __restrict__ inl,
    const float* __restrict__ w, u16* __restrict__ hi, u16* __restrict__ lo,
    int total, int ld) {
  int idx = blockIdx.x * 256 + threadIdx.x;
  if (idx >= total) return;
  const int tt = idx & 1023;
  int r = idx >> 10;
  const int dh = r & 63; r >>= 6;
  const int h = r % 12;
  const int b = r / 12;
  const long long s = ((long long)(b * 4096 + 4 * tt)) * ld + h * 64 + dh;
  const float* wh = w + h * 4;
  float v = 0.f;
#pragma unroll
  for (int j = 0; j < 4; ++j)
    v = fmaf(wh[j], bf16_to_f(inh[s + j * ld]) + bf16_to_f(inl[s + j * ld]), v);
  const u16 hb = bf16_rne(v);
  hi[idx] = hb;
  lo[idx] = bf16_rne(v - bf16_to_f(hb));
}

// ---------------- transpose+split: [4,256,768] fp32 -> [b,h,dh,key] --------
__global__ __launch_bounds__(256) void splitT_kernel(
    const float* __restrict__ in, u16* __restrict__ hi, u16* __restrict__ lo,
    int total) {
  int idx = blockIdx.x * 256 + threadIdx.x;
  if (idx >= total) return;
  const int key = idx & 255;
  int r = idx >> 8;
  const int dh = r & 63; r >>= 6;
  const int h = r % 12;
  const int b = r / 12;
  const float v = in[((long long)(b * 256 + key)) * 768 + h * 64 + dh];
  const u16 hb = bf16_rne(v);
  hi[idx] = hb;
  lo[idx] = bf16_rne(v - bf16_to_f(hb));
}

// ---------------- row softmax (fp32 in, split out), rowlen 1024 ------------
__global__ __launch_bounds__(256) void softmax_split_kernel(
    const float* __restrict__ in, u16* __restrict__ oh, u16* __restrict__ ol) {
  const long long row = blockIdx.x;
  const float* p = in + row * 1024;
  const int t = threadIdx.x;
  __shared__ float red[4];
  float v[4];
  float lmax = -3.4e38f;
#pragma unroll
  for (int i = 0; i < 4; ++i) {
    v[i] = p[t + (i << 8)];
    lmax = fmaxf(lmax, v[i]);
  }
  for (int o = 32; o; o >>= 1) lmax = fmaxf(lmax, __shfl_xor(lmax, o));
  if ((t & 63) == 0) red[t >> 6] = lmax;
  __syncthreads();
  const float gmax = fmaxf(fmaxf(red[0], red[1]), fmaxf(red[2], red[3]));
  float lsum = 0.f;
#pragma unroll
  for (int i = 0; i < 4; ++i) {
    v[i] = expf(v[i] - gmax);
    lsum += v[i];
  }
  __syncthreads();
  for (int o = 32; o; o >>= 1) lsum += __shfl_xor(lsum, o);
  if ((t & 63) == 0) red[t >> 6] = lsum;
  __syncthreads();
  const float inv = 1.f / (red[0] + red[1] + red[2] + red[3]);
#pragma unroll
  for (int i = 0; i < 4; ++i) {
    const float e = v[i] * inv;
    const u16 hb = bf16_rne(e);
    oh[row * 1024 + t + (i << 8)] = hb;
    ol[row * 1024 + t + (i << 8)] = bf16_rne(e - bf16_to_f(hb));
  }
}

// ---------------- LayerNorm(a + b*maskf), eps 1e-6, width 768 ----------------
__global__ __launch_bounds__(256) void ln_kernel(
    const float* __restrict__ a, const float* __restrict__ b,
    const int* __restrict__ mask, float* __restrict__ out) {
  const long long row = blockIdx.x;
  const float* pa = a + row * 768;
  const float* pb = b + row * 768;
  const float ms = mask ? (float)mask[row] : 1.f;
  __shared__ float buf[768];
  __shared__ float red[4];
  const int t = threadIdx.x;
  float lsum = 0.f;
#pragma unroll
  for (int i = t; i < 768; i += 256) {
    const float v = fmaf(pb[i], ms, pa[i]);
    buf[i] = v;
    lsum += v;
  }
  for (int o = 32; o; o >>= 1) lsum += __shfl_xor(lsum, o);
  if ((t & 63) == 0) red[t >> 6] = lsum;
  __syncthreads();
  const float mu = (red[0] + red[1] + red[2] + red[3]) * (1.f / 768.f);
  float lvar = 0.f;
#pragma unroll
  for (int i = t; i < 768; i += 256) {
    const float d = buf[i] - mu;
    lvar = fmaf(d, d, lvar);
  }
  __syncthreads();
  for (int o = 32; o; o >>= 1) lvar += __shfl_xor(lvar, o);
  if ((t & 63) == 0) red[t >> 6] = lvar;
  __syncthreads();
  const float var = (red[0] + red[1] + red[2] + red[3]) * (1.f / 768.f);
  const float rstd = rsqrtf(var + 1e-6f);
  float* po = out + row * 768;
#pragma unroll
  for (int i = t; i < 768; i += 256) po[i] = (buf[i] - mu) * rstd;
}

// ---------------- host ----------------
static inline void split_launch(hipStream_t st, const float* in, u16* hi,
                                u16* lo, int n) {
  int n4 = n / 4;
  split_kernel<<<(n4 + 255) / 256, 256, 0, st>>>(in, hi, lo, n4);
}

extern "C" void kernel_launch(void* const* d_in, const int* in_sizes, int n_in,
                              void* d_out, int out_size, void* d_ws,
                              size_t ws_size, hipStream_t stream) {
  const float* x = (const float*)d_in[0];
  const float* memory = (const float*)d_in[1];
  const int* mask = (const int*)d_in[2];
  const float* Wq = (const float*)d_in[3];
  const float* Wk = (const float*)d_in[4];
  const float* Wv = (const float*)d_in[5];
  const float* Wo = (const float*)d_in[6];
  const float* conv_w = (const float*)d_in[7];
  const float* Uq = (const float*)d_in[8];
  const float* Uk = (const float*)d_in[9];
  const float* Uv = (const float*)d_in[10];
  const float* Uo = (const float*)d_in[11];
  const float* W1 = (const float*)d_in[12];
  const float* W2 = (const float*)d_in[13];
  float* out = (float*)d_out;
  float* ws = (float*)d_ws;

  const int XR = 16384, MR = 1024, D = 768, MLP = 3072;
  const long long CB = 3145728;
  const int WD = 589824;
  const int WM = 2359296;

  // ---- workspace (floats); total 40,894,464 = 163.6 MB ----
  float* slotA = ws + 0;         // 12.58M
  float* slotB = ws + 12582912;  // 12.58M
  float* slotC = ws + 25165824;  //  3.15M
  float* X     = ws + 28311552;  //  6.29M
  float* qproj = ws + 34603008;  //  786K
  float* attvm = ws + 35389440;  //  786K
  float* packed= ws + 36175872;  //  786K
  float* ukb   = ws + 36962304;  //  786K
  float* uvb   = ws + 37748736;  //  786K
  float* Wp    = ws + 38535168;  //  2.36M

  // plane views
  u16* kvh = (u16*)slotA;            // 25,165,824 elems (fills slotA)
  u16* kvl = kvh + 25165824;         // fills slotB
  u16* qph = (u16*)qproj;            // 786,432 elems
  u16* qpl = qph + 786432;
  u16* ath = (u16*)slotB;            // att split: 12,582,912 elems
  u16* atl = ath + 12582912;
  u16* avh = (u16*)attvm;
  u16* avl = avh + 786432;
  u16* pkh = (u16*)Wp;               // packed split (Wkv-split region, dead)
  u16* pkl = pkh + 786432;
  u16* uqh = (u16*)slotB;            // uq split (att split dead)
  u16* uql = uqh + 12582912;
  u16* ukh = (u16*)ukb;
  u16* ukl = ukh + 786432;
  u16* uah = (u16*)slotA;            // uattvm split (att fp32 dead)
  u16* ual = uah + 12582912;
  u16* hbh = (u16*)slotA;            // FFN h split (uattvm dead)
  u16* hbl = hbh + 12582912;

  u16* wp16 = (u16*)Wp;
  u16 *Wkvh = wp16, *Wkvl = wp16 + 2 * WD,
      *Wqh = wp16 + 4 * WD, *Wql = wp16 + 5 * WD, *Woh = wp16 + 6 * WD,
      *Wol = wp16 + 7 * WD;
  u16* xk = (u16*)X;
  u16 *kph = xk, *kpl = xk + 3145728, *vph = xk + 6291456, *vpl = xk + 9437184;
  u16 *Uqh = xk, *Uql = xk + WD, *Ukh = xk + 2 * WD, *Ukl = xk + 3 * WD,
      *Uvh = xk + 4 * WD, *Uvl = xk + 5 * WD, *Uoh = xk + 6 * WD,
      *Uol = xk + 7 * WD;
  u16 *uvth = xk + 6291456, *uvtl = xk + 7077888;
  u16 *W1h = xk, *W1l = xk + WM, *W2h = xk + 2 * WM, *W2l = xk + 3 * WM;

  // ---- pack phase ----
  split_launch(stream, Wk, Wkvh, Wkvl, WD);
  split_launch(stream, Wv, Wkvh + WD, Wkvl + WD, WD);
  split_launch(stream, Wq, Wqh, Wql, WD);
  split_launch(stream, Wo, Woh, Wol, WD);
  // kvproj: x @ [Wk;Wv]^T -> split planes (slotA∪slotB)
  mgemm_kernel<128, 0, 0, 1><<<dim3(12, 128, 1), 256, 0, stream>>>(
      x, nullptr, nullptr, Wkvh, Wkvl, nullptr, kvh, kvl, XR, 1536, D,
      D, D, 1536, 0, 0, 0, 0, 0, 0, 1, 1.f);
  // qproj -> split
  mgemm_kernel<128, 0, 0, 1><<<dim3(6, 8, 1), 256, 0, stream>>>(
      memory, nullptr, nullptr, Wqh, Wql, nullptr, qph, qpl, MR, D, D,
      D, D, D, 0, 0, 0, 0, 0, 0, 1, 1.f);
  conv_split_kernel<<<12288, 256, 0, stream>>>(kvh, kvl, conv_w, kph, kpl, 3145728, 1536);
  conv_splitT_kernel<<<12288, 256, 0, stream>>>(kvh + 768, kvl + 768, conv_w, vph, vpl, 3145728, 1536);
  // pack logits -> fp32 slotA (kv split dead after conv)
  mgemm_kernel<128, 0, 1, 0><<<dim3(8, 2, 48), 256, 0, stream>>>(
      nullptr, qph, qpl, kph, kpl, slotA, nullptr, nullptr, 256, 1024, 64,
      768, 64, 1024, 196608, 64, 786432, 65536, 3145728, 262144, 12, 1.f);
  softmax_split_kernel<<<12288, 256, 0, stream>>>(slotA, ath, atl);
  // pack PV -> attvm split
  mgemm_kernel<64, 0, 1, 1><<<dim3(1, 2, 48), 256, 0, stream>>>(
      nullptr, ath, atl, vph, vpl, nullptr, avh, avl, 256, 64, 1024,
      1024, 1024, 768, 3145728, 262144, 786432, 65536, 196608, 64, 12, 1.f);
  // Wo: -> packed fp32 + split (pkh/pkl)
  mgemm_kernel<128, 0, 1, 2><<<dim3(6, 8, 1), 256, 0, stream>>>(
      nullptr, avh, avl, Woh, Wol, packed, pkh, pkl, MR, D, D,
      D, D, D, 0, 0, 0, 0, 0, 0, 1, 1.f);
  ln_kernel<<<MR, 256, 0, stream>>>(memory, packed, nullptr, out + 12582912);

  // ---- unpack phase ----
  split_launch(stream, Uq, Uqh, Uql, WD);
  split_launch(stream, Uk, Ukh, Ukl, WD);
  split_launch(stream, Uv, Uvh, Uvl, WD);
  split_launch(stream, Uo, Uoh, Uol, WD);
  // uq (scale 1/8 folded) -> split planes slotB (att split dead)
  mgemm_kernel<128, 0, 0, 1><<<dim3(6, 128, 1), 256, 0, stream>>>(
      x, nullptr, nullptr, Uqh, Uql, nullptr, uqh, uql, XR, D, D,
      D, D, D, 0, 0, 0, 0, 0, 0, 1, 0.125f);
  // Uk -> ukb split
  mgemm_kernel<128, 0, 1, 1><<<dim3(6, 8, 1), 256, 0, stream>>>(
      nullptr, pkh, pkl, Ukh, Ukl, nullptr, ukh, ukl, MR, D, D,
      D, D, D, 0, 0, 0, 0, 0, 0, 1, 1.f);
  // Uv -> uvb fp32 (for transposing split)
  mgemm_kernel<128, 0, 1, 0><<<dim3(6, 8, 1), 256, 0, stream>>>(
      nullptr, pkh, pkl, Uvh, Uvl, uvb, nullptr, nullptr, MR, D, D,
      D, D, D, 0, 0, 0, 0, 0, 0, 1, 1.f);
  splitT_kernel<<<3072, 256, 0, stream>>>(uvb, uvth, uvtl, 786432);
  // fused attention -> uattvm split (slotA)
  {
    dim3 g(32, 1, 48);
    fused_unpack_attn<<<g, 512, 0, stream>>>(uqh, uql, ukh, ukl, uvth, uvtl,
                                             uah, ual);
  }
  // Uo (z=4) -> unp fp32 slotB (uq split dead); LN in-place -> qout1
  mgemm_kernel<128, 0, 1, 0><<<dim3(6, 32, 4), 256, 0, stream>>>(
      nullptr, uah, ual, Uoh, Uol, slotB, nullptr, nullptr, 4096, D, D,
      D, D, D, CB, 0, 0, 0, CB, 0, 1, 1.f);
  ln_kernel<<<XR, 256, 0, stream>>>(x, slotB, mask, slotB);

  // ---- FFN phase ----
  split_launch(stream, W1, W1h, W1l, WM);
  split_launch(stream, W2, W2h, W2l, WM);
  for (int b = 0; b < 4; ++b) {
    // W1 + GELU -> h split (slotA; uattvm dead)
    mgemm_kernel<128, 1, 0, 1><<<dim3(24, 32, 1), 256, 0, stream>>>(
        slotB + b * CB, nullptr, nullptr, W1h, W1l, nullptr, hbh, hbl,
        4096, MLP, D, D, D, MLP, 0, 0, 0, 0, 0, 0, 1, 1.f);
    // W2 (A pre-split) -> y fp32 slotC
    mgemm_kernel<64, 0, 1, 0><<<dim3(12, 32, 1), 256, 0, stream>>>(
        nullptr, hbh, hbl, W2h, W2l, slotC, nullptr, nullptr,
        4096, D, MLP, MLP, MLP, D, 0, 0, 0, 0, 0, 0, 1, 1.f);
    ln_kernel<<<4096, 256, 0, stream>>>(slotB + b * CB, slotC,
                                        mask + b * 4096, out + b * CB);
  }
}

// Round 9
// 810.105 us; speedup vs baseline: 2.5804x; 1.9436x over previous
//
#include <hip/hip_runtime.h>
#include <hip/hip_bf16.h>
#include <math.h>

// ----------------------------------------------------------------------------
// vMFLunaBlock v9: plain bf16 (1-term) MFMA everywhere. fp32 accumulate.
// MFMA work /3 and staging bytes /2 vs v8; LDS dbuf 32KB -> 4-5 blocks/CU.
// Workspace: 40,894,464 floats = 163.6 MB (audited timeline in comments).
// ----------------------------------------------------------------------------

typedef unsigned short u16;
typedef __attribute__((ext_vector_type(8))) short bf8v;
typedef __attribute__((ext_vector_type(4))) float f4v;
typedef __attribute__((ext_vector_type(4))) unsigned short us4v;

#define AS1 __attribute__((address_space(1)))
#define AS3 __attribute__((address_space(3)))

__device__ __forceinline__ void gld_lds16(const void* g, void* l) {
  __builtin_amdgcn_global_load_lds((const AS1 unsigned int*)g,
                                   (AS3 unsigned int*)l, 16, 0, 0);
}

__device__ __forceinline__ u16 bf16_rne(float x) {
  unsigned u = __float_as_uint(x);
  return (u16)((u + 0x7fffu + ((u >> 16) & 1u)) >> 16);
}
__device__ __forceinline__ float bf16_to_f(u16 h) {
  return __uint_as_float(((unsigned)h) << 16);
}

// ---------------- fp32 -> bf16 convert (x4) ----------------
__global__ __launch_bounds__(256) void tobf16_kernel(
    const float* __restrict__ in, u16* __restrict__ o, int n4) {
  int i = blockIdx.x * 256 + threadIdx.x;
  if (i >= n4) return;
  float4 v = ((const float4*)in)[i];
  us4v h;
  h[0] = bf16_rne(v.x); h[1] = bf16_rne(v.y);
  h[2] = bf16_rne(v.z); h[3] = bf16_rne(v.w);
  ((us4v*)o)[i] = h;
}

// ---------------- bf16 MFMA GEMM, double-buffered ----------------
// C = scale*(A @ B^T) [+GELU]. A,B bf16 planes (pure gld_lds staging).
// OMODE: 0=fp32 out, 1=bf16 out, 2=both. Tiles 128 x BN, BK=32, 4 waves.
template <int BN, int GELU, int OMODE>
__global__ __launch_bounds__(256) void bgemm_kernel(
    const u16* __restrict__ A, const u16* __restrict__ B,
    float* __restrict__ Cf, u16* __restrict__ Cb, int M, int N, int K,
    int lda, int ldb, int ldc, long long aSB, long long aSH, long long bSB,
    long long bSH, long long cSB, long long cSH, int HB, float scale) {
  constexpr int NJ = BN / 32;   // B frags per wave
  constexpr int LPB = BN / 64;  // B staging issues per wave
  __shared__ u16 smA[2][4096];      // [buf][128*32]
  __shared__ u16 smB[2][BN * 32];
  const int t = threadIdx.x;
  const int w = t >> 6, lane = t & 63;
  const int z = blockIdx.z;
  const int bb = z / HB, hh = z % HB;
  const u16* Ab = A + bb * aSB + hh * aSH;
  const u16* Bb = B + bb * bSB + hh * bSH;
  float* Cfb = (OMODE != 1) ? (Cf + bb * cSB + hh * cSH) : nullptr;
  u16* Cbb = (OMODE >= 1) ? (Cb + bb * cSB + hh * cSH) : nullptr;

  // XCD swizzle (bijective when nwg%8==0)
  const int gx = gridDim.x;
  const int nwg = gx * gridDim.y;
  int f = blockIdx.x + gx * blockIdx.y;
  if ((nwg & 7) == 0) {
    const int cpx = nwg >> 3;
    f = (f & 7) * cpx + (f >> 3);
  }
  const int row0 = (f / gx) * 128, col0 = (f % gx) * BN;

  const int brow_l = lane >> 2;
  const int bchunk = ((lane & 3) ^ ((lane >> 3) & 3)) * 8;
  const int fr = lane & 15;
  const int fq = lane >> 4;
  const int fco = (fq ^ ((lane >> 1) & 3)) * 8;
  const int wr = (w >> 1) * 64, wc = (w & 1) * (BN / 2);

  f4v acc[4][NJ];
#pragma unroll
  for (int i = 0; i < 4; ++i)
#pragma unroll
    for (int j = 0; j < NJ; ++j) acc[i][j] = {0.f, 0.f, 0.f, 0.f};

  const int NT = K >> 5;

  // ---- prologue: stage tile 0 ----
#pragma unroll
  for (int i = 0; i < 2; ++i) {  // A: 8 groups / 4 waves
    const int g = w * 2 + i;
    const int r = g * 16 + brow_l;
    gld_lds16(Ab + (long long)(row0 + r) * lda + bchunk,
              &smA[0][g * 512 + lane * 8]);
  }
#pragma unroll
  for (int i = 0; i < LPB; ++i) {
    const int g = w * LPB + i;
    const int r = g * 16 + brow_l;
    gld_lds16(Bb + (long long)(col0 + r) * ldb + bchunk,
              &smB[0][g * 512 + lane * 8]);
  }
  __syncthreads();

  for (int tt = 0; tt < NT; ++tt) {
    const int cur = tt & 1, nxt = cur ^ 1;
    const bool more = (tt + 1) < NT;
    if (more) {
      const int k1 = (tt + 1) << 5;
#pragma unroll
      for (int i = 0; i < 2; ++i) {
        const int g = w * 2 + i;
        const int r = g * 16 + brow_l;
        gld_lds16(Ab + (long long)(row0 + r) * lda + k1 + bchunk,
                  &smA[nxt][g * 512 + lane * 8]);
      }
#pragma unroll
      for (int i = 0; i < LPB; ++i) {
        const int g = w * LPB + i;
        const int r = g * 16 + brow_l;
        gld_lds16(Bb + (long long)(col0 + r) * ldb + k1 + bchunk,
                  &smB[nxt][g * 512 + lane * 8]);
      }
    }
    {
      bf8v af[4], bfr[NJ];
#pragma unroll
      for (int mi = 0; mi < 4; ++mi)
        af[mi] = *(const bf8v*)&smA[cur][(wr + mi * 16 + fr) * 32 + fco];
#pragma unroll
      for (int nj = 0; nj < NJ; ++nj)
        bfr[nj] = *(const bf8v*)&smB[cur][(wc + nj * 16 + fr) * 32 + fco];
#pragma unroll
      for (int mi = 0; mi < 4; ++mi)
#pragma unroll
        for (int nj = 0; nj < NJ; ++nj)
          acc[mi][nj] = __builtin_amdgcn_mfma_f32_16x16x32_bf16(
              af[mi], bfr[nj], acc[mi][nj], 0, 0, 0);
    }
    __syncthreads();
  }

#pragma unroll
  for (int mi = 0; mi < 4; ++mi)
#pragma unroll
    for (int nj = 0; nj < NJ; ++nj) {
      const int col = col0 + wc + nj * 16 + fr;
      const long long base =
          (long long)(row0 + wr + mi * 16 + fq * 4) * ldc + col;
#pragma unroll
      for (int j = 0; j < 4; ++j) {
        float v = acc[mi][nj][j] * scale;
        if (GELU) v = 0.5f * v * (1.f + erff(v * 0.70710678118654752f));
        const long long idx = base + (long long)j * ldc;
        if (OMODE != 1) Cfb[idx] = v;
        if (OMODE >= 1) Cbb[idx] = bf16_rne(v);
      }
    }
}

// ---------------- fused unpack attention (bf16 Q/K/V, bf16 out) -------------
// Per block: (b,h), 128 q rows, 256 keys. 512 threads (8 waves).
__global__ __launch_bounds__(512) void fused_unpack_attn(
    const u16* __restrict__ q, const u16* __restrict__ k,
    const u16* __restrict__ vt, u16* __restrict__ o) {
  __shared__ char pool[73216];
  u16* smA = (u16*)pool;                  // [128*32] Q (phase 1)
  u16* smB = (u16*)(pool + 8192);         // [256*32] K
  u16* Pbuf = (u16*)pool;                 // [8][128*32] P (phase 2)
  u16* smV = (u16*)(pool + 65536);        // [64*32] V
  float* partial = (float*)(pool + 69632);  // [4][128]
  float* rowmax = (float*)(pool + 71680);   // [128]
  float* rowsum = (float*)(pool + 72192);   // [128]

  const int t = threadIdx.x;
  const int w = t >> 6, lane = t & 63;
  const int z = blockIdx.z;
  const int b = z / 12, h = z % 12;
  const int q0 = blockIdx.x * 128;

  const long long qoff = ((long long)b * 4096 + q0) * 768 + h * 64;
  const long long koff = ((long long)b * 256) * 768 + h * 64;
  const long long vbase = ((long long)(b * 12 + h)) * 16384;

  const int fr = lane & 15, fq = lane >> 4;
  const int fco = (fq ^ ((lane >> 1) & 3)) * 8;
  const int brow_l = lane >> 2;
  const int bchunk = ((lane & 3) ^ ((lane >> 3) & 3)) * 8;

  // ---- phase 1: logits = Qs @ K^T (Q pre-scaled 1/8) ----
  const int wr = (w >> 2) * 64, wc = (w & 3) * 64;
  f4v acc[4][4];
#pragma unroll
  for (int i = 0; i < 4; ++i)
#pragma unroll
    for (int j = 0; j < 4; ++j) acc[i][j] = {0.f, 0.f, 0.f, 0.f};

  for (int k0 = 0; k0 < 64; k0 += 32) {
    __syncthreads();
#pragma unroll
    for (int i = 0; i < 2; ++i) {  // K: 16 groups / 8 waves
      const int g = w * 2 + i;
      const int r = g * 16 + brow_l;
      gld_lds16(k + koff + (long long)r * 768 + k0 + bchunk,
                smB + g * 512 + lane * 8);
    }
    {  // Q: 8 groups / 8 waves
      const int r = w * 16 + brow_l;
      gld_lds16(q + qoff + (long long)r * 768 + k0 + bchunk,
                smA + w * 512 + lane * 8);
    }
    __syncthreads();
#pragma unroll
    for (int mi = 0; mi < 4; ++mi) {
      const bf8v a0 = *(const bf8v*)&smA[(wr + mi * 16 + fr) * 32 + fco];
#pragma unroll
      for (int nj = 0; nj < 4; ++nj) {
        const bf8v b0 = *(const bf8v*)&smB[(wc + nj * 16 + fr) * 32 + fco];
        acc[mi][nj] = __builtin_amdgcn_mfma_f32_16x16x32_bf16(a0, b0, acc[mi][nj], 0, 0, 0);
      }
    }
  }
  __syncthreads();  // smA/smB dead; Pbuf reusable

  // ---- phase 2: softmax ----
#pragma unroll
  for (int mi = 0; mi < 4; ++mi)
#pragma unroll
    for (int j = 0; j < 4; ++j) {
      float m = fmaxf(fmaxf(acc[mi][0][j], acc[mi][1][j]),
                      fmaxf(acc[mi][2][j], acc[mi][3][j]));
#pragma unroll
      for (int o2 = 1; o2 < 16; o2 <<= 1) m = fmaxf(m, __shfl_xor(m, o2));
      if (fr == 0) partial[(w & 3) * 128 + wr + mi * 16 + fq * 4 + j] = m;
    }
  __syncthreads();
  if (t < 128)
    rowmax[t] = fmaxf(fmaxf(partial[t], partial[128 + t]),
                      fmaxf(partial[256 + t], partial[384 + t]));
  __syncthreads();
#pragma unroll
  for (int mi = 0; mi < 4; ++mi)
#pragma unroll
    for (int j = 0; j < 4; ++j) {
      const int row = wr + mi * 16 + fq * 4 + j;
      const float rm = rowmax[row];
      float s = 0.f;
#pragma unroll
      for (int nj = 0; nj < 4; ++nj) {
        const float e = expf(acc[mi][nj][j] - rm);
        s += e;
        const int col = wc + nj * 16 + fr;
        const int kc = col >> 5, kloc = col & 31;
        Pbuf[kc * 4096 + row * 32 + (((kloc >> 3) ^ ((row >> 1) & 3)) * 8) +
             (kloc & 7)] = bf16_rne(e);
      }
#pragma unroll
      for (int o2 = 1; o2 < 16; o2 <<= 1) s += __shfl_xor(s, o2);
      if (fr == 0) partial[(w & 3) * 128 + row] = s;
    }
  __syncthreads();
  if (t < 128)
    rowsum[t] = (partial[t] + partial[128 + t]) + (partial[256 + t] + partial[384 + t]);

  // ---- phase 3: PV ----
  const int wrp = (w >> 1) * 32, wcp = (w & 1) * 32;
  f4v acc2[2][2];
#pragma unroll
  for (int i = 0; i < 2; ++i)
#pragma unroll
    for (int j = 0; j < 2; ++j) acc2[i][j] = {0.f, 0.f, 0.f, 0.f};

  for (int kc = 0; kc < 8; ++kc) {
    __syncthreads();
    if (w < 4) {  // V: 4 groups
      const int r = w * 16 + brow_l;
      gld_lds16(vt + vbase + (long long)r * 256 + kc * 32 + bchunk,
                smV + w * 512 + lane * 8);
    }
    __syncthreads();
#pragma unroll
    for (int mi = 0; mi < 2; ++mi) {
      const bf8v pa =
          *(const bf8v*)&Pbuf[kc * 4096 + (wrp + mi * 16 + fr) * 32 + fco];
#pragma unroll
      for (int nj = 0; nj < 2; ++nj) {
        const bf8v v0 = *(const bf8v*)&smV[(wcp + nj * 16 + fr) * 32 + fco];
        acc2[mi][nj] = __builtin_amdgcn_mfma_f32_16x16x32_bf16(pa, v0, acc2[mi][nj], 0, 0, 0);
      }
    }
  }
#pragma unroll
  for (int mi = 0; mi < 2; ++mi)
#pragma unroll
    for (int nj = 0; nj < 2; ++nj)
#pragma unroll
      for (int j = 0; j < 4; ++j) {
        const int row = wrp + mi * 16 + fq * 4 + j;
        const int col = wcp + nj * 16 + fr;
        o[qoff + (long long)row * 768 + col] =
            bf16_rne(acc2[mi][nj][j] / rowsum[row]);
      }
}

// ---------------- conv pool (bf16 in) -> bf16, [b,h,t,dh] ----------
__global__ __launch_bounds__(256) void conv_bf16_kernel(
    const u16* __restrict__ in, const float* __restrict__ w,
    u16* __restrict__ o, int total, int ld) {
  int idx = blockIdx.x * 256 + threadIdx.x;
  if (idx >= total) return;
  const int dh = idx & 63;
  int r = idx >> 6;
  const int tt = r & 1023; r >>= 10;
  const int h = r % 12;
  const int b = r / 12;
  const long long s = ((long long)(b * 4096 + 4 * tt)) * ld + h * 64 + dh;
  const float* wh = w + h * 4;
  float v = 0.f;
#pragma unroll
  for (int j = 0; j < 4; ++j) v = fmaf(wh[j], bf16_to_f(in[s + j * ld]), v);
  o[idx] = bf16_rne(v);
}

// ---------------- conv pool (bf16 in) -> bf16, TRANSPOSED [b,h,dh,t] --------
__global__ __launch_bounds__(256) void convT_bf16_kernel(
    const u16* __restrict__ in, const float* __restrict__ w,
    u16* __restrict__ o, int total, int ld) {
  int idx = blockIdx.x * 256 + threadIdx.x;
  if (idx >= total) return;
  const int tt = idx & 1023;
  int r = idx >> 10;
  const int dh = r & 63; r >>= 6;
  const int h = r % 12;
  const int b = r / 12;
  const long long s = ((long long)(b * 4096 + 4 * tt)) * ld + h * 64 + dh;
  const float* wh = w + h * 4;
  float v = 0.f;
#pragma unroll
  for (int j = 0; j < 4; ++j) v = fmaf(wh[j], bf16_to_f(in[s + j * ld]), v);
  o[idx] = bf16_rne(v);
}

// ---------------- transpose: [4,256,768] fp32 -> [b,h,dh,key] bf16 ----------
__global__ __launch_bounds__(256) void transT_bf16_kernel(
    const float* __restrict__ in, u16* __restrict__ o, int total) {
  int idx = blockIdx.x * 256 + threadIdx.x;
  if (idx >= total) return;
  const int key = idx & 255;
  int r = idx >> 8;
  const int dh = r & 63; r >>= 6;
  const int h = r % 12;
  const int b = r / 12;
  o[idx] = bf16_rne(in[((long long)(b * 256 + key)) * 768 + h * 64 + dh]);
}

// ---------------- row softmax (fp32 in, bf16 out), rowlen 1024 --------------
__global__ __launch_bounds__(256) void softmax_bf16_kernel(
    const float* __restrict__ in, u16* __restrict__ ob) {
  const long long row = blockIdx.x;
  const float* p = in + row * 1024;
  const int t = threadIdx.x;
  __shared__ float red[4];
  float v[4];
  float lmax = -3.4e38f;
#pragma unroll
  for (int i = 0; i < 4; ++i) {
    v[i] = p[t + (i << 8)];
    lmax = fmaxf(lmax, v[i]);
  }
  for (int o = 32; o; o >>= 1) lmax = fmaxf(lmax, __shfl_xor(lmax, o));
  if ((t & 63) == 0) red[t >> 6] = lmax;
  __syncthreads();
  const float gmax = fmaxf(fmaxf(red[0], red[1]), fmaxf(red[2], red[3]));
  float lsum = 0.f;
#pragma unroll
  for (int i = 0; i < 4; ++i) {
    v[i] = expf(v[i] - gmax);
    lsum += v[i];
  }
  __syncthreads();
  for (int o = 32; o; o >>= 1) lsum += __shfl_xor(lsum, o);
  if ((t & 63) == 0) red[t >> 6] = lsum;
  __syncthreads();
  const float inv = 1.f / (red[0] + red[1] + red[2] + red[3]);
#pragma unroll
  for (int i = 0; i < 4; ++i)
    ob[row * 1024 + t + (i << 8)] = bf16_rne(v[i] * inv);
}

// ---------------- LayerNorm(a + b*maskf); optional bf16 copy out ------------
__global__ __launch_bounds__(256) void ln_kernel(
    const float* __restrict__ a, const float* __restrict__ b,
    const int* __restrict__ mask, float* __restrict__ out,
    u16* __restrict__ outb) {
  const long long row = blockIdx.x;
  const float* pa = a + row * 768;
  const float* pb = b + row * 768;
  const float ms = mask ? (float)mask[row] : 1.f;
  __shared__ float buf[768];
  __shared__ float red[4];
  const int t = threadIdx.x;
  float lsum = 0.f;
#pragma unroll
  for (int i = t; i < 768; i += 256) {
    const float v = fmaf(pb[i], ms, pa[i]);
    buf[i] = v;
    lsum += v;
  }
  for (int o = 32; o; o >>= 1) lsum += __shfl_xor(lsum, o);
  if ((t & 63) == 0) red[t >> 6] = lsum;
  __syncthreads();
  const float mu = (red[0] + red[1] + red[2] + red[3]) * (1.f / 768.f);
  float lvar = 0.f;
#pragma unroll
  for (int i = t; i < 768; i += 256) {
    const float d = buf[i] - mu;
    lvar = fmaf(d, d, lvar);
  }
  __syncthreads();
  for (int o = 32; o; o >>= 1) lvar += __shfl_xor(lvar, o);
  if ((t & 63) == 0) red[t >> 6] = lvar;
  __syncthreads();
  const float var = (red[0] + red[1] + red[2] + red[3]) * (1.f / 768.f);
  const float rstd = rsqrtf(var + 1e-6f);
  float* po = out + row * 768;
  u16* pob = outb ? outb + row * 768 : nullptr;
#pragma unroll
  for (int i = t; i < 768; i += 256) {
    const float v = (buf[i] - mu) * rstd;
    po[i] = v;
    if (outb) pob[i] = bf16_rne(v);
  }
}

// ---------------- host ----------------
static inline void tobf16(hipStream_t st, const float* in, u16* o, int n) {
  int n4 = n / 4;
  tobf16_kernel<<<(n4 + 255) / 256, 256, 0, st>>>(in, o, n4);
}

extern "C" void kernel_launch(void* const* d_in, const int* in_sizes, int n_in,
                              void* d_out, int out_size, void* d_ws,
                              size_t ws_size, hipStream_t stream) {
  const float* x = (const float*)d_in[0];
  const float* memory = (const float*)d_in[1];
  const int* mask = (const int*)d_in[2];
  const float* Wq = (const float*)d_in[3];
  const float* Wk = (const float*)d_in[4];
  const float* Wv = (const float*)d_in[5];
  const float* Wo = (const float*)d_in[6];
  const float* conv_w = (const float*)d_in[7];
  const float* Uq = (const float*)d_in[8];
  const float* Uk = (const float*)d_in[9];
  const float* Uv = (const float*)d_in[10];
  const float* Uo = (const float*)d_in[11];
  const float* W1 = (const float*)d_in[12];
  const float* W2 = (const float*)d_in[13];
  float* out = (float*)d_out;
  float* ws = (float*)d_ws;

  const int XR = 16384, MR = 1024, D = 768, MLP = 3072;
  const long long CB = 3145728;
  const int WD = 589824;   // 768*768
  const int WM = 2359296;  // 3072*768

  // ---- workspace (floats); total 40,894,464 = 163.6 MB ----
  // slotA: kvb(bf16,full) -> packlogits(fp32,full) -> [uattvb|.] -> [qout1b|hb]
  // slotB: [xb | attb(bf16)] -> [xb | uqb] -> unp/qout1 (fp32, full)
  float* slotA = ws + 0;         // 12.58M
  float* slotB = ws + 12582912;  // 12.58M
  float* slotC = ws + 25165824;  //  3.15M: y_b fp32
  float* X     = ws + 28311552;  //  6.29M: kpb+vpTb (bf16)
  float* s0    = ws + 34603008;  //  786K: qpb + memb (u16)
  float* s1    = ws + 35389440;  //  786K: avmb + pkb (u16)
  float* s2    = ws + 36175872;  //  786K: packed fp32
  float* s3    = ws + 36962304;  //  786K: ukbb + uvTb (u16)
  float* s4    = ws + 37748736;  //  786K: uvb fp32
  float* Wp    = ws + 38535168;  //  2.36M: weight bf16 planes (4.72M u16)

  u16* kvb  = (u16*)slotA;            // [16384][1536]
  u16* xb   = (u16*)slotB;            // [16384][768] (first half)
  u16* attb = (u16*)(slotB + 6291456);  // [48][256][1024]
  u16* uqb  = (u16*)(slotB + 6291456);  // [16384][768] (attb dead)
  u16* uattvb = (u16*)slotA;          // [16384][768] (packlogits dead)
  u16* qout1b = (u16*)slotA;          // [16384][768] (uattvb dead)
  u16* hb   = (u16*)(slotA + 6291456);  // [4096][3072] per batch
  u16* qpb  = (u16*)s0;               // [1024][768]
  u16* memb = qpb + 786432;
  u16* avmb = (u16*)s1;
  u16* pkb  = avmb + 786432;
  float* packed = s2;
  u16* ukbb = (u16*)s3;
  u16* uvTb = ukbb + 786432;
  float* uvb = s4;
  u16* kpb  = (u16*)X;                // [4][12][1024][64]
  u16* vpTb = kpb + 3145728;          // [4][12][64][1024]
  u16* wp16 = (u16*)Wp;               // capacity 4,718,592 u16
  u16* Wkvb = wp16;                   // [1536][768]
  u16* Wqb = wp16 + 2 * WD;
  u16* Wob = wp16 + 3 * WD;
  u16 *Uqb = wp16, *Ukb = wp16 + WD, *Uvb = wp16 + 2 * WD, *Uob = wp16 + 3 * WD;
  u16 *W1b = wp16, *W2b = wp16 + WM;

  // ---- pack phase ----
  tobf16(stream, x, xb, 12582912);
  tobf16(stream, memory, memb, 786432);
  tobf16(stream, Wk, Wkvb, WD);
  tobf16(stream, Wv, Wkvb + WD, WD);
  tobf16(stream, Wq, Wqb, WD);
  tobf16(stream, Wo, Wob, WD);
  // kvproj: xb @ [Wk;Wv]^T -> kvb
  bgemm_kernel<128, 0, 1><<<dim3(12, 128, 1), 256, 0, stream>>>(
      xb, Wkvb, nullptr, kvb, XR, 1536, D, D, D, 1536,
      0, 0, 0, 0, 0, 0, 1, 1.f);
  bgemm_kernel<128, 0, 1><<<dim3(6, 8, 1), 256, 0, stream>>>(
      memb, Wqb, nullptr, qpb, MR, D, D, D, D, D, 0, 0, 0, 0, 0, 0, 1, 1.f);
  conv_bf16_kernel<<<12288, 256, 0, stream>>>(kvb, conv_w, kpb, 3145728, 1536);
  convT_bf16_kernel<<<12288, 256, 0, stream>>>(kvb + 768, conv_w, vpTb, 3145728, 1536);
  // pack logits -> fp32 slotA (kvb dead)
  bgemm_kernel<128, 0, 0><<<dim3(8, 2, 48), 256, 0, stream>>>(
      qpb, kpb, slotA, nullptr, 256, 1024, 64, 768, 64, 1024,
      196608, 64, 786432, 65536, 3145728, 262144, 12, 1.f);
  softmax_bf16_kernel<<<12288, 256, 0, stream>>>(slotA, attb);
  // pack PV -> avmb
  bgemm_kernel<64, 0, 1><<<dim3(1, 2, 48), 256, 0, stream>>>(
      attb, vpTb, nullptr, avmb, 256, 64, 1024, 1024, 1024, 768,
      3145728, 262144, 786432, 65536, 196608, 64, 12, 1.f);
  // Wo -> packed fp32 + pkb bf16
  bgemm_kernel<128, 0, 2><<<dim3(6, 8, 1), 256, 0, stream>>>(
      avmb, Wob, packed, pkb, MR, D, D, D, D, D, 0, 0, 0, 0, 0, 0, 1, 1.f);
  ln_kernel<<<MR, 256, 0, stream>>>(memory, packed, nullptr, out + 12582912,
                                    nullptr);

  // ---- unpack phase ----
  tobf16(stream, Uq, Uqb, WD);
  tobf16(stream, Uk, Ukb, WD);
  tobf16(stream, Uv, Uvb, WD);
  tobf16(stream, Uo, Uob, WD);
  // uq (scale 1/8 folded) -> uqb (attb dead)
  bgemm_kernel<128, 0, 1><<<dim3(6, 128, 1), 256, 0, stream>>>(
      xb, Uqb, nullptr, uqb, XR, D, D, D, D, D, 0, 0, 0, 0, 0, 0, 1, 0.125f);
  bgemm_kernel<128, 0, 1><<<dim3(6, 8, 1), 256, 0, stream>>>(
      pkb, Ukb, nullptr, ukbb, MR, D, D, D, D, D, 0, 0, 0, 0, 0, 0, 1, 1.f);
  bgemm_kernel<128, 0, 0><<<dim3(6, 8, 1), 256, 0, stream>>>(
      pkb, Uvb, uvb, nullptr, MR, D, D, D, D, D, 0, 0, 0, 0, 0, 0, 1, 1.f);
  transT_bf16_kernel<<<3072, 256, 0, stream>>>(uvb, uvTb, 786432);
  // fused attention -> uattvb (slotA)
  {
    dim3 g(32, 1, 48);
    fused_unpack_attn<<<g, 512, 0, stream>>>(uqb, ukbb, uvTb, uattvb);
  }
  // Uo (z=4) -> unp fp32 (full slotB; xb+uqb dead); LN in-place + bf16 out
  bgemm_kernel<128, 0, 0><<<dim3(6, 32, 4), 256, 0, stream>>>(
      uattvb, Uob, slotB, nullptr, 4096, D, D, D, D, D,
      CB, 0, 0, 0, CB, 0, 1, 1.f);
  ln_kernel<<<XR, 256, 0, stream>>>(x, slotB, mask, slotB, qout1b);

  // ---- FFN phase ----
  tobf16(stream, W1, W1b, WM);
  tobf16(stream, W2, W2b, WM);
  for (int b = 0; b < 4; ++b) {
    bgemm_kernel<128, 1, 1><<<dim3(24, 32, 1), 256, 0, stream>>>(
        qout1b + (long long)b * CB, W1b, nullptr, hb, 4096, MLP, D,
        D, D, MLP, 0, 0, 0, 0, 0, 0, 1, 1.f);
    bgemm_kernel<64, 0, 0><<<dim3(12, 32, 1), 256, 0, stream>>>(
        hb, W2b, slotC, nullptr, 4096, D, MLP, MLP, MLP, D,
        0, 0, 0, 0, 0, 0, 1, 1.f);
    ln_kernel<<<4096, 256, 0, stream>>>(slotB + b * CB, slotC,
                                        mask + b * 4096, out + b * CB, nullptr);
  }
}

// Round 10
// 720.943 us; speedup vs baseline: 2.8995x; 1.1237x over previous
//
#include <hip/hip_runtime.h>
#include <hip/hip_bf16.h>
#include <math.h>

// ----------------------------------------------------------------------------
// vMFLunaBlock v10: v9 + attn VALU cuts (exp2 fold, reciprocal rowsum, V dbuf
// with single barrier) + 2-batch z=2 FFN (qout1b scratch in out's upper half).
// Workspace: 40,894,464 floats = 163.6 MB.
// ----------------------------------------------------------------------------

typedef unsigned short u16;
typedef __attribute__((ext_vector_type(8))) short bf8v;
typedef __attribute__((ext_vector_type(4))) float f4v;
typedef __attribute__((ext_vector_type(4))) unsigned short us4v;

#define AS1 __attribute__((address_space(1)))
#define AS3 __attribute__((address_space(3)))

__device__ __forceinline__ void gld_lds16(const void* g, void* l) {
  __builtin_amdgcn_global_load_lds((const AS1 unsigned int*)g,
                                   (AS3 unsigned int*)l, 16, 0, 0);
}

__device__ __forceinline__ u16 bf16_rne(float x) {
  unsigned u = __float_as_uint(x);
  return (u16)((u + 0x7fffu + ((u >> 16) & 1u)) >> 16);
}
__device__ __forceinline__ float bf16_to_f(u16 h) {
  return __uint_as_float(((unsigned)h) << 16);
}

// ---------------- fp32 -> bf16 convert (x4) ----------------
__global__ __launch_bounds__(256) void tobf16_kernel(
    const float* __restrict__ in, u16* __restrict__ o, int n4) {
  int i = blockIdx.x * 256 + threadIdx.x;
  if (i >= n4) return;
  float4 v = ((const float4*)in)[i];
  us4v h;
  h[0] = bf16_rne(v.x); h[1] = bf16_rne(v.y);
  h[2] = bf16_rne(v.z); h[3] = bf16_rne(v.w);
  ((us4v*)o)[i] = h;
}

// ---------------- bf16 MFMA GEMM, double-buffered ----------------
// C = scale*(A @ B^T) [+GELU]. A,B bf16 planes (pure gld_lds staging).
// OMODE: 0=fp32 out, 1=bf16 out, 2=both. Tiles 128 x BN, BK=32, 4 waves.
template <int BN, int GELU, int OMODE>
__global__ __launch_bounds__(256) void bgemm_kernel(
    const u16* __restrict__ A, const u16* __restrict__ B,
    float* __restrict__ Cf, u16* __restrict__ Cb, int M, int N, int K,
    int lda, int ldb, int ldc, long long aSB, long long aSH, long long bSB,
    long long bSH, long long cSB, long long cSH, int HB, float scale) {
  constexpr int NJ = BN / 32;   // B frags per wave
  constexpr int LPB = BN / 64;  // B staging issues per wave
  __shared__ u16 smA[2][4096];      // [buf][128*32]
  __shared__ u16 smB[2][BN * 32];
  const int t = threadIdx.x;
  const int w = t >> 6, lane = t & 63;
  const int z = blockIdx.z;
  const int bb = z / HB, hh = z % HB;
  const u16* Ab = A + bb * aSB + hh * aSH;
  const u16* Bb = B + bb * bSB + hh * bSH;
  float* Cfb = (OMODE != 1) ? (Cf + bb * cSB + hh * cSH) : nullptr;
  u16* Cbb = (OMODE >= 1) ? (Cb + bb * cSB + hh * cSH) : nullptr;

  // XCD swizzle (bijective when nwg%8==0)
  const int gx = gridDim.x;
  const int nwg = gx * gridDim.y;
  int f = blockIdx.x + gx * blockIdx.y;
  if ((nwg & 7) == 0) {
    const int cpx = nwg >> 3;
    f = (f & 7) * cpx + (f >> 3);
  }
  const int row0 = (f / gx) * 128, col0 = (f % gx) * BN;

  const int brow_l = lane >> 2;
  const int bchunk = ((lane & 3) ^ ((lane >> 3) & 3)) * 8;
  const int fr = lane & 15;
  const int fq = lane >> 4;
  const int fco = (fq ^ ((lane >> 1) & 3)) * 8;
  const int wr = (w >> 1) * 64, wc = (w & 1) * (BN / 2);

  f4v acc[4][NJ];
#pragma unroll
  for (int i = 0; i < 4; ++i)
#pragma unroll
    for (int j = 0; j < NJ; ++j) acc[i][j] = {0.f, 0.f, 0.f, 0.f};

  const int NT = K >> 5;

  // ---- prologue: stage tile 0 ----
#pragma unroll
  for (int i = 0; i < 2; ++i) {  // A: 8 groups / 4 waves
    const int g = w * 2 + i;
    const int r = g * 16 + brow_l;
    gld_lds16(Ab + (long long)(row0 + r) * lda + bchunk,
              &smA[0][g * 512 + lane * 8]);
  }
#pragma unroll
  for (int i = 0; i < LPB; ++i) {
    const int g = w * LPB + i;
    const int r = g * 16 + brow_l;
    gld_lds16(Bb + (long long)(col0 + r) * ldb + bchunk,
              &smB[0][g * 512 + lane * 8]);
  }
  __syncthreads();

  for (int tt = 0; tt < NT; ++tt) {
    const int cur = tt & 1, nxt = cur ^ 1;
    const bool more = (tt + 1) < NT;
    if (more) {
      const int k1 = (tt + 1) << 5;
#pragma unroll
      for (int i = 0; i < 2; ++i) {
        const int g = w * 2 + i;
        const int r = g * 16 + brow_l;
        gld_lds16(Ab + (long long)(row0 + r) * lda + k1 + bchunk,
                  &smA[nxt][g * 512 + lane * 8]);
      }
#pragma unroll
      for (int i = 0; i < LPB; ++i) {
        const int g = w * LPB + i;
        const int r = g * 16 + brow_l;
        gld_lds16(Bb + (long long)(col0 + r) * ldb + k1 + bchunk,
                  &smB[nxt][g * 512 + lane * 8]);
      }
    }
    {
      bf8v af[4], bfr[NJ];
#pragma unroll
      for (int mi = 0; mi < 4; ++mi)
        af[mi] = *(const bf8v*)&smA[cur][(wr + mi * 16 + fr) * 32 + fco];
#pragma unroll
      for (int nj = 0; nj < NJ; ++nj)
        bfr[nj] = *(const bf8v*)&smB[cur][(wc + nj * 16 + fr) * 32 + fco];
#pragma unroll
      for (int mi = 0; mi < 4; ++mi)
#pragma unroll
        for (int nj = 0; nj < NJ; ++nj)
          acc[mi][nj] = __builtin_amdgcn_mfma_f32_16x16x32_bf16(
              af[mi], bfr[nj], acc[mi][nj], 0, 0, 0);
    }
    __syncthreads();
  }

#pragma unroll
  for (int mi = 0; mi < 4; ++mi)
#pragma unroll
    for (int nj = 0; nj < NJ; ++nj) {
      const int col = col0 + wc + nj * 16 + fr;
      const long long base =
          (long long)(row0 + wr + mi * 16 + fq * 4) * ldc + col;
#pragma unroll
      for (int j = 0; j < 4; ++j) {
        float v = acc[mi][nj][j] * scale;
        if (GELU) v = 0.5f * v * (1.f + erff(v * 0.70710678118654752f));
        const long long idx = base + (long long)j * ldc;
        if (OMODE != 1) Cfb[idx] = v;
        if (OMODE >= 1) Cbb[idx] = bf16_rne(v);
      }
    }
}

// ---------------- fused unpack attention (bf16 Q/K/V, bf16 out) -------------
// Per block: (b,h), 128 q rows, 256 keys. 512 threads (8 waves).
// Q is pre-scaled by 0.125*log2(e) -> softmax uses exp2 (identical function).
__global__ __launch_bounds__(512) void fused_unpack_attn(
    const u16* __restrict__ q, const u16* __restrict__ k,
    const u16* __restrict__ vt, u16* __restrict__ o) {
  __shared__ char pool[76800];
  u16* smA = (u16*)pool;                  // [128*32] Q (phase 1)
  u16* smB = (u16*)(pool + 8192);         // [256*32] K
  u16* Pbuf = (u16*)pool;                 // [8][128*32] P (phase 2)
  u16* smV = (u16*)(pool + 65536);        // [2][64*32] V dbuf
  float* partial = (float*)(pool + 73728);  // [4][128]
  float* rowmax = (float*)(pool + 75776);   // [128]
  float* rowsum = (float*)(pool + 76288);   // [128] (reciprocal)

  const int t = threadIdx.x;
  const int w = t >> 6, lane = t & 63;
  const int z = blockIdx.z;
  const int b = z / 12, h = z % 12;
  const int q0 = blockIdx.x * 128;

  const long long qoff = ((long long)b * 4096 + q0) * 768 + h * 64;
  const long long koff = ((long long)b * 256) * 768 + h * 64;
  const long long vbase = ((long long)(b * 12 + h)) * 16384;

  const int fr = lane & 15, fq = lane >> 4;
  const int fco = (fq ^ ((lane >> 1) & 3)) * 8;
  const int brow_l = lane >> 2;
  const int bchunk = ((lane & 3) ^ ((lane >> 3) & 3)) * 8;

  // ---- phase 1: logits (log2 domain) = Qs @ K^T ----
  const int wr = (w >> 2) * 64, wc = (w & 3) * 64;
  f4v acc[4][4];
#pragma unroll
  for (int i = 0; i < 4; ++i)
#pragma unroll
    for (int j = 0; j < 4; ++j) acc[i][j] = {0.f, 0.f, 0.f, 0.f};

  for (int k0 = 0; k0 < 64; k0 += 32) {
    __syncthreads();
#pragma unroll
    for (int i = 0; i < 2; ++i) {  // K: 16 groups / 8 waves
      const int g = w * 2 + i;
      const int r = g * 16 + brow_l;
      gld_lds16(k + koff + (long long)r * 768 + k0 + bchunk,
                smB + g * 512 + lane * 8);
    }
    {  // Q: 8 groups / 8 waves
      const int r = w * 16 + brow_l;
      gld_lds16(q + qoff + (long long)r * 768 + k0 + bchunk,
                smA + w * 512 + lane * 8);
    }
    __syncthreads();
#pragma unroll
    for (int mi = 0; mi < 4; ++mi) {
      const bf8v a0 = *(const bf8v*)&smA[(wr + mi * 16 + fr) * 32 + fco];
#pragma unroll
      for (int nj = 0; nj < 4; ++nj) {
        const bf8v b0 = *(const bf8v*)&smB[(wc + nj * 16 + fr) * 32 + fco];
        acc[mi][nj] = __builtin_amdgcn_mfma_f32_16x16x32_bf16(a0, b0, acc[mi][nj], 0, 0, 0);
      }
    }
  }
  __syncthreads();  // smA/smB dead; Pbuf reusable

  // issue V chunk 0 early -- softmax hides the load; next barrier drains it
  if (w < 4) {
    const int r = w * 16 + brow_l;
    gld_lds16(vt + vbase + (long long)r * 256 + bchunk,
              smV + w * 512 + lane * 8);
  }

  // ---- phase 2: softmax (exp2 domain) ----
#pragma unroll
  for (int mi = 0; mi < 4; ++mi)
#pragma unroll
    for (int j = 0; j < 4; ++j) {
      float m = fmaxf(fmaxf(acc[mi][0][j], acc[mi][1][j]),
                      fmaxf(acc[mi][2][j], acc[mi][3][j]));
#pragma unroll
      for (int o2 = 1; o2 < 16; o2 <<= 1) m = fmaxf(m, __shfl_xor(m, o2));
      if (fr == 0) partial[(w & 3) * 128 + wr + mi * 16 + fq * 4 + j] = m;
    }
  __syncthreads();
  if (t < 128)
    rowmax[t] = fmaxf(fmaxf(partial[t], partial[128 + t]),
                      fmaxf(partial[256 + t], partial[384 + t]));
  __syncthreads();
#pragma unroll
  for (int mi = 0; mi < 4; ++mi)
#pragma unroll
    for (int j = 0; j < 4; ++j) {
      const int row = wr + mi * 16 + fq * 4 + j;
      const float rm = rowmax[row];
      float s = 0.f;
#pragma unroll
      for (int nj = 0; nj < 4; ++nj) {
        const float e = exp2f(acc[mi][nj][j] - rm);
        s += e;
        const int col = wc + nj * 16 + fr;
        const int kc = col >> 5, kloc = col & 31;
        Pbuf[kc * 4096 + row * 32 + (((kloc >> 3) ^ ((row >> 1) & 3)) * 8) +
             (kloc & 7)] = bf16_rne(e);
      }
#pragma unroll
      for (int o2 = 1; o2 < 16; o2 <<= 1) s += __shfl_xor(s, o2);
      if (fr == 0) partial[(w & 3) * 128 + row] = s;
    }
  __syncthreads();
  if (t < 128)
    rowsum[t] = 1.f / ((partial[t] + partial[128 + t]) +
                       (partial[256 + t] + partial[384 + t]));
  __syncthreads();  // covers rowsum + Pbuf + V chunk 0 arrival

  // ---- phase 3: PV (V double-buffered, one barrier per chunk) ----
  const int wrp = (w >> 1) * 32, wcp = (w & 1) * 32;
  f4v acc2[2][2];
#pragma unroll
  for (int i = 0; i < 2; ++i)
#pragma unroll
    for (int j = 0; j < 2; ++j) acc2[i][j] = {0.f, 0.f, 0.f, 0.f};

  for (int kc = 0; kc < 8; ++kc) {
    const int cur = (kc & 1) * 2048;
    if (kc < 7 && w < 4) {  // prefetch next V chunk into other half
      const int r = w * 16 + brow_l;
      gld_lds16(vt + vbase + (long long)r * 256 + (kc + 1) * 32 + bchunk,
                smV + (2048 - cur) + w * 512 + lane * 8);
    }
#pragma unroll
    for (int mi = 0; mi < 2; ++mi) {
      const bf8v pa =
          *(const bf8v*)&Pbuf[kc * 4096 + (wrp + mi * 16 + fr) * 32 + fco];
#pragma unroll
      for (int nj = 0; nj < 2; ++nj) {
        const bf8v v0 =
            *(const bf8v*)&smV[cur + (wcp + nj * 16 + fr) * 32 + fco];
        acc2[mi][nj] = __builtin_amdgcn_mfma_f32_16x16x32_bf16(pa, v0, acc2[mi][nj], 0, 0, 0);
      }
    }
    __syncthreads();
  }
#pragma unroll
  for (int mi = 0; mi < 2; ++mi)
#pragma unroll
    for (int nj = 0; nj < 2; ++nj)
#pragma unroll
      for (int j = 0; j < 4; ++j) {
        const int row = wrp + mi * 16 + fq * 4 + j;
        const int col = wcp + nj * 16 + fr;
        o[qoff + (long long)row * 768 + col] =
            bf16_rne(acc2[mi][nj][j] * rowsum[row]);
      }
}

// ---------------- conv pool (bf16 in) -> bf16, [b,h,t,dh] ----------
__global__ __launch_bounds__(256) void conv_bf16_kernel(
    const u16* __restrict__ in, const float* __restrict__ w,
    u16* __restrict__ o, int total, int ld) {
  int idx = blockIdx.x * 256 + threadIdx.x;
  if (idx >= total) return;
  const int dh = idx & 63;
  int r = idx >> 6;
  const int tt = r & 1023; r >>= 10;
  const int h = r % 12;
  const int b = r / 12;
  const long long s = ((long long)(b * 4096 + 4 * tt)) * ld + h * 64 + dh;
  const float* wh = w + h * 4;
  float v = 0.f;
#pragma unroll
  for (int j = 0; j < 4; ++j) v = fmaf(wh[j], bf16_to_f(in[s + j * ld]), v);
  o[idx] = bf16_rne(v);
}

// ---------------- conv pool (bf16 in) -> bf16, TRANSPOSED [b,h,dh,t] --------
__global__ __launch_bounds__(256) void convT_bf16_kernel(
    const u16* __restrict__ in, const float* __restrict__ w,
    u16* __restrict__ o, int total, int ld) {
  int idx = blockIdx.x * 256 + threadIdx.x;
  if (idx >= total) return;
  const int tt = idx & 1023;
  int r = idx >> 10;
  const int dh = r & 63; r >>= 6;
  const int h = r % 12;
  const int b = r / 12;
  const long long s = ((long long)(b * 4096 + 4 * tt)) * ld + h * 64 + dh;
  const float* wh = w + h * 4;
  float v = 0.f;
#pragma unroll
  for (int j = 0; j < 4; ++j) v = fmaf(wh[j], bf16_to_f(in[s + j * ld]), v);
  o[idx] = bf16_rne(v);
}

// ---------------- transpose: [4,256,768] fp32 -> [b,h,dh,key] bf16 ----------
__global__ __launch_bounds__(256) void transT_bf16_kernel(
    const float* __restrict__ in, u16* __restrict__ o, int total) {
  int idx = blockIdx.x * 256 + threadIdx.x;
  if (idx >= total) return;
  const int key = idx & 255;
  int r = idx >> 8;
  const int dh = r & 63; r >>= 6;
  const int h = r % 12;
  const int b = r / 12;
  o[idx] = bf16_rne(in[((long long)(b * 256 + key)) * 768 + h * 64 + dh]);
}

// ---------------- row softmax (fp32 in, bf16 out), rowlen 1024 --------------
__global__ __launch_bounds__(256) void softmax_bf16_kernel(
    const float* __restrict__ in, u16* __restrict__ ob) {
  const long long row = blockIdx.x;
  const float* p = in + row * 1024;
  const int t = threadIdx.x;
  __shared__ float red[4];
  float v[4];
  float lmax = -3.4e38f;
#pragma unroll
  for (int i = 0; i < 4; ++i) {
    v[i] = p[t + (i << 8)];
    lmax = fmaxf(lmax, v[i]);
  }
  for (int o = 32; o; o >>= 1) lmax = fmaxf(lmax, __shfl_xor(lmax, o));
  if ((t & 63) == 0) red[t >> 6] = lmax;
  __syncthreads();
  const float gmax = fmaxf(fmaxf(red[0], red[1]), fmaxf(red[2], red[3]));
  float lsum = 0.f;
#pragma unroll
  for (int i = 0; i < 4; ++i) {
    v[i] = expf(v[i] - gmax);
    lsum += v[i];
  }
  __syncthreads();
  for (int o = 32; o; o >>= 1) lsum += __shfl_xor(lsum, o);
  if ((t & 63) == 0) red[t >> 6] = lsum;
  __syncthreads();
  const float inv = 1.f / (red[0] + red[1] + red[2] + red[3]);
#pragma unroll
  for (int i = 0; i < 4; ++i)
    ob[row * 1024 + t + (i << 8)] = bf16_rne(v[i] * inv);
}

// ---------------- LayerNorm(a + b*maskf); optional bf16 copy out ------------
__global__ __launch_bounds__(256) void ln_kernel(
    const float* __restrict__ a, const float* __restrict__ b,
    const int* __restrict__ mask, float* __restrict__ out,
    u16* __restrict__ outb) {
  const long long row = blockIdx.x;
  const float* pa = a + row * 768;
  const float* pb = b + row * 768;
  const float ms = mask ? (float)mask[row] : 1.f;
  __shared__ float buf[768];
  __shared__ float red[4];
  const int t = threadIdx.x;
  float lsum = 0.f;
#pragma unroll
  for (int i = t; i < 768; i += 256) {
    const float v = fmaf(pb[i], ms, pa[i]);
    buf[i] = v;
    lsum += v;
  }
  for (int o = 32; o; o >>= 1) lsum += __shfl_xor(lsum, o);
  if ((t & 63) == 0) red[t >> 6] = lsum;
  __syncthreads();
  const float mu = (red[0] + red[1] + red[2] + red[3]) * (1.f / 768.f);
  float lvar = 0.f;
#pragma unroll
  for (int i = t; i < 768; i += 256) {
    const float d = buf[i] - mu;
    lvar = fmaf(d, d, lvar);
  }
  __syncthreads();
  for (int o = 32; o; o >>= 1) lvar += __shfl_xor(lvar, o);
  if ((t & 63) == 0) red[t >> 6] = lvar;
  __syncthreads();
  const float var = (red[0] + red[1] + red[2] + red[3]) * (1.f / 768.f);
  const float rstd = rsqrtf(var + 1e-6f);
  float* po = out + row * 768;
  u16* pob = outb ? outb + row * 768 : nullptr;
#pragma unroll
  for (int i = t; i < 768; i += 256) {
    const float v = (buf[i] - mu) * rstd;
    po[i] = v;
    if (outb) pob[i] = bf16_rne(v);
  }
}

// ---------------- host ----------------
static inline void tobf16(hipStream_t st, const float* in, u16* o, int n) {
  int n4 = n / 4;
  tobf16_kernel<<<(n4 + 255) / 256, 256, 0, st>>>(in, o, n4);
}

extern "C" void kernel_launch(void* const* d_in, const int* in_sizes, int n_in,
                              void* d_out, int out_size, void* d_ws,
                              size_t ws_size, hipStream_t stream) {
  const float* x = (const float*)d_in[0];
  const float* memory = (const float*)d_in[1];
  const int* mask = (const int*)d_in[2];
  const float* Wq = (const float*)d_in[3];
  const float* Wk = (const float*)d_in[4];
  const float* Wv = (const float*)d_in[5];
  const float* Wo = (const float*)d_in[6];
  const float* conv_w = (const float*)d_in[7];
  const float* Uq = (const float*)d_in[8];
  const float* Uk = (const float*)d_in[9];
  const float* Uv = (const float*)d_in[10];
  const float* Uo = (const float*)d_in[11];
  const float* W1 = (const float*)d_in[12];
  const float* W2 = (const float*)d_in[13];
  float* out = (float*)d_out;
  float* ws = (float*)d_ws;

  const int XR = 16384, MR = 1024, D = 768, MLP = 3072;
  const long long CB = 3145728;
  const int WD = 589824;   // 768*768
  const int WM = 2359296;  // 3072*768

  // ---- workspace (floats); total 40,894,464 = 163.6 MB ----
  float* slotA = ws + 0;         // 12.58M: kvb -> packlogits -> uattvb -> hb(2bat)
  float* slotB = ws + 12582912;  // 12.58M: [xb|attb/uqb] -> unp/qout1 fp32
  float* slotC = ws + 25165824;  //  3.15M: (FFN) y 2-batch fp32 start
  float* X     = ws + 28311552;  //  6.29M: kpb+vpTb -> (FFN) y spill region
  float* s0    = ws + 34603008;  //  786K: qpb + memb
  float* s1    = ws + 35389440;  //  786K: avmb + pkb
  float* s2    = ws + 36175872;  //  786K: packed fp32
  float* s3    = ws + 36962304;  //  786K: ukbb + uvTb
  float* s4    = ws + 37748736;  //  786K: uvb fp32
  float* Wp    = ws + 38535168;  //  2.36M: weight bf16 planes

  u16* kvb  = (u16*)slotA;              // [16384][1536]
  u16* xb   = (u16*)slotB;              // [16384][768]
  u16* attb = (u16*)(slotB + 6291456);  // [48][256][1024]
  u16* uqb  = (u16*)(slotB + 6291456);  // [16384][768] (attb dead)
  u16* uattvb = (u16*)slotA;            // [16384][768] (packlogits dead)
  u16* qout1b = (u16*)(out + 6291456);  // scratch in q_out upper half (audited)
  u16* hb   = (u16*)slotA;              // [2][4096*3072] (uattvb dead)
  float* ybuf = slotC;                  // [2][4096*768] fp32 (spans into X)
  u16* qpb  = (u16*)s0;
  u16* memb = qpb + 786432;
  u16* avmb = (u16*)s1;
  u16* pkb  = avmb + 786432;
  float* packed = s2;
  u16* ukbb = (u16*)s3;
  u16* uvTb = ukbb + 786432;
  float* uvb = s4;
  u16* kpb  = (u16*)X;                  // [4][12][1024][64]
  u16* vpTb = kpb + 3145728;            // [4][12][64][1024]
  u16* wp16 = (u16*)Wp;
  u16* Wkvb = wp16;                     // [1536][768]
  u16* Wqb = wp16 + 2 * WD;
  u16* Wob = wp16 + 3 * WD;
  u16 *Uqb = wp16, *Ukb = wp16 + WD, *Uvb = wp16 + 2 * WD, *Uob = wp16 + 3 * WD;
  u16 *W1b = wp16, *W2b = wp16 + WM;

  // ---- pack phase ----
  tobf16(stream, x, xb, 12582912);
  tobf16(stream, memory, memb, 786432);
  tobf16(stream, Wk, Wkvb, WD);
  tobf16(stream, Wv, Wkvb + WD, WD);
  tobf16(stream, Wq, Wqb, WD);
  tobf16(stream, Wo, Wob, WD);
  bgemm_kernel<128, 0, 1><<<dim3(12, 128, 1), 256, 0, stream>>>(
      xb, Wkvb, nullptr, kvb, XR, 1536, D, D, D, 1536,
      0, 0, 0, 0, 0, 0, 1, 1.f);
  bgemm_kernel<128, 0, 1><<<dim3(6, 8, 1), 256, 0, stream>>>(
      memb, Wqb, nullptr, qpb, MR, D, D, D, D, D, 0, 0, 0, 0, 0, 0, 1, 1.f);
  conv_bf16_kernel<<<12288, 256, 0, stream>>>(kvb, conv_w, kpb, 3145728, 1536);
  convT_bf16_kernel<<<12288, 256, 0, stream>>>(kvb + 768, conv_w, vpTb, 3145728, 1536);
  bgemm_kernel<128, 0, 0><<<dim3(8, 2, 48), 256, 0, stream>>>(
      qpb, kpb, slotA, nullptr, 256, 1024, 64, 768, 64, 1024,
      196608, 64, 786432, 65536, 3145728, 262144, 12, 1.f);
  softmax_bf16_kernel<<<12288, 256, 0, stream>>>(slotA, attb);
  bgemm_kernel<64, 0, 1><<<dim3(1, 2, 48), 256, 0, stream>>>(
      attb, vpTb, nullptr, avmb, 256, 64, 1024, 1024, 1024, 768,
      3145728, 262144, 786432, 65536, 196608, 64, 12, 1.f);
  bgemm_kernel<128, 0, 2><<<dim3(6, 8, 1), 256, 0, stream>>>(
      avmb, Wob, packed, pkb, MR, D, D, D, D, D, 0, 0, 0, 0, 0, 0, 1, 1.f);
  ln_kernel<<<MR, 256, 0, stream>>>(memory, packed, nullptr, out + 12582912,
                                    nullptr);

  // ---- unpack phase ----
  tobf16(stream, Uq, Uqb, WD);
  tobf16(stream, Uk, Ukb, WD);
  tobf16(stream, Uv, Uvb, WD);
  tobf16(stream, Uo, Uob, WD);
  // uq scale folds 1/8 AND log2(e): softmax runs in exp2 domain
  bgemm_kernel<128, 0, 1><<<dim3(6, 128, 1), 256, 0, stream>>>(
      xb, Uqb, nullptr, uqb, XR, D, D, D, D, D, 0, 0, 0, 0, 0, 0, 1,
      0.18033688011112042592f);
  bgemm_kernel<128, 0, 1><<<dim3(6, 8, 1), 256, 0, stream>>>(
      pkb, Ukb, nullptr, ukbb, MR, D, D, D, D, D, 0, 0, 0, 0, 0, 0, 1, 1.f);
  bgemm_kernel<128, 0, 0><<<dim3(6, 8, 1), 256, 0, stream>>>(
      pkb, Uvb, uvb, nullptr, MR, D, D, D, D, D, 0, 0, 0, 0, 0, 0, 1, 1.f);
  transT_bf16_kernel<<<3072, 256, 0, stream>>>(uvb, uvTb, 786432);
  {
    dim3 g(32, 1, 48);
    fused_unpack_attn<<<g, 512, 0, stream>>>(uqb, ukbb, uvTb, uattvb);
  }
  bgemm_kernel<128, 0, 0><<<dim3(6, 32, 4), 256, 0, stream>>>(
      uattvb, Uob, slotB, nullptr, 4096, D, D, D, D, D,
      CB, 0, 0, 0, CB, 0, 1, 1.f);
  ln_kernel<<<XR, 256, 0, stream>>>(x, slotB, mask, slotB, qout1b);

  // ---- FFN phase: 2 chunks of z=2 batches ----
  // qout1b lives in out[6.29M..12.58M) floats; LN chunk c writes
  // out[c*6.29M..(c+1)*6.29M) AFTER W1 consumed those batches (audited).
  tobf16(stream, W1, W1b, WM);
  tobf16(stream, W2, W2b, WM);
  for (int c = 0; c < 2; ++c) {
    bgemm_kernel<128, 1, 1><<<dim3(24, 32, 2), 256, 0, stream>>>(
        qout1b + (long long)c * 2 * 3145728, W1b, nullptr, hb, 4096, MLP, D,
        D, D, MLP, 3145728, 0, 0, 0, 12582912, 0, 1, 1.f);
    bgemm_kernel<64, 0, 0><<<dim3(12, 32, 2), 256, 0, stream>>>(
        hb, W2b, ybuf, nullptr, 4096, D, MLP, MLP, MLP, D,
        12582912, 0, 0, 0, 3145728, 0, 1, 1.f);
    ln_kernel<<<8192, 256, 0, stream>>>(slotB + (long long)c * 2 * CB, ybuf,
                                        mask + c * 8192,
                                        out + (long long)c * 2 * CB, nullptr);
  }
}